// Round 14
// baseline (238.528 us; speedup 1.0000x reference)
//
#include <hip/hip_runtime.h>
#include <hip/hip_bf16.h>

#define HID 256
#define H1H 8
#define C1 32
#define C2 16
#define NEG 0.2f

typedef unsigned short ushort_t;
typedef unsigned int uint_t;
typedef __attribute__((ext_vector_type(8))) short short8;
typedef __attribute__((ext_vector_type(4))) float f32x4;

__device__ __forceinline__ float lrelu(float t){ return (t >= 0.f) ? t : NEG * t; }
__device__ __forceinline__ ushort_t f2bf(float f){
    uint_t u = __float_as_uint(f);
    u = (u + 0x7fffu + ((u >> 16) & 1u)) >> 16;   // RNE
    return (ushort_t)u;
}
__device__ __forceinline__ float bf_lo(uint_t p){ return __uint_as_float(p << 16); }
__device__ __forceinline__ float bf_hi(uint_t p){ return __uint_as_float(p & 0xffff0000u); }

// ---------------- prep (merged): W1t | W2t | Xbf stream | deg_count + slot ----------------
// deg must be zeroed (hipMemsetAsync) BEFORE this kernel.
__global__ __launch_bounds__(256) void prep_k(const float* __restrict__ X,
                                              ushort_t* __restrict__ Xbf, long n4,
                                              const float* __restrict__ W1,
                                              ushort_t* __restrict__ W1t,
                                              const float* __restrict__ W2,
                                              ushort_t* __restrict__ W2t,
                                              const int* __restrict__ dst,
                                              int E, int Etot, int* __restrict__ deg,
                                              int* __restrict__ slot)
{
    int bid = blockIdx.x;
    if (bid < 64) {
        __shared__ ushort_t sh[32][33];
        int bx = bid & 7, by = bid >> 3;                  // k-tile, n-tile
        int tx = threadIdx.x & 31, ty = threadIdx.x >> 5; // 32 x 8
        #pragma unroll
        for (int i = 0; i < 32; i += 8)
            sh[ty + i][tx] = f2bf(W1[(long)(bx * 32 + ty + i) * 256 + by * 32 + tx]);
        __syncthreads();
        #pragma unroll
        for (int i = 0; i < 32; i += 8)
            W1t[(long)(by * 32 + ty + i) * 256 + bx * 32 + tx] = sh[tx][ty + i];
    } else if (bid == 64) {
        // W2t[c][k] = bf16(W2[k][c]); 4096 elems
        for (int idx = threadIdx.x; idx < 4096; idx += 256) {
            int k = idx >> 4, c = idx & 15;
            W2t[c * 256 + k] = f2bf(W2[idx]);
        }
    } else if (bid < 65 + 2048) {
        long stride = (long)2048 * 256;
        for (long i = (long)(bid - 65) * 256 + threadIdx.x; i < n4; i += stride) {
            float4 v = ((const float4*)X)[i];
            ushort4 o;
            o.x = f2bf(fmaxf(v.x, 0.f)); o.y = f2bf(fmaxf(v.y, 0.f));
            o.z = f2bf(fmaxf(v.z, 0.f)); o.w = f2bf(fmaxf(v.w, 0.f));
            ((ushort4*)Xbf)[i] = o;
        }
    } else {
        int i = (bid - 65 - 2048) * 256 + threadIdx.x;
        if (i < E) {
            int p = atomicAdd(&deg[dst[i]], 1);
            slot[i] = p;                                  // within-node slot index
        } else if (i < Etot) {
            int p = atomicAdd(&deg[i - E], 1);            // self loop
            slot[i] = p;
        }
    }
}

// ---------------- GEMM1 (MFMA, LDS-free): h1b = Xbf @ W1t^T + fused alpha1 ----------------
// A/B fragments loaded directly from global (16B/lane short8). No LDS, no barriers.
// W1t (128KB) is L2-resident; A-tile 2nd-wave reuse L2-hits. OOB A-rows (last tile)
// only affect D-rows >= M, never stored; reads stay inside d_ws (h1b follows xbf).
__global__ __launch_bounds__(256) void gemm1_k(const ushort_t* __restrict__ Xbf,
                                               const ushort_t* __restrict__ W1t,
                                               const float* __restrict__ a1s_g,
                                               const float* __restrict__ a1d_g,
                                               ushort_t* __restrict__ H1b,
                                               float* __restrict__ as1,
                                               float* __restrict__ ad1, int M)
{
    int tid = threadIdx.x;
    int bm = blockIdx.y * 128, bn = blockIdx.x * 128;
    int wid = tid >> 6, lane = tid & 63;
    int wr = wid >> 1, wc = wid & 1;
    int lg = lane >> 4, lm = lane & 15;

    f32x4 acc[4][4];
    #pragma unroll
    for (int m = 0; m < 4; m++)
        #pragma unroll
        for (int n = 0; n < 4; n++) acc[m][n] = (f32x4){0.f, 0.f, 0.f, 0.f};

    // per-lane row pointers (A: 4 rows, B: 4 cols), k-window base = lg*8
    const ushort_t* arow[4];
    const ushort_t* brow[4];
    #pragma unroll
    for (int m = 0; m < 4; m++)
        arow[m] = Xbf + (long)(bm + wr * 64 + m * 16 + lm) * 256 + lg * 8;
    #pragma unroll
    for (int n = 0; n < 4; n++)
        brow[n] = W1t + (long)(bn + wc * 64 + n * 16 + lm) * 256 + lg * 8;

    #pragma unroll
    for (int kk = 0; kk < 256; kk += 32) {
        short8 af[4], bfr[4];
        #pragma unroll
        for (int m = 0; m < 4; m++) af[m] = *(const short8*)(arow[m] + kk);
        #pragma unroll
        for (int n = 0; n < 4; n++) bfr[n] = *(const short8*)(brow[n] + kk);
        #pragma unroll
        for (int m = 0; m < 4; m++)
            #pragma unroll
            for (int n = 0; n < 4; n++)
                acc[m][n] = __builtin_amdgcn_mfma_f32_16x16x32_bf16(af[m], bfr[n], acc[m][n], 0, 0, 0);
    }

    // fused alpha1
    int h0 = ((bn >> 5) + (wc << 1));
    float as_l0 = a1s_g[h0 * 32 + lm],       as_h0 = a1s_g[h0 * 32 + 16 + lm];
    float as_l1 = a1s_g[(h0 + 1) * 32 + lm], as_h1 = a1s_g[(h0 + 1) * 32 + 16 + lm];
    float ad_l0 = a1d_g[h0 * 32 + lm],       ad_h0 = a1d_g[h0 * 32 + 16 + lm];
    float ad_l1 = a1d_g[(h0 + 1) * 32 + lm], ad_h1 = a1d_g[(h0 + 1) * 32 + 16 + lm];

    #pragma unroll
    for (int m = 0; m < 4; m++) {
        #pragma unroll
        for (int r = 0; r < 4; r++) {
            int gm = bm + wr * 64 + m * 16 + lg * 4 + r;
            float s0 = acc[m][0][r] * as_l0 + acc[m][1][r] * as_h0;
            float s1 = acc[m][2][r] * as_l1 + acc[m][3][r] * as_h1;
            float d0 = acc[m][0][r] * ad_l0 + acc[m][1][r] * ad_h0;
            float d1 = acc[m][2][r] * ad_l1 + acc[m][3][r] * ad_h1;
            #pragma unroll
            for (int off = 1; off < 16; off <<= 1) {
                s0 += __shfl_xor(s0, off);
                s1 += __shfl_xor(s1, off);
                d0 += __shfl_xor(d0, off);
                d1 += __shfl_xor(d1, off);
            }
            if (gm < M) {
                long base = (long)gm * 256 + bn + wc * 64 + lm;
                #pragma unroll
                for (int n = 0; n < 4; n++)
                    H1b[base + n * 16] = f2bf(acc[m][n][r]);
                if (lm == 0) {
                    float2 sv = {s0, s1}, dv = {d0, d1};
                    *(float2*)&as1[(gm << 3) + h0] = sv;
                    *(float2*)&ad1[(gm << 3) + h0] = dv;
                }
            }
        }
    }
}

// ---------------- CSR scans ----------------
__global__ __launch_bounds__(256) void scan1_k(const int* __restrict__ deg,
                                               int* __restrict__ incl,
                                               int* __restrict__ bsum, int Nn)
{
    __shared__ int sh[256];
    int t = threadIdx.x;
    int base = blockIdx.x * 1024 + t * 4;
    int v0 = (base     < Nn) ? deg[base]     : 0;
    int v1 = (base + 1 < Nn) ? deg[base + 1] : 0;
    int v2 = (base + 2 < Nn) ? deg[base + 2] : 0;
    int v3 = (base + 3 < Nn) ? deg[base + 3] : 0;
    int s0 = v0, s1 = s0 + v1, s2 = s1 + v2, s3 = s2 + v3;
    sh[t] = s3;
    __syncthreads();
    for (int off = 1; off < 256; off <<= 1) {
        int x = (t >= off) ? sh[t - off] : 0;
        __syncthreads();
        sh[t] += x;
        __syncthreads();
    }
    int prev = (t > 0) ? sh[t - 1] : 0;
    if (base     < Nn) incl[base]     = prev + s0;
    if (base + 1 < Nn) incl[base + 1] = prev + s1;
    if (base + 2 < Nn) incl[base + 2] = prev + s2;
    if (base + 3 < Nn) incl[base + 3] = prev + s3;
    if (t == 255) bsum[blockIdx.x] = sh[255];
}
__global__ void scan2_k(const int* __restrict__ bsum, int* __restrict__ bpre, int nb)
{
    int t = threadIdx.x;                // single wave, nb <= 64
    int own = (t < nb) ? bsum[t] : 0;
    int v = own;
    for (int off = 1; off < 64; off <<= 1) {
        int x = __shfl_up(v, off);
        if (t >= off) v += x;
    }
    if (t < nb) bpre[t] = v - own;      // exclusive
}
__global__ void scan3_k(const int* __restrict__ incl, const int* __restrict__ deg,
                        const int* __restrict__ bpre, int* __restrict__ offs,
                        int Nn, int Etot)
{
    int i = blockIdx.x * 256 + threadIdx.x;
    if (i < Nn) {
        int e = bpre[i >> 10] + incl[i] - deg[i];
        offs[i] = e;
    }
    if (i == 0) offs[Nn] = Etot;
}

// ---------------- scatter: atomic-free (slot precomputed in prep) ----------------
__global__ __launch_bounds__(256) void scatter_k(const int* __restrict__ src,
    const int* __restrict__ dst, const int* __restrict__ slot,
    const int* __restrict__ offs, int E, int Etot, int* __restrict__ srcs)
{
    long base = (long)blockIdx.x * 1024;
    #pragma unroll
    for (int q = 0; q < 4; q++) {
        long i = base + q * 256 + threadIdx.x;
        if (i < E) {
            int d = dst[i];
            srcs[offs[d] + slot[i]] = src[i];       // offs is L2-resident (200 KB)
        } else if (i < Etot) {
            int n = (int)(i - E);
            srcs[offs[n] + slot[i]] = n;            // self loop
        }
    }
}

// ---------------- GAT layer 1 aggregate: wave per dst node ----------------
__global__ __launch_bounds__(256) void gat1_agg_k(const ushort_t* __restrict__ H1b,
    const float* __restrict__ as1, const float* __restrict__ ad1,
    const int* __restrict__ offs, const int* __restrict__ srcs,
    const float* __restrict__ b1, ushort_t* __restrict__ X1b, int Nn)
{
    int w = (blockIdx.x << 2) + (threadIdx.x >> 6);
    if (w >= Nn) return;
    int lane = threadIdx.x & 63;
    int he = lane & 7, el = lane >> 3;
    int myh = lane >> 3;
    int beg = offs[w], end = offs[w + 1];
    int deg = end - beg;
    float adv = ad1[(w << 3) + he];
    float4 acc = {0.f, 0.f, 0.f, 0.f};

    if (deg <= 64) {
        int sv0=0,sv1=0,sv2=0,sv3=0,sv4=0,sv5=0,sv6=0,sv7=0;
        float wv0=0,wv1=0,wv2=0,wv3=0,wv4=0,wv5=0,wv6=0,wv7=0;
        {
            int j;
            j = beg + el;      if (j < end){ sv0 = srcs[j]; wv0 = __expf(lrelu(as1[(sv0<<3)+he]+adv)); }
            j = beg + 8 + el;  if (j < end){ sv1 = srcs[j]; wv1 = __expf(lrelu(as1[(sv1<<3)+he]+adv)); }
            j = beg + 16 + el; if (j < end){ sv2 = srcs[j]; wv2 = __expf(lrelu(as1[(sv2<<3)+he]+adv)); }
            j = beg + 24 + el; if (j < end){ sv3 = srcs[j]; wv3 = __expf(lrelu(as1[(sv3<<3)+he]+adv)); }
            j = beg + 32 + el; if (j < end){ sv4 = srcs[j]; wv4 = __expf(lrelu(as1[(sv4<<3)+he]+adv)); }
            j = beg + 40 + el; if (j < end){ sv5 = srcs[j]; wv5 = __expf(lrelu(as1[(sv5<<3)+he]+adv)); }
            j = beg + 48 + el; if (j < end){ sv6 = srcs[j]; wv6 = __expf(lrelu(as1[(sv6<<3)+he]+adv)); }
            j = beg + 56 + el; if (j < end){ sv7 = srcs[j]; wv7 = __expf(lrelu(as1[(sv7<<3)+he]+adv)); }
        }
        float d = ((wv0 + wv1) + (wv2 + wv3)) + ((wv4 + wv5) + (wv6 + wv7));
        #pragma unroll
        for (int off = 8; off < 64; off <<= 1) d += __shfl_xor(d, off);
        float inv = 1.f / d;
        wv0 *= inv; wv1 *= inv; wv2 *= inv; wv3 *= inv;
        wv4 *= inv; wv5 *= inv; wv6 *= inv; wv7 *= inv;

        #define GAT1_BATCH(SV, WV, Q)                                            \
        {                                                                        \
            int ne = deg - (Q << 3);                                             \
            if (ne > 0) {                                                        \
                ne = min(ne, 8);                                                 \
                int sb[8]; float wb[8];                                          \
                _Pragma("unroll")                                                \
                for (int e8 = 0; e8 < 8; e8++) {                                 \
                    sb[e8] = __shfl(SV, e8 << 3);                                \
                    wb[e8] = __shfl(WV, (e8 << 3) + myh);                        \
                }                                                                \
                if (ne == 8) {                                                   \
                    _Pragma("unroll")                                            \
                    for (int e8 = 0; e8 < 8; e8++) {                             \
                        uint2 v = ((const uint2*)(H1b + ((long)sb[e8] << 8)))[lane]; \
                        acc.x += wb[e8] * bf_lo(v.x);                            \
                        acc.y += wb[e8] * bf_hi(v.x);                            \
                        acc.z += wb[e8] * bf_lo(v.y);                            \
                        acc.w += wb[e8] * bf_hi(v.y);                            \
                    }                                                            \
                } else {                                                         \
                    _Pragma("unroll")                                            \
                    for (int e8 = 0; e8 < 8; e8++) {                             \
                        if (e8 < ne) {                                           \
                            uint2 v = ((const uint2*)(H1b + ((long)sb[e8] << 8)))[lane]; \
                            acc.x += wb[e8] * bf_lo(v.x);                        \
                            acc.y += wb[e8] * bf_hi(v.x);                        \
                            acc.z += wb[e8] * bf_lo(v.y);                        \
                            acc.w += wb[e8] * bf_hi(v.y);                        \
                        }                                                        \
                    }                                                            \
                }                                                                \
            }                                                                    \
        }
        GAT1_BATCH(sv0, wv0, 0)
        GAT1_BATCH(sv1, wv1, 1)
        GAT1_BATCH(sv2, wv2, 2)
        GAT1_BATCH(sv3, wv3, 3)
        GAT1_BATCH(sv4, wv4, 4)
        GAT1_BATCH(sv5, wv5, 5)
        GAT1_BATCH(sv6, wv6, 6)
        GAT1_BATCH(sv7, wv7, 7)
        #undef GAT1_BATCH
    } else {
        float dA = 0.f, dB = 0.f;
        for (int j0 = beg; j0 < end; j0 += 16) {
            int j = j0 + el, jb = j0 + 8 + el;
            if (j < end)  dA += __expf(lrelu(as1[(srcs[j] << 3) + he] + adv));
            if (jb < end) dB += __expf(lrelu(as1[(srcs[jb] << 3) + he] + adv));
        }
        float d = dA + dB;
        #pragma unroll
        for (int off = 8; off < 64; off <<= 1) d += __shfl_xor(d, off);
        float inv = 1.f / d;
        for (int j0 = beg; j0 < end; j0 += 8) {
            int j = j0 + el;
            int s = 0; float wv = 0.f;
            if (j < end) {
                s = srcs[j];
                wv = __expf(lrelu(as1[(s << 3) + he] + adv)) * inv;
            }
            int ne = min(end - j0, 8);
            int sb[8]; float wb[8];
            #pragma unroll
            for (int e8 = 0; e8 < 8; e8++) {
                sb[e8] = __shfl(s, e8 << 3);
                wb[e8] = __shfl(wv, (e8 << 3) + myh);
            }
            #pragma unroll
            for (int e8 = 0; e8 < 8; e8++) {
                if (e8 < ne) {
                    uint2 v = ((const uint2*)(H1b + ((long)sb[e8] << 8)))[lane];
                    acc.x += wb[e8] * bf_lo(v.x);
                    acc.y += wb[e8] * bf_hi(v.x);
                    acc.z += wb[e8] * bf_lo(v.y);
                    acc.w += wb[e8] * bf_hi(v.y);
                }
            }
        }
    }

    float4 bb = ((const float4*)b1)[lane];
    float o0 = fmaxf(acc.x + bb.x, 0.f);
    float o1 = fmaxf(acc.y + bb.y, 0.f);
    float o2 = fmaxf(acc.z + bb.z, 0.f);
    float o3 = fmaxf(acc.w + bb.w, 0.f);
    uint2 ov;
    ov.x = (uint_t)f2bf(o0) | ((uint_t)f2bf(o1) << 16);
    ov.y = (uint_t)f2bf(o2) | ((uint_t)f2bf(o3) << 16);
    ((uint2*)(X1b + ((long)w << 8)))[lane] = ov;
}

// ---------------- GEMM2 (MFMA) + fused alpha2: h2 = x1b @ W2t^T ----------------
__global__ __launch_bounds__(256) void gemm2_k(const ushort_t* __restrict__ X1b,
    const ushort_t* __restrict__ W2t, const float* __restrict__ a2s_w,
    const float* __restrict__ a2d_w, float* __restrict__ H2,
    float* __restrict__ as2, float* __restrict__ ad2, int Nn)
{
    int wid = threadIdx.x >> 6, lane = threadIdx.x & 63;
    int row0 = blockIdx.x * 64 + wid * 16;
    if (row0 >= Nn) return;
    int lm = lane & 15, lg = lane >> 4;
    f32x4 acc = (f32x4){0.f, 0.f, 0.f, 0.f};
    const ushort_t* arow = X1b + (long)(row0 + lm) * 256 + lg * 8;
    const ushort_t* brow = W2t + lm * 256 + lg * 8;
    #pragma unroll
    for (int k0 = 0; k0 < 256; k0 += 32) {
        short8 af = *(const short8*)(arow + k0);
        short8 bf = *(const short8*)(brow + k0);
        acc = __builtin_amdgcn_mfma_f32_16x16x32_bf16(af, bf, acc, 0, 0, 0);
    }
    float a2sv = a2s_w[lm], a2dv = a2d_w[lm];
    #pragma unroll
    for (int r = 0; r < 4; r++) {
        int grow = row0 + lg * 4 + r;
        if (grow < Nn) H2[(grow << 4) + lm] = acc[r];
        float s = acc[r] * a2sv, d2 = acc[r] * a2dv;
        #pragma unroll
        for (int off = 1; off < 16; off <<= 1) {
            s += __shfl_xor(s, off);
            d2 += __shfl_xor(d2, off);
        }
        if (lm == 0 && grow < Nn) { as2[grow] = s; ad2[grow] = d2; }
    }
}

// ---------------- GAT layer 2 aggregate + final softmax (weight-cached) ----------------
__global__ __launch_bounds__(256) void gat2_agg_k(const float* __restrict__ H2,
    const float* __restrict__ as2, const float* __restrict__ ad2,
    const int* __restrict__ offs, const int* __restrict__ srcs,
    const float* __restrict__ b2, float* __restrict__ out, int Nn)
{
    int w = (blockIdx.x << 2) + (threadIdx.x >> 6);
    if (w >= Nn) return;
    int lane = threadIdx.x & 63;
    int beg = offs[w], end = offs[w + 1];
    int deg = end - beg;
    float adv = ad2[w];
    int c = lane & 15, eg = lane >> 4;
    float acc = 0.f;

    if (deg <= 64) {
        int j = beg + lane;
        int s_l = 0; float w_l = 0.f;
        if (j < end) { s_l = srcs[j]; w_l = __expf(lrelu(as2[s_l] + adv)); }
        float d = w_l;
        #pragma unroll
        for (int off = 1; off < 64; off <<= 1) d += __shfl_xor(d, off);
        float w_n = w_l / d;
        for (int j0 = 0; j0 < deg; j0 += 4) {
            int jj = j0 + eg;
            int s = __shfl(s_l, jj);
            float wv = __shfl(w_n, jj);
            if (jj < deg)
                acc += wv * H2[(s << 4) + c];
        }
    } else {
        float d = 0.f;
        for (int j = beg + lane; j < end; j += 64)
            d += __expf(lrelu(as2[srcs[j]] + adv));
        #pragma unroll
        for (int off = 1; off < 64; off <<= 1) d += __shfl_xor(d, off);
        float inv = 1.f / d;
        for (int j0 = beg; j0 < end; j0 += 4) {
            int j = j0 + eg;
            if (j < end) {
                int s = srcs[j];
                float wv = __expf(lrelu(as2[s] + adv)) * inv;
                acc += wv * H2[(s << 4) + c];
            }
        }
    }
    acc += __shfl_xor(acc, 16);
    acc += __shfl_xor(acc, 32);
    float v = acc + b2[c];
    float mx = v;
    #pragma unroll
    for (int off = 1; off < 16; off <<= 1) mx = fmaxf(mx, __shfl_xor(mx, off));
    float ex = __expf(v - mx);
    float se = ex;
    #pragma unroll
    for (int off = 1; off < 16; off <<= 1) se += __shfl_xor(se, off);
    if (eg == 0) out[(w << 4) + c] = ex / se;
}

// ---------------- host launcher ----------------
extern "C" void kernel_launch(void* const* d_in, const int* in_sizes, int n_in,
                              void* d_out, int out_size, void* d_ws, size_t ws_size,
                              hipStream_t stream)
{
    const float* x    = (const float*)d_in[0];
    const int*   ei   = (const int*)d_in[1];
    const float* W1   = (const float*)d_in[2];
    const float* a1s  = (const float*)d_in[3];
    const float* a1d  = (const float*)d_in[4];
    const float* b1   = (const float*)d_in[5];
    const float* W2   = (const float*)d_in[6];
    const float* a2s  = (const float*)d_in[7];
    const float* a2d  = (const float*)d_in[8];
    const float* b2   = (const float*)d_in[9];
    float* out = (float*)d_out;

    int N = in_sizes[0] / HID;
    int E = in_sizes[1] / 2;
    int Etot = E + N;
    const int* src = ei;
    const int* dst = ei + E;

    char* p = (char*)d_ws;
    auto alloc = [&](size_t bytes) {
        void* r = (void*)p;
        p += (bytes + 255) & ~(size_t)255;
        return r;
    };
    ushort_t* xbf  = (ushort_t*)alloc((size_t)N * 256 * 2);
    ushort_t* h1b  = (ushort_t*)alloc((size_t)N * 256 * 2);
    ushort_t* x1b  = (ushort_t*)alloc((size_t)N * 256 * 2);
    ushort_t* w1t  = (ushort_t*)alloc((size_t)256 * 256 * 2);
    ushort_t* w2t  = (ushort_t*)alloc((size_t)16 * 256 * 2);
    float* h2      = (float*)alloc((size_t)N * 16 * 4);
    float* as1     = (float*)alloc((size_t)N * 8 * 4);
    float* ad1     = (float*)alloc((size_t)N * 8 * 4);
    float* as2v    = (float*)alloc((size_t)N * 4);
    float* ad2v    = (float*)alloc((size_t)N * 4);
    int*   deg     = (int*)alloc((size_t)N * 4);
    int*   incl    = (int*)alloc((size_t)N * 4);
    int*   offs    = (int*)alloc((size_t)(N + 1) * 4);
    int*   bsum    = (int*)alloc(256 * 4);
    int*   bpre    = (int*)alloc(256 * 4);
    int*   srcs    = (int*)alloc((size_t)Etot * 4);
    int*   slot    = (int*)alloc((size_t)Etot * 4);

    int nb = (N + 1023) / 1024;
    int cnt_blocks = (Etot + 255) / 256;
    int scat_blocks = (Etot + 1023) / 1024;

    // zero deg, then merged prep (W1t | W2t | Xbf | deg_count+slot)
    hipMemsetAsync(deg, 0, (size_t)N * 4, stream);
    hipLaunchKernelGGL(prep_k, dim3(65 + 2048 + cnt_blocks), dim3(256), 0, stream,
                       x, xbf, (long)N * 64, W1, w1t, W2, w2t, dst, E, Etot, deg, slot);
    // CSR scans
    hipLaunchKernelGGL(scan1_k, dim3(nb), dim3(256), 0, stream, deg, incl, bsum, N);
    hipLaunchKernelGGL(scan2_k, dim3(1), dim3(64), 0, stream, bsum, bpre, nb);
    hipLaunchKernelGGL(scan3_k, dim3((N + 255) / 256), dim3(256), 0, stream,
                       incl, deg, bpre, offs, N, Etot);
    // atomic-free scatter
    hipLaunchKernelGGL(scatter_k, dim3(scat_blocks), dim3(256), 0, stream,
                       src, dst, slot, offs, E, Etot, srcs);
    // GEMM1 (MFMA, LDS-free, fused alpha1)
    dim3 g1(2, (N + 127) / 128);
    hipLaunchKernelGGL(gemm1_k, g1, dim3(256), 0, stream,
                       xbf, w1t, a1s, a1d, h1b, as1, ad1, N);
    // layer 1 aggregate
    hipLaunchKernelGGL(gat1_agg_k, dim3((N + 3) / 4), dim3(256), 0, stream,
                       h1b, as1, ad1, offs, srcs, b1, x1b, N);
    // layer 2: MFMA gemm2 + aggregate
    hipLaunchKernelGGL(gemm2_k, dim3((N + 63) / 64), dim3(256), 0, stream,
                       x1b, w2t, a2s, a2d, h2, as2v, ad2v, N);
    hipLaunchKernelGGL(gat2_agg_k, dim3((N + 3) / 4), dim3(256), 0, stream,
                       h2, as2v, ad2v, offs, srcs, b2, out, N);
}

// Round 15
// 212.277 us; speedup vs baseline: 1.1237x; 1.1237x over previous
//
#include <hip/hip_runtime.h>
#include <hip/hip_bf16.h>

#define HID 256
#define H1H 8
#define C1 32
#define C2 16
#define NEG 0.2f

typedef unsigned short ushort_t;
typedef unsigned int uint_t;
typedef __attribute__((ext_vector_type(8))) short short8;
typedef __attribute__((ext_vector_type(4))) float f32x4;

__device__ __forceinline__ float lrelu(float t){ return (t >= 0.f) ? t : NEG * t; }
__device__ __forceinline__ ushort_t f2bf(float f){
    uint_t u = __float_as_uint(f);
    u = (u + 0x7fffu + ((u >> 16) & 1u)) >> 16;   // RNE
    return (ushort_t)u;
}
__device__ __forceinline__ float bf_lo(uint_t p){ return __uint_as_float(p << 16); }
__device__ __forceinline__ float bf_hi(uint_t p){ return __uint_as_float(p & 0xffff0000u); }

#define GLOAD_LDS16(g, l) \
    __builtin_amdgcn_global_load_lds( \
        (const __attribute__((address_space(1))) void*)(g), \
        (__attribute__((address_space(3))) void*)(l), 16, 0, 0)

// ---------------- prep (merged): W1t | W2t | Xbf stream | deg_count + slot ----------------
// deg must be zeroed (hipMemsetAsync) BEFORE this kernel.
__global__ __launch_bounds__(256) void prep_k(const float* __restrict__ X,
                                              ushort_t* __restrict__ Xbf, long n4,
                                              const float* __restrict__ W1,
                                              ushort_t* __restrict__ W1t,
                                              const float* __restrict__ W2,
                                              ushort_t* __restrict__ W2t,
                                              const int* __restrict__ dst,
                                              int E, int Etot, int* __restrict__ deg,
                                              int* __restrict__ slot)
{
    int bid = blockIdx.x;
    if (bid < 64) {
        __shared__ ushort_t sh[32][33];
        int bx = bid & 7, by = bid >> 3;                  // k-tile, n-tile
        int tx = threadIdx.x & 31, ty = threadIdx.x >> 5; // 32 x 8
        #pragma unroll
        for (int i = 0; i < 32; i += 8)
            sh[ty + i][tx] = f2bf(W1[(long)(bx * 32 + ty + i) * 256 + by * 32 + tx]);
        __syncthreads();
        #pragma unroll
        for (int i = 0; i < 32; i += 8)
            W1t[(long)(by * 32 + ty + i) * 256 + bx * 32 + tx] = sh[tx][ty + i];
    } else if (bid == 64) {
        // W2t[c][k] = bf16(W2[k][c]); 4096 elems
        for (int idx = threadIdx.x; idx < 4096; idx += 256) {
            int k = idx >> 4, c = idx & 15;
            W2t[c * 256 + k] = f2bf(W2[idx]);
        }
    } else if (bid < 65 + 2048) {
        long stride = (long)2048 * 256;
        for (long i = (long)(bid - 65) * 256 + threadIdx.x; i < n4; i += stride) {
            float4 v = ((const float4*)X)[i];
            ushort4 o;
            o.x = f2bf(fmaxf(v.x, 0.f)); o.y = f2bf(fmaxf(v.y, 0.f));
            o.z = f2bf(fmaxf(v.z, 0.f)); o.w = f2bf(fmaxf(v.w, 0.f));
            ((ushort4*)Xbf)[i] = o;
        }
    } else {
        int i = (bid - 65 - 2048) * 256 + threadIdx.x;
        if (i < E) {
            int p = atomicAdd(&deg[dst[i]], 1);
            slot[i] = p;                                  // within-node slot index
        } else if (i < Etot) {
            int p = atomicAdd(&deg[i - E], 1);            // self loop
            slot[i] = p;
        }
    }
}

// ---------------- GEMM1 (MFMA, async-staged, R13 structure) + co-scheduled atomic-free scatter ----
// blocks [0, nGemm): 128x128 GEMM tile (bid>>1 = row tile, bid&1 = col tile);
// blocks [nGemm, ...): 1024-edge atomic-free scatter (4 indep edges/thread).
__global__ __launch_bounds__(256) void gemm1_k(const ushort_t* __restrict__ Xbf,
                                               const ushort_t* __restrict__ W1t,
                                               const float* __restrict__ a1s_g,
                                               const float* __restrict__ a1d_g,
                                               ushort_t* __restrict__ H1b,
                                               float* __restrict__ as1,
                                               float* __restrict__ ad1, int M, int nGemm,
                                               const int* __restrict__ src,
                                               const int* __restrict__ dst,
                                               const int* __restrict__ slot,
                                               const int* __restrict__ offs,
                                               int E, int Etot, int* __restrict__ srcs)
{
    __shared__ ushort_t Abuf[128 * 64];   // 16 KiB, chunk-swizzled
    __shared__ ushort_t Bbuf[128 * 64];   // 16 KiB
    int bid = blockIdx.x;
    int tid = threadIdx.x;

    if (bid >= nGemm) {
        // ---- atomic-free scatter: offs L2-resident; stores fire-and-forget ----
        long base = (long)(bid - nGemm) * 1024;
        #pragma unroll
        for (int q = 0; q < 4; q++) {
            long i = base + q * 256 + tid;
            if (i < E) {
                int d = dst[i];
                srcs[offs[d] + slot[i]] = src[i];
            } else if (i < Etot) {
                int n = (int)(i - E);
                srcs[offs[n] + slot[i]] = n;            // self loop
            }
        }
        return;
    }

    int bm = (bid >> 1) * 128, bn = (bid & 1) * 128;
    int wid = tid >> 6, lane = tid & 63;
    int wr = wid >> 1, wc = wid & 1;
    int lg = lane >> 4, lm = lane & 15;

    f32x4 acc[4][4];
    #pragma unroll
    for (int m = 0; m < 4; m++)
        #pragma unroll
        for (int n = 0; n < 4; n++) acc[m][n] = (f32x4){0.f, 0.f, 0.f, 0.f};

    int r_st[4], lc_st[4];
    #pragma unroll
    for (int q = 0; q < 4; q++) {
        int idx = q * 256 + tid;
        r_st[q] = idx >> 3;
        lc_st[q] = (idx & 7) ^ (r_st[q] & 7);
    }

    for (int k0 = 0; k0 < 256; k0 += 64) {
        __syncthreads();
        #pragma unroll
        for (int q = 0; q < 4; q++) {
            const ushort_t* asrc = Xbf + (long)(bm + r_st[q]) * 256 + k0 + lc_st[q] * 8;
            GLOAD_LDS16(asrc, Abuf + (q * 256 + wid * 64) * 8);
            const ushort_t* bsrc = W1t + (long)(bn + r_st[q]) * 256 + k0 + lc_st[q] * 8;
            GLOAD_LDS16(bsrc, Bbuf + (q * 256 + wid * 64) * 8);
        }
        __syncthreads();
        #pragma unroll
        for (int ks = 0; ks < 2; ks++) {
            int kg = ks * 4 + lg;
            short8 af[4], bfr[4];
            #pragma unroll
            for (int m = 0; m < 4; m++) {
                int R = wr * 64 + m * 16 + lm;
                af[m] = *(const short8*)&Abuf[(R * 8 + (kg ^ (R & 7))) * 8];
            }
            #pragma unroll
            for (int n = 0; n < 4; n++) {
                int Cc = wc * 64 + n * 16 + lm;
                bfr[n] = *(const short8*)&Bbuf[(Cc * 8 + (kg ^ (Cc & 7))) * 8];
            }
            #pragma unroll
            for (int m = 0; m < 4; m++)
                #pragma unroll
                for (int n = 0; n < 4; n++)
                    acc[m][n] = __builtin_amdgcn_mfma_f32_16x16x32_bf16(af[m], bfr[n], acc[m][n], 0, 0, 0);
        }
    }

    // fused alpha1
    int h0 = ((bn >> 5) + (wc << 1));
    float as_l0 = a1s_g[h0 * 32 + lm],       as_h0 = a1s_g[h0 * 32 + 16 + lm];
    float as_l1 = a1s_g[(h0 + 1) * 32 + lm], as_h1 = a1s_g[(h0 + 1) * 32 + 16 + lm];
    float ad_l0 = a1d_g[h0 * 32 + lm],       ad_h0 = a1d_g[h0 * 32 + 16 + lm];
    float ad_l1 = a1d_g[(h0 + 1) * 32 + lm], ad_h1 = a1d_g[(h0 + 1) * 32 + 16 + lm];

    #pragma unroll
    for (int m = 0; m < 4; m++) {
        #pragma unroll
        for (int r = 0; r < 4; r++) {
            int gm = bm + wr * 64 + m * 16 + lg * 4 + r;
            float s0 = acc[m][0][r] * as_l0 + acc[m][1][r] * as_h0;
            float s1 = acc[m][2][r] * as_l1 + acc[m][3][r] * as_h1;
            float d0 = acc[m][0][r] * ad_l0 + acc[m][1][r] * ad_h0;
            float d1 = acc[m][2][r] * ad_l1 + acc[m][3][r] * ad_h1;
            #pragma unroll
            for (int off = 1; off < 16; off <<= 1) {
                s0 += __shfl_xor(s0, off);
                s1 += __shfl_xor(s1, off);
                d0 += __shfl_xor(d0, off);
                d1 += __shfl_xor(d1, off);
            }
            if (gm < M) {
                long base = (long)gm * 256 + bn + wc * 64 + lm;
                #pragma unroll
                for (int n = 0; n < 4; n++)
                    H1b[base + n * 16] = f2bf(acc[m][n][r]);
                if (lm == 0) {
                    float2 sv = {s0, s1}, dv = {d0, d1};
                    *(float2*)&as1[(gm << 3) + h0] = sv;
                    *(float2*)&ad1[(gm << 3) + h0] = dv;
                }
            }
        }
    }
}

// ---------------- CSR scans ----------------
__global__ __launch_bounds__(256) void scan1_k(const int* __restrict__ deg,
                                               int* __restrict__ incl,
                                               int* __restrict__ bsum, int Nn)
{
    __shared__ int sh[256];
    int t = threadIdx.x;
    int base = blockIdx.x * 1024 + t * 4;
    int v0 = (base     < Nn) ? deg[base]     : 0;
    int v1 = (base + 1 < Nn) ? deg[base + 1] : 0;
    int v2 = (base + 2 < Nn) ? deg[base + 2] : 0;
    int v3 = (base + 3 < Nn) ? deg[base + 3] : 0;
    int s0 = v0, s1 = s0 + v1, s2 = s1 + v2, s3 = s2 + v3;
    sh[t] = s3;
    __syncthreads();
    for (int off = 1; off < 256; off <<= 1) {
        int x = (t >= off) ? sh[t - off] : 0;
        __syncthreads();
        sh[t] += x;
        __syncthreads();
    }
    int prev = (t > 0) ? sh[t - 1] : 0;
    if (base     < Nn) incl[base]     = prev + s0;
    if (base + 1 < Nn) incl[base + 1] = prev + s1;
    if (base + 2 < Nn) incl[base + 2] = prev + s2;
    if (base + 3 < Nn) incl[base + 3] = prev + s3;
    if (t == 255) bsum[blockIdx.x] = sh[255];
}
__global__ void scan2_k(const int* __restrict__ bsum, int* __restrict__ bpre, int nb)
{
    int t = threadIdx.x;                // single wave, nb <= 64
    int own = (t < nb) ? bsum[t] : 0;
    int v = own;
    for (int off = 1; off < 64; off <<= 1) {
        int x = __shfl_up(v, off);
        if (t >= off) v += x;
    }
    if (t < nb) bpre[t] = v - own;      // exclusive
}
__global__ void scan3_k(const int* __restrict__ incl, const int* __restrict__ deg,
                        const int* __restrict__ bpre, int* __restrict__ offs,
                        int Nn, int Etot)
{
    int i = blockIdx.x * 256 + threadIdx.x;
    if (i < Nn) {
        int e = bpre[i >> 10] + incl[i] - deg[i];
        offs[i] = e;
    }
    if (i == 0) offs[Nn] = Etot;
}

// ---------------- GAT layer 1 aggregate: wave per dst node ----------------
__global__ __launch_bounds__(256) void gat1_agg_k(const ushort_t* __restrict__ H1b,
    const float* __restrict__ as1, const float* __restrict__ ad1,
    const int* __restrict__ offs, const int* __restrict__ srcs,
    const float* __restrict__ b1, ushort_t* __restrict__ X1b, int Nn)
{
    int w = (blockIdx.x << 2) + (threadIdx.x >> 6);
    if (w >= Nn) return;
    int lane = threadIdx.x & 63;
    int he = lane & 7, el = lane >> 3;
    int myh = lane >> 3;
    int beg = offs[w], end = offs[w + 1];
    int deg = end - beg;
    float adv = ad1[(w << 3) + he];
    float4 acc = {0.f, 0.f, 0.f, 0.f};

    if (deg <= 64) {
        int sv0=0,sv1=0,sv2=0,sv3=0,sv4=0,sv5=0,sv6=0,sv7=0;
        float wv0=0,wv1=0,wv2=0,wv3=0,wv4=0,wv5=0,wv6=0,wv7=0;
        {
            int j;
            j = beg + el;      if (j < end){ sv0 = srcs[j]; wv0 = __expf(lrelu(as1[(sv0<<3)+he]+adv)); }
            j = beg + 8 + el;  if (j < end){ sv1 = srcs[j]; wv1 = __expf(lrelu(as1[(sv1<<3)+he]+adv)); }
            j = beg + 16 + el; if (j < end){ sv2 = srcs[j]; wv2 = __expf(lrelu(as1[(sv2<<3)+he]+adv)); }
            j = beg + 24 + el; if (j < end){ sv3 = srcs[j]; wv3 = __expf(lrelu(as1[(sv3<<3)+he]+adv)); }
            j = beg + 32 + el; if (j < end){ sv4 = srcs[j]; wv4 = __expf(lrelu(as1[(sv4<<3)+he]+adv)); }
            j = beg + 40 + el; if (j < end){ sv5 = srcs[j]; wv5 = __expf(lrelu(as1[(sv5<<3)+he]+adv)); }
            j = beg + 48 + el; if (j < end){ sv6 = srcs[j]; wv6 = __expf(lrelu(as1[(sv6<<3)+he]+adv)); }
            j = beg + 56 + el; if (j < end){ sv7 = srcs[j]; wv7 = __expf(lrelu(as1[(sv7<<3)+he]+adv)); }
        }
        float d = ((wv0 + wv1) + (wv2 + wv3)) + ((wv4 + wv5) + (wv6 + wv7));
        #pragma unroll
        for (int off = 8; off < 64; off <<= 1) d += __shfl_xor(d, off);
        float inv = 1.f / d;
        wv0 *= inv; wv1 *= inv; wv2 *= inv; wv3 *= inv;
        wv4 *= inv; wv5 *= inv; wv6 *= inv; wv7 *= inv;

        #define GAT1_BATCH(SV, WV, Q)                                            \
        {                                                                        \
            int ne = deg - (Q << 3);                                             \
            if (ne > 0) {                                                        \
                ne = min(ne, 8);                                                 \
                int sb[8]; float wb[8];                                          \
                _Pragma("unroll")                                                \
                for (int e8 = 0; e8 < 8; e8++) {                                 \
                    sb[e8] = __shfl(SV, e8 << 3);                                \
                    wb[e8] = __shfl(WV, (e8 << 3) + myh);                        \
                }                                                                \
                if (ne == 8) {                                                   \
                    _Pragma("unroll")                                            \
                    for (int e8 = 0; e8 < 8; e8++) {                             \
                        uint2 v = ((const uint2*)(H1b + ((long)sb[e8] << 8)))[lane]; \
                        acc.x += wb[e8] * bf_lo(v.x);                            \
                        acc.y += wb[e8] * bf_hi(v.x);                            \
                        acc.z += wb[e8] * bf_lo(v.y);                            \
                        acc.w += wb[e8] * bf_hi(v.y);                            \
                    }                                                            \
                } else {                                                         \
                    _Pragma("unroll")                                            \
                    for (int e8 = 0; e8 < 8; e8++) {                             \
                        if (e8 < ne) {                                           \
                            uint2 v = ((const uint2*)(H1b + ((long)sb[e8] << 8)))[lane]; \
                            acc.x += wb[e8] * bf_lo(v.x);                        \
                            acc.y += wb[e8] * bf_hi(v.x);                        \
                            acc.z += wb[e8] * bf_lo(v.y);                        \
                            acc.w += wb[e8] * bf_hi(v.y);                        \
                        }                                                        \
                    }                                                            \
                }                                                                \
            }                                                                    \
        }
        GAT1_BATCH(sv0, wv0, 0)
        GAT1_BATCH(sv1, wv1, 1)
        GAT1_BATCH(sv2, wv2, 2)
        GAT1_BATCH(sv3, wv3, 3)
        GAT1_BATCH(sv4, wv4, 4)
        GAT1_BATCH(sv5, wv5, 5)
        GAT1_BATCH(sv6, wv6, 6)
        GAT1_BATCH(sv7, wv7, 7)
        #undef GAT1_BATCH
    } else {
        float dA = 0.f, dB = 0.f;
        for (int j0 = beg; j0 < end; j0 += 16) {
            int j = j0 + el, jb = j0 + 8 + el;
            if (j < end)  dA += __expf(lrelu(as1[(srcs[j] << 3) + he] + adv));
            if (jb < end) dB += __expf(lrelu(as1[(srcs[jb] << 3) + he] + adv));
        }
        float d = dA + dB;
        #pragma unroll
        for (int off = 8; off < 64; off <<= 1) d += __shfl_xor(d, off);
        float inv = 1.f / d;
        for (int j0 = beg; j0 < end; j0 += 8) {
            int j = j0 + el;
            int s = 0; float wv = 0.f;
            if (j < end) {
                s = srcs[j];
                wv = __expf(lrelu(as1[(s << 3) + he] + adv)) * inv;
            }
            int ne = min(end - j0, 8);
            int sb[8]; float wb[8];
            #pragma unroll
            for (int e8 = 0; e8 < 8; e8++) {
                sb[e8] = __shfl(s, e8 << 3);
                wb[e8] = __shfl(wv, (e8 << 3) + myh);
            }
            #pragma unroll
            for (int e8 = 0; e8 < 8; e8++) {
                if (e8 < ne) {
                    uint2 v = ((const uint2*)(H1b + ((long)sb[e8] << 8)))[lane];
                    acc.x += wb[e8] * bf_lo(v.x);
                    acc.y += wb[e8] * bf_hi(v.x);
                    acc.z += wb[e8] * bf_lo(v.y);
                    acc.w += wb[e8] * bf_hi(v.y);
                }
            }
        }
    }

    float4 bb = ((const float4*)b1)[lane];
    float o0 = fmaxf(acc.x + bb.x, 0.f);
    float o1 = fmaxf(acc.y + bb.y, 0.f);
    float o2 = fmaxf(acc.z + bb.z, 0.f);
    float o3 = fmaxf(acc.w + bb.w, 0.f);
    uint2 ov;
    ov.x = (uint_t)f2bf(o0) | ((uint_t)f2bf(o1) << 16);
    ov.y = (uint_t)f2bf(o2) | ((uint_t)f2bf(o3) << 16);
    ((uint2*)(X1b + ((long)w << 8)))[lane] = ov;
}

// ---------------- GEMM2 (MFMA) + fused alpha2: h2 = x1b @ W2t^T ----------------
__global__ __launch_bounds__(256) void gemm2_k(const ushort_t* __restrict__ X1b,
    const ushort_t* __restrict__ W2t, const float* __restrict__ a2s_w,
    const float* __restrict__ a2d_w, float* __restrict__ H2,
    float* __restrict__ as2, float* __restrict__ ad2, int Nn)
{
    int wid = threadIdx.x >> 6, lane = threadIdx.x & 63;
    int row0 = blockIdx.x * 64 + wid * 16;
    if (row0 >= Nn) return;
    int lm = lane & 15, lg = lane >> 4;
    f32x4 acc = (f32x4){0.f, 0.f, 0.f, 0.f};
    const ushort_t* arow = X1b + (long)(row0 + lm) * 256 + lg * 8;
    const ushort_t* brow = W2t + lm * 256 + lg * 8;
    #pragma unroll
    for (int k0 = 0; k0 < 256; k0 += 32) {
        short8 af = *(const short8*)(arow + k0);
        short8 bf = *(const short8*)(brow + k0);
        acc = __builtin_amdgcn_mfma_f32_16x16x32_bf16(af, bf, acc, 0, 0, 0);
    }
    float a2sv = a2s_w[lm], a2dv = a2d_w[lm];
    #pragma unroll
    for (int r = 0; r < 4; r++) {
        int grow = row0 + lg * 4 + r;
        if (grow < Nn) H2[(grow << 4) + lm] = acc[r];
        float s = acc[r] * a2sv, d2 = acc[r] * a2dv;
        #pragma unroll
        for (int off = 1; off < 16; off <<= 1) {
            s += __shfl_xor(s, off);
            d2 += __shfl_xor(d2, off);
        }
        if (lm == 0 && grow < Nn) { as2[grow] = s; ad2[grow] = d2; }
    }
}

// ---------------- GAT layer 2 aggregate + final softmax (weight-cached) ----------------
__global__ __launch_bounds__(256) void gat2_agg_k(const float* __restrict__ H2,
    const float* __restrict__ as2, const float* __restrict__ ad2,
    const int* __restrict__ offs, const int* __restrict__ srcs,
    const float* __restrict__ b2, float* __restrict__ out, int Nn)
{
    int w = (blockIdx.x << 2) + (threadIdx.x >> 6);
    if (w >= Nn) return;
    int lane = threadIdx.x & 63;
    int beg = offs[w], end = offs[w + 1];
    int deg = end - beg;
    float adv = ad2[w];
    int c = lane & 15, eg = lane >> 4;
    float acc = 0.f;

    if (deg <= 64) {
        int j = beg + lane;
        int s_l = 0; float w_l = 0.f;
        if (j < end) { s_l = srcs[j]; w_l = __expf(lrelu(as2[s_l] + adv)); }
        float d = w_l;
        #pragma unroll
        for (int off = 1; off < 64; off <<= 1) d += __shfl_xor(d, off);
        float w_n = w_l / d;
        for (int j0 = 0; j0 < deg; j0 += 4) {
            int jj = j0 + eg;
            int s = __shfl(s_l, jj);
            float wv = __shfl(w_n, jj);
            if (jj < deg)
                acc += wv * H2[(s << 4) + c];
        }
    } else {
        float d = 0.f;
        for (int j = beg + lane; j < end; j += 64)
            d += __expf(lrelu(as2[srcs[j]] + adv));
        #pragma unroll
        for (int off = 1; off < 64; off <<= 1) d += __shfl_xor(d, off);
        float inv = 1.f / d;
        for (int j0 = beg; j0 < end; j0 += 4) {
            int j = j0 + eg;
            if (j < end) {
                int s = srcs[j];
                float wv = __expf(lrelu(as2[s] + adv)) * inv;
                acc += wv * H2[(s << 4) + c];
            }
        }
    }
    acc += __shfl_xor(acc, 16);
    acc += __shfl_xor(acc, 32);
    float v = acc + b2[c];
    float mx = v;
    #pragma unroll
    for (int off = 1; off < 16; off <<= 1) mx = fmaxf(mx, __shfl_xor(mx, off));
    float ex = __expf(v - mx);
    float se = ex;
    #pragma unroll
    for (int off = 1; off < 16; off <<= 1) se += __shfl_xor(se, off);
    if (eg == 0) out[(w << 4) + c] = ex / se;
}

// ---------------- host launcher ----------------
extern "C" void kernel_launch(void* const* d_in, const int* in_sizes, int n_in,
                              void* d_out, int out_size, void* d_ws, size_t ws_size,
                              hipStream_t stream)
{
    const float* x    = (const float*)d_in[0];
    const int*   ei   = (const int*)d_in[1];
    const float* W1   = (const float*)d_in[2];
    const float* a1s  = (const float*)d_in[3];
    const float* a1d  = (const float*)d_in[4];
    const float* b1   = (const float*)d_in[5];
    const float* W2   = (const float*)d_in[6];
    const float* a2s  = (const float*)d_in[7];
    const float* a2d  = (const float*)d_in[8];
    const float* b2   = (const float*)d_in[9];
    float* out = (float*)d_out;

    int N = in_sizes[0] / HID;
    int E = in_sizes[1] / 2;
    int Etot = E + N;
    const int* src = ei;
    const int* dst = ei + E;

    char* p = (char*)d_ws;
    auto alloc = [&](size_t bytes) {
        void* r = (void*)p;
        p += (bytes + 255) & ~(size_t)255;
        return r;
    };
    ushort_t* xbf  = (ushort_t*)alloc((size_t)N * 256 * 2);
    ushort_t* h1b  = (ushort_t*)alloc((size_t)N * 256 * 2);
    ushort_t* x1b  = (ushort_t*)alloc((size_t)N * 256 * 2);
    ushort_t* w1t  = (ushort_t*)alloc((size_t)256 * 256 * 2);
    ushort_t* w2t  = (ushort_t*)alloc((size_t)16 * 256 * 2);
    float* h2      = (float*)alloc((size_t)N * 16 * 4);
    float* as1     = (float*)alloc((size_t)N * 8 * 4);
    float* ad1     = (float*)alloc((size_t)N * 8 * 4);
    float* as2v    = (float*)alloc((size_t)N * 4);
    float* ad2v    = (float*)alloc((size_t)N * 4);
    int*   deg     = (int*)alloc((size_t)N * 4);
    int*   incl    = (int*)alloc((size_t)N * 4);
    int*   offs    = (int*)alloc((size_t)(N + 1) * 4);
    int*   bsum    = (int*)alloc(256 * 4);
    int*   bpre    = (int*)alloc(256 * 4);
    int*   srcs    = (int*)alloc((size_t)Etot * 4);
    int*   slot    = (int*)alloc((size_t)Etot * 4);

    int nb = (N + 1023) / 1024;
    int cnt_blocks = (Etot + 255) / 256;
    int nGemm = 2 * ((N + 127) / 128);
    int scat_blocks = (Etot + 1023) / 1024;

    // zero deg, then merged prep (W1t | W2t | Xbf | deg_count+slot)
    hipMemsetAsync(deg, 0, (size_t)N * 4, stream);
    hipLaunchKernelGGL(prep_k, dim3(65 + 2048 + cnt_blocks), dim3(256), 0, stream,
                       x, xbf, (long)N * 64, W1, w1t, W2, w2t, dst, E, Etot, deg, slot);
    // CSR scans
    hipLaunchKernelGGL(scan1_k, dim3(nb), dim3(256), 0, stream, deg, incl, bsum, N);
    hipLaunchKernelGGL(scan2_k, dim3(1), dim3(64), 0, stream, bsum, bpre, nb);
    hipLaunchKernelGGL(scan3_k, dim3((N + 255) / 256), dim3(256), 0, stream,
                       incl, deg, bpre, offs, N, Etot);
    // GEMM1 (MFMA, async-staged, fused alpha1) + co-scheduled atomic-free scatter
    hipLaunchKernelGGL(gemm1_k, dim3(nGemm + scat_blocks), dim3(256), 0, stream,
                       xbf, w1t, a1s, a1d, h1b, as1, ad1, N, nGemm,
                       src, dst, slot, offs, E, Etot, srcs);
    // layer 1 aggregate
    hipLaunchKernelGGL(gat1_agg_k, dim3((N + 3) / 4), dim3(256), 0, stream,
                       h1b, as1, ad1, offs, srcs, b1, x1b, N);
    // layer 2: MFMA gemm2 + aggregate
    hipLaunchKernelGGL(gemm2_k, dim3((N + 63) / 64), dim3(256), 0, stream,
                       x1b, w2t, a2s, a2d, h2, as2v, ad2v, N);
    hipLaunchKernelGGL(gat2_agg_k, dim3((N + 3) / 4), dim3(256), 0, stream,
                       h2, as2v, ad2v, offs, srcs, b2, out, N);
}

// Round 16
// 206.207 us; speedup vs baseline: 1.1567x; 1.0294x over previous
//
#include <hip/hip_runtime.h>
#include <hip/hip_bf16.h>

#define HID 256
#define H1H 8
#define C1 32
#define C2 16
#define NEG 0.2f

typedef unsigned short ushort_t;
typedef unsigned int uint_t;
typedef __attribute__((ext_vector_type(8))) short short8;
typedef __attribute__((ext_vector_type(4))) float f32x4;

__device__ __forceinline__ float lrelu(float t){ return (t >= 0.f) ? t : NEG * t; }
__device__ __forceinline__ ushort_t f2bf(float f){
    uint_t u = __float_as_uint(f);
    u = (u + 0x7fffu + ((u >> 16) & 1u)) >> 16;   // RNE
    return (ushort_t)u;
}
__device__ __forceinline__ float bf_lo(uint_t p){ return __uint_as_float(p << 16); }
__device__ __forceinline__ float bf_hi(uint_t p){ return __uint_as_float(p & 0xffff0000u); }

#define GLOAD_LDS16(g, l) \
    __builtin_amdgcn_global_load_lds( \
        (const __attribute__((address_space(1))) void*)(g), \
        (__attribute__((address_space(3))) void*)(l), 16, 0, 0)

// ---------------- prep (merged): W1t | W2t | Xbf stream | deg_count + slot ----------------
// deg must be zeroed (hipMemsetAsync) BEFORE this kernel.
__global__ __launch_bounds__(256) void prep_k(const float* __restrict__ X,
                                              ushort_t* __restrict__ Xbf, long n4,
                                              const float* __restrict__ W1,
                                              ushort_t* __restrict__ W1t,
                                              const float* __restrict__ W2,
                                              ushort_t* __restrict__ W2t,
                                              const int* __restrict__ dst,
                                              int E, int Etot, int* __restrict__ deg,
                                              int* __restrict__ slot)
{
    int bid = blockIdx.x;
    if (bid < 64) {
        __shared__ ushort_t sh[32][33];
        int bx = bid & 7, by = bid >> 3;                  // k-tile, n-tile
        int tx = threadIdx.x & 31, ty = threadIdx.x >> 5; // 32 x 8
        #pragma unroll
        for (int i = 0; i < 32; i += 8)
            sh[ty + i][tx] = f2bf(W1[(long)(bx * 32 + ty + i) * 256 + by * 32 + tx]);
        __syncthreads();
        #pragma unroll
        for (int i = 0; i < 32; i += 8)
            W1t[(long)(by * 32 + ty + i) * 256 + bx * 32 + tx] = sh[tx][ty + i];
    } else if (bid == 64) {
        // W2t[c][k] = bf16(W2[k][c]); 4096 elems
        for (int idx = threadIdx.x; idx < 4096; idx += 256) {
            int k = idx >> 4, c = idx & 15;
            W2t[c * 256 + k] = f2bf(W2[idx]);
        }
    } else if (bid < 65 + 2048) {
        long stride = (long)2048 * 256;
        for (long i = (long)(bid - 65) * 256 + threadIdx.x; i < n4; i += stride) {
            float4 v = ((const float4*)X)[i];
            ushort4 o;
            o.x = f2bf(fmaxf(v.x, 0.f)); o.y = f2bf(fmaxf(v.y, 0.f));
            o.z = f2bf(fmaxf(v.z, 0.f)); o.w = f2bf(fmaxf(v.w, 0.f));
            ((ushort4*)Xbf)[i] = o;
        }
    } else {
        int i = (bid - 65 - 2048) * 256 + threadIdx.x;
        if (i < E) {
            int p = atomicAdd(&deg[dst[i]], 1);
            slot[i] = p;                                  // within-node slot index
        } else if (i < Etot) {
            int p = atomicAdd(&deg[i - E], 1);            // self loop
            slot[i] = p;
        }
    }
}

// ---------------- GEMM1 (MFMA, async-staged, 64x128 tile): h1b = Xbf @ W1t^T + fused alpha1 ----
// 24KB LDS -> ~6 blocks/CU; 2x col tiles x (N/64) row tiles for latency overlap.
// 4 waves as 2x2 over 64 rows x 128 cols: each wave 32x64, acc[2][4].
__global__ __launch_bounds__(256) void gemm1_k(const ushort_t* __restrict__ Xbf,
                                               const ushort_t* __restrict__ W1t,
                                               const float* __restrict__ a1s_g,
                                               const float* __restrict__ a1d_g,
                                               ushort_t* __restrict__ H1b,
                                               float* __restrict__ as1,
                                               float* __restrict__ ad1, int M)
{
    __shared__ ushort_t Abuf[64 * 64];    // 8 KiB: 64 rows x 8 chunks, chunk-swizzled
    __shared__ ushort_t Bbuf[128 * 64];   // 16 KiB: 128 cols x 8 chunks
    int tid = threadIdx.x;
    int bm = blockIdx.y * 64, bn = blockIdx.x * 128;
    int wid = tid >> 6, lane = tid & 63;
    int wr = wid >> 1, wc = wid & 1;
    int lg = lane >> 4, lm = lane & 15;

    f32x4 acc[2][4];
    #pragma unroll
    for (int m = 0; m < 2; m++)
        #pragma unroll
        for (int n = 0; n < 4; n++) acc[m][n] = (f32x4){0.f, 0.f, 0.f, 0.f};

    // staging geometry: chunk idx = q*256 + tid; row = idx>>3, cpos = idx&7,
    // logical chunk lc = cpos ^ (row&7)  (inverse-swizzled source, linear dest)
    int rA[2], lcA[2];
    #pragma unroll
    for (int q = 0; q < 2; q++) {
        int idx = q * 256 + tid;
        rA[q] = idx >> 3;
        lcA[q] = (idx & 7) ^ (rA[q] & 7);
    }
    int rB[4], lcB[4];
    #pragma unroll
    for (int q = 0; q < 4; q++) {
        int idx = q * 256 + tid;
        rB[q] = idx >> 3;
        lcB[q] = (idx & 7) ^ (rB[q] & 7);
    }

    for (int k0 = 0; k0 < 256; k0 += 64) {
        __syncthreads();
        #pragma unroll
        for (int q = 0; q < 2; q++) {
            const ushort_t* asrc = Xbf + (long)(bm + rA[q]) * 256 + k0 + lcA[q] * 8;
            GLOAD_LDS16(asrc, Abuf + (q * 256 + wid * 64) * 8);
        }
        #pragma unroll
        for (int q = 0; q < 4; q++) {
            const ushort_t* bsrc = W1t + (long)(bn + rB[q]) * 256 + k0 + lcB[q] * 8;
            GLOAD_LDS16(bsrc, Bbuf + (q * 256 + wid * 64) * 8);
        }
        __syncthreads();
        #pragma unroll
        for (int ks = 0; ks < 2; ks++) {
            int kg = ks * 4 + lg;
            short8 af[2], bfr[4];
            #pragma unroll
            for (int m = 0; m < 2; m++) {
                int R = wr * 32 + m * 16 + lm;
                af[m] = *(const short8*)&Abuf[(R * 8 + (kg ^ (R & 7))) * 8];
            }
            #pragma unroll
            for (int n = 0; n < 4; n++) {
                int Cc = wc * 64 + n * 16 + lm;
                bfr[n] = *(const short8*)&Bbuf[(Cc * 8 + (kg ^ (Cc & 7))) * 8];
            }
            #pragma unroll
            for (int m = 0; m < 2; m++)
                #pragma unroll
                for (int n = 0; n < 4; n++)
                    acc[m][n] = __builtin_amdgcn_mfma_f32_16x16x32_bf16(af[m], bfr[n], acc[m][n], 0, 0, 0);
        }
    }

    // fused alpha1: this thread's cols for (m,r) live in heads h0 (n=0,1) and h0+1 (n=2,3)
    int h0 = ((bn >> 5) + (wc << 1));
    float as_l0 = a1s_g[h0 * 32 + lm],       as_h0 = a1s_g[h0 * 32 + 16 + lm];
    float as_l1 = a1s_g[(h0 + 1) * 32 + lm], as_h1 = a1s_g[(h0 + 1) * 32 + 16 + lm];
    float ad_l0 = a1d_g[h0 * 32 + lm],       ad_h0 = a1d_g[h0 * 32 + 16 + lm];
    float ad_l1 = a1d_g[(h0 + 1) * 32 + lm], ad_h1 = a1d_g[(h0 + 1) * 32 + 16 + lm];

    #pragma unroll
    for (int m = 0; m < 2; m++) {
        #pragma unroll
        for (int r = 0; r < 4; r++) {
            int gm = bm + wr * 32 + m * 16 + lg * 4 + r;
            float s0 = acc[m][0][r] * as_l0 + acc[m][1][r] * as_h0;
            float s1 = acc[m][2][r] * as_l1 + acc[m][3][r] * as_h1;
            float d0 = acc[m][0][r] * ad_l0 + acc[m][1][r] * ad_h0;
            float d1 = acc[m][2][r] * ad_l1 + acc[m][3][r] * ad_h1;
            #pragma unroll
            for (int off = 1; off < 16; off <<= 1) {
                s0 += __shfl_xor(s0, off);
                s1 += __shfl_xor(s1, off);
                d0 += __shfl_xor(d0, off);
                d1 += __shfl_xor(d1, off);
            }
            if (gm < M) {
                long base = (long)gm * 256 + bn + wc * 64 + lm;
                #pragma unroll
                for (int n = 0; n < 4; n++)
                    H1b[base + n * 16] = f2bf(acc[m][n][r]);
                if (lm == 0) {
                    float2 sv = {s0, s1}, dv = {d0, d1};
                    *(float2*)&as1[(gm << 3) + h0] = sv;
                    *(float2*)&ad1[(gm << 3) + h0] = dv;
                }
            }
        }
    }
}

// ---------------- CSR scans ----------------
__global__ __launch_bounds__(256) void scan1_k(const int* __restrict__ deg,
                                               int* __restrict__ incl,
                                               int* __restrict__ bsum, int Nn)
{
    __shared__ int sh[256];
    int t = threadIdx.x;
    int base = blockIdx.x * 1024 + t * 4;
    int v0 = (base     < Nn) ? deg[base]     : 0;
    int v1 = (base + 1 < Nn) ? deg[base + 1] : 0;
    int v2 = (base + 2 < Nn) ? deg[base + 2] : 0;
    int v3 = (base + 3 < Nn) ? deg[base + 3] : 0;
    int s0 = v0, s1 = s0 + v1, s2 = s1 + v2, s3 = s2 + v3;
    sh[t] = s3;
    __syncthreads();
    for (int off = 1; off < 256; off <<= 1) {
        int x = (t >= off) ? sh[t - off] : 0;
        __syncthreads();
        sh[t] += x;
        __syncthreads();
    }
    int prev = (t > 0) ? sh[t - 1] : 0;
    if (base     < Nn) incl[base]     = prev + s0;
    if (base + 1 < Nn) incl[base + 1] = prev + s1;
    if (base + 2 < Nn) incl[base + 2] = prev + s2;
    if (base + 3 < Nn) incl[base + 3] = prev + s3;
    if (t == 255) bsum[blockIdx.x] = sh[255];
}
__global__ void scan2_k(const int* __restrict__ bsum, int* __restrict__ bpre, int nb)
{
    int t = threadIdx.x;                // single wave, nb <= 64
    int own = (t < nb) ? bsum[t] : 0;
    int v = own;
    for (int off = 1; off < 64; off <<= 1) {
        int x = __shfl_up(v, off);
        if (t >= off) v += x;
    }
    if (t < nb) bpre[t] = v - own;      // exclusive
}
__global__ void scan3_k(const int* __restrict__ incl, const int* __restrict__ deg,
                        const int* __restrict__ bpre, int* __restrict__ offs,
                        int Nn, int Etot)
{
    int i = blockIdx.x * 256 + threadIdx.x;
    if (i < Nn) {
        int e = bpre[i >> 10] + incl[i] - deg[i];
        offs[i] = e;
    }
    if (i == 0) offs[Nn] = Etot;
}

// ---------------- scatter: atomic-free (slot precomputed in prep) ----------------
__global__ __launch_bounds__(256) void scatter_k(const int* __restrict__ src,
    const int* __restrict__ dst, const int* __restrict__ slot,
    const int* __restrict__ offs, int E, int Etot, int* __restrict__ srcs)
{
    long base = (long)blockIdx.x * 1024;
    #pragma unroll
    for (int q = 0; q < 4; q++) {
        long i = base + q * 256 + threadIdx.x;
        if (i < E) {
            int d = dst[i];
            srcs[offs[d] + slot[i]] = src[i];       // offs is L2-resident (200 KB)
        } else if (i < Etot) {
            int n = (int)(i - E);
            srcs[offs[n] + slot[i]] = n;            // self loop
        }
    }
}

// ---------------- GAT layer 1 aggregate: wave per dst node ----------------
__global__ __launch_bounds__(256) void gat1_agg_k(const ushort_t* __restrict__ H1b,
    const float* __restrict__ as1, const float* __restrict__ ad1,
    const int* __restrict__ offs, const int* __restrict__ srcs,
    const float* __restrict__ b1, ushort_t* __restrict__ X1b, int Nn)
{
    int w = (blockIdx.x << 2) + (threadIdx.x >> 6);
    if (w >= Nn) return;
    int lane = threadIdx.x & 63;
    int he = lane & 7, el = lane >> 3;
    int myh = lane >> 3;
    int beg = offs[w], end = offs[w + 1];
    int deg = end - beg;
    float adv = ad1[(w << 3) + he];
    float4 acc = {0.f, 0.f, 0.f, 0.f};

    if (deg <= 64) {
        int sv0=0,sv1=0,sv2=0,sv3=0,sv4=0,sv5=0,sv6=0,sv7=0;
        float wv0=0,wv1=0,wv2=0,wv3=0,wv4=0,wv5=0,wv6=0,wv7=0;
        {
            int j;
            j = beg + el;      if (j < end){ sv0 = srcs[j]; wv0 = __expf(lrelu(as1[(sv0<<3)+he]+adv)); }
            j = beg + 8 + el;  if (j < end){ sv1 = srcs[j]; wv1 = __expf(lrelu(as1[(sv1<<3)+he]+adv)); }
            j = beg + 16 + el; if (j < end){ sv2 = srcs[j]; wv2 = __expf(lrelu(as1[(sv2<<3)+he]+adv)); }
            j = beg + 24 + el; if (j < end){ sv3 = srcs[j]; wv3 = __expf(lrelu(as1[(sv3<<3)+he]+adv)); }
            j = beg + 32 + el; if (j < end){ sv4 = srcs[j]; wv4 = __expf(lrelu(as1[(sv4<<3)+he]+adv)); }
            j = beg + 40 + el; if (j < end){ sv5 = srcs[j]; wv5 = __expf(lrelu(as1[(sv5<<3)+he]+adv)); }
            j = beg + 48 + el; if (j < end){ sv6 = srcs[j]; wv6 = __expf(lrelu(as1[(sv6<<3)+he]+adv)); }
            j = beg + 56 + el; if (j < end){ sv7 = srcs[j]; wv7 = __expf(lrelu(as1[(sv7<<3)+he]+adv)); }
        }
        float d = ((wv0 + wv1) + (wv2 + wv3)) + ((wv4 + wv5) + (wv6 + wv7));
        #pragma unroll
        for (int off = 8; off < 64; off <<= 1) d += __shfl_xor(d, off);
        float inv = 1.f / d;
        wv0 *= inv; wv1 *= inv; wv2 *= inv; wv3 *= inv;
        wv4 *= inv; wv5 *= inv; wv6 *= inv; wv7 *= inv;

        #define GAT1_BATCH(SV, WV, Q)                                            \
        {                                                                        \
            int ne = deg - (Q << 3);                                             \
            if (ne > 0) {                                                        \
                ne = min(ne, 8);                                                 \
                int sb[8]; float wb[8];                                          \
                _Pragma("unroll")                                                \
                for (int e8 = 0; e8 < 8; e8++) {                                 \
                    sb[e8] = __shfl(SV, e8 << 3);                                \
                    wb[e8] = __shfl(WV, (e8 << 3) + myh);                        \
                }                                                                \
                if (ne == 8) {                                                   \
                    _Pragma("unroll")                                            \
                    for (int e8 = 0; e8 < 8; e8++) {                             \
                        uint2 v = ((const uint2*)(H1b + ((long)sb[e8] << 8)))[lane]; \
                        acc.x += wb[e8] * bf_lo(v.x);                            \
                        acc.y += wb[e8] * bf_hi(v.x);                            \
                        acc.z += wb[e8] * bf_lo(v.y);                            \
                        acc.w += wb[e8] * bf_hi(v.y);                            \
                    }                                                            \
                } else {                                                         \
                    _Pragma("unroll")                                            \
                    for (int e8 = 0; e8 < 8; e8++) {                             \
                        if (e8 < ne) {                                           \
                            uint2 v = ((const uint2*)(H1b + ((long)sb[e8] << 8)))[lane]; \
                            acc.x += wb[e8] * bf_lo(v.x);                        \
                            acc.y += wb[e8] * bf_hi(v.x);                        \
                            acc.z += wb[e8] * bf_lo(v.y);                        \
                            acc.w += wb[e8] * bf_hi(v.y);                        \
                        }                                                        \
                    }                                                            \
                }                                                                \
            }                                                                    \
        }
        GAT1_BATCH(sv0, wv0, 0)
        GAT1_BATCH(sv1, wv1, 1)
        GAT1_BATCH(sv2, wv2, 2)
        GAT1_BATCH(sv3, wv3, 3)
        GAT1_BATCH(sv4, wv4, 4)
        GAT1_BATCH(sv5, wv5, 5)
        GAT1_BATCH(sv6, wv6, 6)
        GAT1_BATCH(sv7, wv7, 7)
        #undef GAT1_BATCH
    } else {
        float dA = 0.f, dB = 0.f;
        for (int j0 = beg; j0 < end; j0 += 16) {
            int j = j0 + el, jb = j0 + 8 + el;
            if (j < end)  dA += __expf(lrelu(as1[(srcs[j] << 3) + he] + adv));
            if (jb < end) dB += __expf(lrelu(as1[(srcs[jb] << 3) + he] + adv));
        }
        float d = dA + dB;
        #pragma unroll
        for (int off = 8; off < 64; off <<= 1) d += __shfl_xor(d, off);
        float inv = 1.f / d;
        for (int j0 = beg; j0 < end; j0 += 8) {
            int j = j0 + el;
            int s = 0; float wv = 0.f;
            if (j < end) {
                s = srcs[j];
                wv = __expf(lrelu(as1[(s << 3) + he] + adv)) * inv;
            }
            int ne = min(end - j0, 8);
            int sb[8]; float wb[8];
            #pragma unroll
            for (int e8 = 0; e8 < 8; e8++) {
                sb[e8] = __shfl(s, e8 << 3);
                wb[e8] = __shfl(wv, (e8 << 3) + myh);
            }
            #pragma unroll
            for (int e8 = 0; e8 < 8; e8++) {
                if (e8 < ne) {
                    uint2 v = ((const uint2*)(H1b + ((long)sb[e8] << 8)))[lane];
                    acc.x += wb[e8] * bf_lo(v.x);
                    acc.y += wb[e8] * bf_hi(v.x);
                    acc.z += wb[e8] * bf_lo(v.y);
                    acc.w += wb[e8] * bf_hi(v.y);
                }
            }
        }
    }

    float4 bb = ((const float4*)b1)[lane];
    float o0 = fmaxf(acc.x + bb.x, 0.f);
    float o1 = fmaxf(acc.y + bb.y, 0.f);
    float o2 = fmaxf(acc.z + bb.z, 0.f);
    float o3 = fmaxf(acc.w + bb.w, 0.f);
    uint2 ov;
    ov.x = (uint_t)f2bf(o0) | ((uint_t)f2bf(o1) << 16);
    ov.y = (uint_t)f2bf(o2) | ((uint_t)f2bf(o3) << 16);
    ((uint2*)(X1b + ((long)w << 8)))[lane] = ov;
}

// ---------------- GEMM2 (MFMA) + fused alpha2: h2 = x1b @ W2t^T ----------------
__global__ __launch_bounds__(256) void gemm2_k(const ushort_t* __restrict__ X1b,
    const ushort_t* __restrict__ W2t, const float* __restrict__ a2s_w,
    const float* __restrict__ a2d_w, float* __restrict__ H2,
    float* __restrict__ as2, float* __restrict__ ad2, int Nn)
{
    int wid = threadIdx.x >> 6, lane = threadIdx.x & 63;
    int row0 = blockIdx.x * 64 + wid * 16;
    if (row0 >= Nn) return;
    int lm = lane & 15, lg = lane >> 4;
    f32x4 acc = (f32x4){0.f, 0.f, 0.f, 0.f};
    const ushort_t* arow = X1b + (long)(row0 + lm) * 256 + lg * 8;
    const ushort_t* brow = W2t + lm * 256 + lg * 8;
    #pragma unroll
    for (int k0 = 0; k0 < 256; k0 += 32) {
        short8 af = *(const short8*)(arow + k0);
        short8 bf = *(const short8*)(brow + k0);
        acc = __builtin_amdgcn_mfma_f32_16x16x32_bf16(af, bf, acc, 0, 0, 0);
    }
    float a2sv = a2s_w[lm], a2dv = a2d_w[lm];
    #pragma unroll
    for (int r = 0; r < 4; r++) {
        int grow = row0 + lg * 4 + r;
        if (grow < Nn) H2[(grow << 4) + lm] = acc[r];
        float s = acc[r] * a2sv, d2 = acc[r] * a2dv;
        #pragma unroll
        for (int off = 1; off < 16; off <<= 1) {
            s += __shfl_xor(s, off);
            d2 += __shfl_xor(d2, off);
        }
        if (lm == 0 && grow < Nn) { as2[grow] = s; ad2[grow] = d2; }
    }
}

// ---------------- GAT layer 2 aggregate + final softmax (weight-cached) ----------------
__global__ __launch_bounds__(256) void gat2_agg_k(const float* __restrict__ H2,
    const float* __restrict__ as2, const float* __restrict__ ad2,
    const int* __restrict__ offs, const int* __restrict__ srcs,
    const float* __restrict__ b2, float* __restrict__ out, int Nn)
{
    int w = (blockIdx.x << 2) + (threadIdx.x >> 6);
    if (w >= Nn) return;
    int lane = threadIdx.x & 63;
    int beg = offs[w], end = offs[w + 1];
    int deg = end - beg;
    float adv = ad2[w];
    int c = lane & 15, eg = lane >> 4;
    float acc = 0.f;

    if (deg <= 64) {
        int j = beg + lane;
        int s_l = 0; float w_l = 0.f;
        if (j < end) { s_l = srcs[j]; w_l = __expf(lrelu(as2[s_l] + adv)); }
        float d = w_l;
        #pragma unroll
        for (int off = 1; off < 64; off <<= 1) d += __shfl_xor(d, off);
        float w_n = w_l / d;
        for (int j0 = 0; j0 < deg; j0 += 4) {
            int jj = j0 + eg;
            int s = __shfl(s_l, jj);
            float wv = __shfl(w_n, jj);
            if (jj < deg)
                acc += wv * H2[(s << 4) + c];
        }
    } else {
        float d = 0.f;
        for (int j = beg + lane; j < end; j += 64)
            d += __expf(lrelu(as2[srcs[j]] + adv));
        #pragma unroll
        for (int off = 1; off < 64; off <<= 1) d += __shfl_xor(d, off);
        float inv = 1.f / d;
        for (int j0 = beg; j0 < end; j0 += 4) {
            int j = j0 + eg;
            if (j < end) {
                int s = srcs[j];
                float wv = __expf(lrelu(as2[s] + adv)) * inv;
                acc += wv * H2[(s << 4) + c];
            }
        }
    }
    acc += __shfl_xor(acc, 16);
    acc += __shfl_xor(acc, 32);
    float v = acc + b2[c];
    float mx = v;
    #pragma unroll
    for (int off = 1; off < 16; off <<= 1) mx = fmaxf(mx, __shfl_xor(mx, off));
    float ex = __expf(v - mx);
    float se = ex;
    #pragma unroll
    for (int off = 1; off < 16; off <<= 1) se += __shfl_xor(se, off);
    if (eg == 0) out[(w << 4) + c] = ex / se;
}

// ---------------- host launcher ----------------
extern "C" void kernel_launch(void* const* d_in, const int* in_sizes, int n_in,
                              void* d_out, int out_size, void* d_ws, size_t ws_size,
                              hipStream_t stream)
{
    const float* x    = (const float*)d_in[0];
    const int*   ei   = (const int*)d_in[1];
    const float* W1   = (const float*)d_in[2];
    const float* a1s  = (const float*)d_in[3];
    const float* a1d  = (const float*)d_in[4];
    const float* b1   = (const float*)d_in[5];
    const float* W2   = (const float*)d_in[6];
    const float* a2s  = (const float*)d_in[7];
    const float* a2d  = (const float*)d_in[8];
    const float* b2   = (const float*)d_in[9];
    float* out = (float*)d_out;

    int N = in_sizes[0] / HID;
    int E = in_sizes[1] / 2;
    int Etot = E + N;
    const int* src = ei;
    const int* dst = ei + E;

    char* p = (char*)d_ws;
    auto alloc = [&](size_t bytes) {
        void* r = (void*)p;
        p += (bytes + 255) & ~(size_t)255;
        return r;
    };
    ushort_t* xbf  = (ushort_t*)alloc((size_t)N * 256 * 2);
    ushort_t* h1b  = (ushort_t*)alloc((size_t)N * 256 * 2);
    ushort_t* x1b  = (ushort_t*)alloc((size_t)N * 256 * 2);
    ushort_t* w1t  = (ushort_t*)alloc((size_t)256 * 256 * 2);
    ushort_t* w2t  = (ushort_t*)alloc((size_t)16 * 256 * 2);
    float* h2      = (float*)alloc((size_t)N * 16 * 4);
    float* as1     = (float*)alloc((size_t)N * 8 * 4);
    float* ad1     = (float*)alloc((size_t)N * 8 * 4);
    float* as2v    = (float*)alloc((size_t)N * 4);
    float* ad2v    = (float*)alloc((size_t)N * 4);
    int*   deg     = (int*)alloc((size_t)N * 4);
    int*   incl    = (int*)alloc((size_t)N * 4);
    int*   offs    = (int*)alloc((size_t)(N + 1) * 4);
    int*   bsum    = (int*)alloc(256 * 4);
    int*   bpre    = (int*)alloc(256 * 4);
    int*   srcs    = (int*)alloc((size_t)Etot * 4);
    int*   slot    = (int*)alloc((size_t)Etot * 4);

    int nb = (N + 1023) / 1024;
    int cnt_blocks = (Etot + 255) / 256;
    int scat_blocks = (Etot + 1023) / 1024;

    // zero deg, then merged prep (W1t | W2t | Xbf | deg_count+slot)
    hipMemsetAsync(deg, 0, (size_t)N * 4, stream);
    hipLaunchKernelGGL(prep_k, dim3(65 + 2048 + cnt_blocks), dim3(256), 0, stream,
                       x, xbf, (long)N * 64, W1, w1t, W2, w2t, dst, E, Etot, deg, slot);
    // CSR scans
    hipLaunchKernelGGL(scan1_k, dim3(nb), dim3(256), 0, stream, deg, incl, bsum, N);
    hipLaunchKernelGGL(scan2_k, dim3(1), dim3(64), 0, stream, bsum, bpre, nb);
    hipLaunchKernelGGL(scan3_k, dim3((N + 255) / 256), dim3(256), 0, stream,
                       incl, deg, bpre, offs, N, Etot);
    // atomic-free scatter
    hipLaunchKernelGGL(scatter_k, dim3(scat_blocks), dim3(256), 0, stream,
                       src, dst, slot, offs, E, Etot, srcs);
    // GEMM1 (MFMA, async-staged, 64x128 tile, fused alpha1)
    dim3 g1(2, (N + 63) / 64);
    hipLaunchKernelGGL(gemm1_k, g1, dim3(256), 0, stream,
                       xbf, w1t, a1s, a1d, h1b, as1, ad1, N);
    // layer 1 aggregate
    hipLaunchKernelGGL(gat1_agg_k, dim3((N + 3) / 4), dim3(256), 0, stream,
                       h1b, as1, ad1, offs, srcs, b1, x1b, N);
    // layer 2: MFMA gemm2 + aggregate
    hipLaunchKernelGGL(gemm2_k, dim3((N + 63) / 64), dim3(256), 0, stream,
                       x1b, w2t, a2s, a2d, h2, as2v, ad2v, N);
    hipLaunchKernelGGL(gat2_agg_k, dim3((N + 3) / 4), dim3(256), 0, stream,
                       h2, as2v, ad2v, offs, srcs, b2, out, N);
}

// Round 17
// 190.162 us; speedup vs baseline: 1.2543x; 1.0844x over previous
//
#include <hip/hip_runtime.h>
#include <hip/hip_bf16.h>

#define HID 256
#define H1H 8
#define C1 32
#define C2 16
#define NEG 0.2f

typedef unsigned short ushort_t;
typedef unsigned int uint_t;
typedef unsigned char uchar_t;
typedef __attribute__((ext_vector_type(8))) short short8;
typedef __attribute__((ext_vector_type(4))) float f32x4;
typedef __attribute__((ext_vector_type(2))) float f32x2;

__device__ __forceinline__ float lrelu(float t){ return (t >= 0.f) ? t : NEG * t; }
__device__ __forceinline__ ushort_t f2bf(float f){
    uint_t u = __float_as_uint(f);
    u = (u + 0x7fffu + ((u >> 16) & 1u)) >> 16;   // RNE
    return (ushort_t)u;
}
__device__ __forceinline__ float bf_lo(uint_t p){ return __uint_as_float(p << 16); }
__device__ __forceinline__ float bf_hi(uint_t p){ return __uint_as_float(p & 0xffff0000u); }
__device__ __forceinline__ uchar_t f2fp8(float f){
    int r = __builtin_amdgcn_cvt_pk_fp8_f32(f, f, 0, false);   // OCP e4m3, RNE
    return (uchar_t)(r & 0xFF);
}

#define GLOAD_LDS16(g, l) \
    __builtin_amdgcn_global_load_lds( \
        (const __attribute__((address_space(1))) void*)(g), \
        (__attribute__((address_space(3))) void*)(l), 16, 0, 0)

// ---------------- prep (merged): W1t | W2t | Xbf stream | deg_count + slot ----------------
// deg must be zeroed (hipMemsetAsync) BEFORE this kernel.
__global__ __launch_bounds__(256) void prep_k(const float* __restrict__ X,
                                              ushort_t* __restrict__ Xbf, long n4,
                                              const float* __restrict__ W1,
                                              ushort_t* __restrict__ W1t,
                                              const float* __restrict__ W2,
                                              ushort_t* __restrict__ W2t,
                                              const int* __restrict__ dst,
                                              int E, int Etot, int* __restrict__ deg,
                                              int* __restrict__ slot)
{
    int bid = blockIdx.x;
    if (bid < 64) {
        __shared__ ushort_t sh[32][33];
        int bx = bid & 7, by = bid >> 3;                  // k-tile, n-tile
        int tx = threadIdx.x & 31, ty = threadIdx.x >> 5; // 32 x 8
        #pragma unroll
        for (int i = 0; i < 32; i += 8)
            sh[ty + i][tx] = f2bf(W1[(long)(bx * 32 + ty + i) * 256 + by * 32 + tx]);
        __syncthreads();
        #pragma unroll
        for (int i = 0; i < 32; i += 8)
            W1t[(long)(by * 32 + ty + i) * 256 + bx * 32 + tx] = sh[tx][ty + i];
    } else if (bid == 64) {
        // W2t[c][k] = bf16(W2[k][c]); 4096 elems
        for (int idx = threadIdx.x; idx < 4096; idx += 256) {
            int k = idx >> 4, c = idx & 15;
            W2t[c * 256 + k] = f2bf(W2[idx]);
        }
    } else if (bid < 65 + 2048) {
        long stride = (long)2048 * 256;
        for (long i = (long)(bid - 65) * 256 + threadIdx.x; i < n4; i += stride) {
            float4 v = ((const float4*)X)[i];
            ushort4 o;
            o.x = f2bf(fmaxf(v.x, 0.f)); o.y = f2bf(fmaxf(v.y, 0.f));
            o.z = f2bf(fmaxf(v.z, 0.f)); o.w = f2bf(fmaxf(v.w, 0.f));
            ((ushort4*)Xbf)[i] = o;
        }
    } else {
        int i = (bid - 65 - 2048) * 256 + threadIdx.x;
        if (i < E) {
            int p = atomicAdd(&deg[dst[i]], 1);
            slot[i] = p;                                  // within-node slot index
        } else if (i < Etot) {
            int p = atomicAdd(&deg[i - E], 1);            // self loop
            slot[i] = p;
        }
    }
}

// ---------------- GEMM1 (MFMA, async-staged, 64x128 tile): h1f8 = fp8( relu(x) @ W1 ) + alpha1 ----
__global__ __launch_bounds__(256) void gemm1_k(const ushort_t* __restrict__ Xbf,
                                               const ushort_t* __restrict__ W1t,
                                               const float* __restrict__ a1s_g,
                                               const float* __restrict__ a1d_g,
                                               uchar_t* __restrict__ H1f8,
                                               float* __restrict__ as1,
                                               float* __restrict__ ad1, int M)
{
    __shared__ ushort_t Abuf[64 * 64];    // 8 KiB: 64 rows x 8 chunks, chunk-swizzled
    __shared__ ushort_t Bbuf[128 * 64];   // 16 KiB: 128 cols x 8 chunks
    int tid = threadIdx.x;
    int bm = blockIdx.y * 64, bn = blockIdx.x * 128;
    int wid = tid >> 6, lane = tid & 63;
    int wr = wid >> 1, wc = wid & 1;
    int lg = lane >> 4, lm = lane & 15;

    f32x4 acc[2][4];
    #pragma unroll
    for (int m = 0; m < 2; m++)
        #pragma unroll
        for (int n = 0; n < 4; n++) acc[m][n] = (f32x4){0.f, 0.f, 0.f, 0.f};

    int rA[2], lcA[2];
    #pragma unroll
    for (int q = 0; q < 2; q++) {
        int idx = q * 256 + tid;
        rA[q] = idx >> 3;
        lcA[q] = (idx & 7) ^ (rA[q] & 7);
    }
    int rB[4], lcB[4];
    #pragma unroll
    for (int q = 0; q < 4; q++) {
        int idx = q * 256 + tid;
        rB[q] = idx >> 3;
        lcB[q] = (idx & 7) ^ (rB[q] & 7);
    }

    for (int k0 = 0; k0 < 256; k0 += 64) {
        __syncthreads();
        #pragma unroll
        for (int q = 0; q < 2; q++) {
            const ushort_t* asrc = Xbf + (long)(bm + rA[q]) * 256 + k0 + lcA[q] * 8;
            GLOAD_LDS16(asrc, Abuf + (q * 256 + wid * 64) * 8);
        }
        #pragma unroll
        for (int q = 0; q < 4; q++) {
            const ushort_t* bsrc = W1t + (long)(bn + rB[q]) * 256 + k0 + lcB[q] * 8;
            GLOAD_LDS16(bsrc, Bbuf + (q * 256 + wid * 64) * 8);
        }
        __syncthreads();
        #pragma unroll
        for (int ks = 0; ks < 2; ks++) {
            int kg = ks * 4 + lg;
            short8 af[2], bfr[4];
            #pragma unroll
            for (int m = 0; m < 2; m++) {
                int R = wr * 32 + m * 16 + lm;
                af[m] = *(const short8*)&Abuf[(R * 8 + (kg ^ (R & 7))) * 8];
            }
            #pragma unroll
            for (int n = 0; n < 4; n++) {
                int Cc = wc * 64 + n * 16 + lm;
                bfr[n] = *(const short8*)&Bbuf[(Cc * 8 + (kg ^ (Cc & 7))) * 8];
            }
            #pragma unroll
            for (int m = 0; m < 2; m++)
                #pragma unroll
                for (int n = 0; n < 4; n++)
                    acc[m][n] = __builtin_amdgcn_mfma_f32_16x16x32_bf16(af[m], bfr[n], acc[m][n], 0, 0, 0);
        }
    }

    // fused alpha1 (fp32 accumulators -> full precision dots)
    int h0 = ((bn >> 5) + (wc << 1));
    float as_l0 = a1s_g[h0 * 32 + lm],       as_h0 = a1s_g[h0 * 32 + 16 + lm];
    float as_l1 = a1s_g[(h0 + 1) * 32 + lm], as_h1 = a1s_g[(h0 + 1) * 32 + 16 + lm];
    float ad_l0 = a1d_g[h0 * 32 + lm],       ad_h0 = a1d_g[h0 * 32 + 16 + lm];
    float ad_l1 = a1d_g[(h0 + 1) * 32 + lm], ad_h1 = a1d_g[(h0 + 1) * 32 + 16 + lm];

    #pragma unroll
    for (int m = 0; m < 2; m++) {
        #pragma unroll
        for (int r = 0; r < 4; r++) {
            int gm = bm + wr * 32 + m * 16 + lg * 4 + r;
            float s0 = acc[m][0][r] * as_l0 + acc[m][1][r] * as_h0;
            float s1 = acc[m][2][r] * as_l1 + acc[m][3][r] * as_h1;
            float d0 = acc[m][0][r] * ad_l0 + acc[m][1][r] * ad_h0;
            float d1 = acc[m][2][r] * ad_l1 + acc[m][3][r] * ad_h1;
            #pragma unroll
            for (int off = 1; off < 16; off <<= 1) {
                s0 += __shfl_xor(s0, off);
                s1 += __shfl_xor(s1, off);
                d0 += __shfl_xor(d0, off);
                d1 += __shfl_xor(d1, off);
            }
            if (gm < M) {
                uchar_t* basep = H1f8 + (long)gm * 256 + bn + wc * 64 + lm;
                #pragma unroll
                for (int n = 0; n < 4; n++)
                    basep[n * 16] = f2fp8(acc[m][n][r]);
                if (lm == 0) {
                    float2 sv = {s0, s1}, dv = {d0, d1};
                    *(float2*)&as1[(gm << 3) + h0] = sv;
                    *(float2*)&ad1[(gm << 3) + h0] = dv;
                }
            }
        }
    }
}

// ---------------- CSR scans ----------------
__global__ __launch_bounds__(256) void scan1_k(const int* __restrict__ deg,
                                               int* __restrict__ incl,
                                               int* __restrict__ bsum, int Nn)
{
    __shared__ int sh[256];
    int t = threadIdx.x;
    int base = blockIdx.x * 1024 + t * 4;
    int v0 = (base     < Nn) ? deg[base]     : 0;
    int v1 = (base + 1 < Nn) ? deg[base + 1] : 0;
    int v2 = (base + 2 < Nn) ? deg[base + 2] : 0;
    int v3 = (base + 3 < Nn) ? deg[base + 3] : 0;
    int s0 = v0, s1 = s0 + v1, s2 = s1 + v2, s3 = s2 + v3;
    sh[t] = s3;
    __syncthreads();
    for (int off = 1; off < 256; off <<= 1) {
        int x = (t >= off) ? sh[t - off] : 0;
        __syncthreads();
        sh[t] += x;
        __syncthreads();
    }
    int prev = (t > 0) ? sh[t - 1] : 0;
    if (base     < Nn) incl[base]     = prev + s0;
    if (base + 1 < Nn) incl[base + 1] = prev + s1;
    if (base + 2 < Nn) incl[base + 2] = prev + s2;
    if (base + 3 < Nn) incl[base + 3] = prev + s3;
    if (t == 255) bsum[blockIdx.x] = sh[255];
}
__global__ void scan2_k(const int* __restrict__ bsum, int* __restrict__ bpre, int nb)
{
    int t = threadIdx.x;                // single wave, nb <= 64
    int own = (t < nb) ? bsum[t] : 0;
    int v = own;
    for (int off = 1; off < 64; off <<= 1) {
        int x = __shfl_up(v, off);
        if (t >= off) v += x;
    }
    if (t < nb) bpre[t] = v - own;      // exclusive
}
__global__ void scan3_k(const int* __restrict__ incl, const int* __restrict__ deg,
                        const int* __restrict__ bpre, int* __restrict__ offs,
                        int Nn, int Etot)
{
    int i = blockIdx.x * 256 + threadIdx.x;
    if (i < Nn) {
        int e = bpre[i >> 10] + incl[i] - deg[i];
        offs[i] = e;
    }
    if (i == 0) offs[Nn] = Etot;
}

// ---------------- scatter: atomic-free (slot precomputed in prep) ----------------
__global__ __launch_bounds__(256) void scatter_k(const int* __restrict__ src,
    const int* __restrict__ dst, const int* __restrict__ slot,
    const int* __restrict__ offs, int E, int Etot, int* __restrict__ srcs)
{
    long base = (long)blockIdx.x * 1024;
    #pragma unroll
    for (int q = 0; q < 4; q++) {
        long i = base + q * 256 + threadIdx.x;
        if (i < E) {
            int d = dst[i];
            srcs[offs[d] + slot[i]] = src[i];       // offs is L2-resident (200 KB)
        } else if (i < Etot) {
            int n = (int)(i - E);
            srcs[offs[n] + slot[i]] = n;            // self loop
        }
    }
}

// ---------------- GAT layer 1 aggregate: wave per dst node (fp8 gather, 256B rows) ----------------
__global__ __launch_bounds__(256) void gat1_agg_k(const uchar_t* __restrict__ H1f8,
    const float* __restrict__ as1, const float* __restrict__ ad1,
    const int* __restrict__ offs, const int* __restrict__ srcs,
    const float* __restrict__ b1, ushort_t* __restrict__ X1b, int Nn)
{
    int w = (blockIdx.x << 2) + (threadIdx.x >> 6);
    if (w >= Nn) return;
    int lane = threadIdx.x & 63;
    int he = lane & 7, el = lane >> 3;
    int myh = lane >> 3;
    int beg = offs[w], end = offs[w + 1];
    int deg = end - beg;
    float adv = ad1[(w << 3) + he];
    float4 acc = {0.f, 0.f, 0.f, 0.f};

    if (deg <= 64) {
        int sv0=0,sv1=0,sv2=0,sv3=0,sv4=0,sv5=0,sv6=0,sv7=0;
        float wv0=0,wv1=0,wv2=0,wv3=0,wv4=0,wv5=0,wv6=0,wv7=0;
        {
            int j;
            j = beg + el;      if (j < end){ sv0 = srcs[j]; wv0 = __expf(lrelu(as1[(sv0<<3)+he]+adv)); }
            j = beg + 8 + el;  if (j < end){ sv1 = srcs[j]; wv1 = __expf(lrelu(as1[(sv1<<3)+he]+adv)); }
            j = beg + 16 + el; if (j < end){ sv2 = srcs[j]; wv2 = __expf(lrelu(as1[(sv2<<3)+he]+adv)); }
            j = beg + 24 + el; if (j < end){ sv3 = srcs[j]; wv3 = __expf(lrelu(as1[(sv3<<3)+he]+adv)); }
            j = beg + 32 + el; if (j < end){ sv4 = srcs[j]; wv4 = __expf(lrelu(as1[(sv4<<3)+he]+adv)); }
            j = beg + 40 + el; if (j < end){ sv5 = srcs[j]; wv5 = __expf(lrelu(as1[(sv5<<3)+he]+adv)); }
            j = beg + 48 + el; if (j < end){ sv6 = srcs[j]; wv6 = __expf(lrelu(as1[(sv6<<3)+he]+adv)); }
            j = beg + 56 + el; if (j < end){ sv7 = srcs[j]; wv7 = __expf(lrelu(as1[(sv7<<3)+he]+adv)); }
        }
        float d = ((wv0 + wv1) + (wv2 + wv3)) + ((wv4 + wv5) + (wv6 + wv7));
        #pragma unroll
        for (int off = 8; off < 64; off <<= 1) d += __shfl_xor(d, off);
        float inv = 1.f / d;
        // normalize on the OWNING lane BEFORE broadcast
        wv0 *= inv; wv1 *= inv; wv2 *= inv; wv3 *= inv;
        wv4 *= inv; wv5 *= inv; wv6 *= inv; wv7 *= inv;

        #define GAT1_BATCH(SV, WV, Q)                                            \
        {                                                                        \
            int ne = deg - (Q << 3);                                             \
            if (ne > 0) {                                                        \
                ne = min(ne, 8);                                                 \
                int sb[8]; float wb[8];                                          \
                _Pragma("unroll")                                                \
                for (int e8 = 0; e8 < 8; e8++) {                                 \
                    sb[e8] = __shfl(SV, e8 << 3);                                \
                    wb[e8] = __shfl(WV, (e8 << 3) + myh);                        \
                }                                                                \
                if (ne == 8) {                                                   \
                    _Pragma("unroll")                                            \
                    for (int e8 = 0; e8 < 8; e8++) {                             \
                        uint_t v = ((const uint_t*)(H1f8 + ((long)sb[e8] << 8)))[lane]; \
                        f32x2 lo = __builtin_amdgcn_cvt_pk_f32_fp8((int)v, false); \
                        f32x2 hi = __builtin_amdgcn_cvt_pk_f32_fp8((int)v, true);  \
                        acc.x += wb[e8] * lo[0];                                 \
                        acc.y += wb[e8] * lo[1];                                 \
                        acc.z += wb[e8] * hi[0];                                 \
                        acc.w += wb[e8] * hi[1];                                 \
                    }                                                            \
                } else {                                                         \
                    _Pragma("unroll")                                            \
                    for (int e8 = 0; e8 < 8; e8++) {                             \
                        if (e8 < ne) {                                           \
                            uint_t v = ((const uint_t*)(H1f8 + ((long)sb[e8] << 8)))[lane]; \
                            f32x2 lo = __builtin_amdgcn_cvt_pk_f32_fp8((int)v, false); \
                            f32x2 hi = __builtin_amdgcn_cvt_pk_f32_fp8((int)v, true);  \
                            acc.x += wb[e8] * lo[0];                             \
                            acc.y += wb[e8] * lo[1];                             \
                            acc.z += wb[e8] * hi[0];                             \
                            acc.w += wb[e8] * hi[1];                             \
                        }                                                        \
                    }                                                            \
                }                                                                \
            }                                                                    \
        }
        GAT1_BATCH(sv0, wv0, 0)
        GAT1_BATCH(sv1, wv1, 1)
        GAT1_BATCH(sv2, wv2, 2)
        GAT1_BATCH(sv3, wv3, 3)
        GAT1_BATCH(sv4, wv4, 4)
        GAT1_BATCH(sv5, wv5, 5)
        GAT1_BATCH(sv6, wv6, 6)
        GAT1_BATCH(sv7, wv7, 7)
        #undef GAT1_BATCH
    } else {
        float dA = 0.f, dB = 0.f;
        for (int j0 = beg; j0 < end; j0 += 16) {
            int j = j0 + el, jb = j0 + 8 + el;
            if (j < end)  dA += __expf(lrelu(as1[(srcs[j] << 3) + he] + adv));
            if (jb < end) dB += __expf(lrelu(as1[(srcs[jb] << 3) + he] + adv));
        }
        float d = dA + dB;
        #pragma unroll
        for (int off = 8; off < 64; off <<= 1) d += __shfl_xor(d, off);
        float inv = 1.f / d;
        for (int j0 = beg; j0 < end; j0 += 8) {
            int j = j0 + el;
            int s = 0; float wv = 0.f;
            if (j < end) {
                s = srcs[j];
                wv = __expf(lrelu(as1[(s << 3) + he] + adv)) * inv;
            }
            int ne = min(end - j0, 8);
            int sb[8]; float wb[8];
            #pragma unroll
            for (int e8 = 0; e8 < 8; e8++) {
                sb[e8] = __shfl(s, e8 << 3);
                wb[e8] = __shfl(wv, (e8 << 3) + myh);
            }
            #pragma unroll
            for (int e8 = 0; e8 < 8; e8++) {
                if (e8 < ne) {
                    uint_t v = ((const uint_t*)(H1f8 + ((long)sb[e8] << 8)))[lane];
                    f32x2 lo = __builtin_amdgcn_cvt_pk_f32_fp8((int)v, false);
                    f32x2 hi = __builtin_amdgcn_cvt_pk_f32_fp8((int)v, true);
                    acc.x += wb[e8] * lo[0];
                    acc.y += wb[e8] * lo[1];
                    acc.z += wb[e8] * hi[0];
                    acc.w += wb[e8] * hi[1];
                }
            }
        }
    }

    float4 bb = ((const float4*)b1)[lane];
    float o0 = fmaxf(acc.x + bb.x, 0.f);
    float o1 = fmaxf(acc.y + bb.y, 0.f);
    float o2 = fmaxf(acc.z + bb.z, 0.f);
    float o3 = fmaxf(acc.w + bb.w, 0.f);
    uint2 ov;
    ov.x = (uint_t)f2bf(o0) | ((uint_t)f2bf(o1) << 16);
    ov.y = (uint_t)f2bf(o2) | ((uint_t)f2bf(o3) << 16);
    ((uint2*)(X1b + ((long)w << 8)))[lane] = ov;
}

// ---------------- GEMM2 (MFMA) + fused alpha2: h2 = x1b @ W2t^T ----------------
__global__ __launch_bounds__(256) void gemm2_k(const ushort_t* __restrict__ X1b,
    const ushort_t* __restrict__ W2t, const float* __restrict__ a2s_w,
    const float* __restrict__ a2d_w, float* __restrict__ H2,
    float* __restrict__ as2, float* __restrict__ ad2, int Nn)
{
    int wid = threadIdx.x >> 6, lane = threadIdx.x & 63;
    int row0 = blockIdx.x * 64 + wid * 16;
    if (row0 >= Nn) return;
    int lm = lane & 15, lg = lane >> 4;
    f32x4 acc = (f32x4){0.f, 0.f, 0.f, 0.f};
    const ushort_t* arow = X1b + (long)(row0 + lm) * 256 + lg * 8;
    const ushort_t* brow = W2t + lm * 256 + lg * 8;
    #pragma unroll
    for (int k0 = 0; k0 < 256; k0 += 32) {
        short8 af = *(const short8*)(arow + k0);
        short8 bf = *(const short8*)(brow + k0);
        acc = __builtin_amdgcn_mfma_f32_16x16x32_bf16(af, bf, acc, 0, 0, 0);
    }
    float a2sv = a2s_w[lm], a2dv = a2d_w[lm];
    #pragma unroll
    for (int r = 0; r < 4; r++) {
        int grow = row0 + lg * 4 + r;
        if (grow < Nn) H2[(grow << 4) + lm] = acc[r];
        float s = acc[r] * a2sv, d2 = acc[r] * a2dv;
        #pragma unroll
        for (int off = 1; off < 16; off <<= 1) {
            s += __shfl_xor(s, off);
            d2 += __shfl_xor(d2, off);
        }
        if (lm == 0 && grow < Nn) { as2[grow] = s; ad2[grow] = d2; }
    }
}

// ---------------- GAT layer 2 aggregate + final softmax (weight-cached) ----------------
__global__ __launch_bounds__(256) void gat2_agg_k(const float* __restrict__ H2,
    const float* __restrict__ as2, const float* __restrict__ ad2,
    const int* __restrict__ offs, const int* __restrict__ srcs,
    const float* __restrict__ b2, float* __restrict__ out, int Nn)
{
    int w = (blockIdx.x << 2) + (threadIdx.x >> 6);
    if (w >= Nn) return;
    int lane = threadIdx.x & 63;
    int beg = offs[w], end = offs[w + 1];
    int deg = end - beg;
    float adv = ad2[w];
    int c = lane & 15, eg = lane >> 4;
    float acc = 0.f;

    if (deg <= 64) {
        int j = beg + lane;
        int s_l = 0; float w_l = 0.f;
        if (j < end) { s_l = srcs[j]; w_l = __expf(lrelu(as2[s_l] + adv)); }
        float d = w_l;
        #pragma unroll
        for (int off = 1; off < 64; off <<= 1) d += __shfl_xor(d, off);
        float w_n = w_l / d;
        for (int j0 = 0; j0 < deg; j0 += 4) {
            int jj = j0 + eg;
            int s = __shfl(s_l, jj);
            float wv = __shfl(w_n, jj);
            if (jj < deg)
                acc += wv * H2[(s << 4) + c];
        }
    } else {
        float d = 0.f;
        for (int j = beg + lane; j < end; j += 64)
            d += __expf(lrelu(as2[srcs[j]] + adv));
        #pragma unroll
        for (int off = 1; off < 64; off <<= 1) d += __shfl_xor(d, off);
        float inv = 1.f / d;
        for (int j0 = beg; j0 < end; j0 += 4) {
            int j = j0 + eg;
            if (j < end) {
                int s = srcs[j];
                float wv = __expf(lrelu(as2[s] + adv)) * inv;
                acc += wv * H2[(s << 4) + c];
            }
        }
    }
    acc += __shfl_xor(acc, 16);
    acc += __shfl_xor(acc, 32);
    float v = acc + b2[c];
    float mx = v;
    #pragma unroll
    for (int off = 1; off < 16; off <<= 1) mx = fmaxf(mx, __shfl_xor(mx, off));
    float ex = __expf(v - mx);
    float se = ex;
    #pragma unroll
    for (int off = 1; off < 16; off <<= 1) se += __shfl_xor(se, off);
    if (eg == 0) out[(w << 4) + c] = ex / se;
}

// ---------------- host launcher ----------------
extern "C" void kernel_launch(void* const* d_in, const int* in_sizes, int n_in,
                              void* d_out, int out_size, void* d_ws, size_t ws_size,
                              hipStream_t stream)
{
    const float* x    = (const float*)d_in[0];
    const int*   ei   = (const int*)d_in[1];
    const float* W1   = (const float*)d_in[2];
    const float* a1s  = (const float*)d_in[3];
    const float* a1d  = (const float*)d_in[4];
    const float* b1   = (const float*)d_in[5];
    const float* W2   = (const float*)d_in[6];
    const float* a2s  = (const float*)d_in[7];
    const float* a2d  = (const float*)d_in[8];
    const float* b2   = (const float*)d_in[9];
    float* out = (float*)d_out;

    int N = in_sizes[0] / HID;
    int E = in_sizes[1] / 2;
    int Etot = E + N;
    const int* src = ei;
    const int* dst = ei + E;

    char* p = (char*)d_ws;
    auto alloc = [&](size_t bytes) {
        void* r = (void*)p;
        p += (bytes + 255) & ~(size_t)255;
        return r;
    };
    ushort_t* xbf  = (ushort_t*)alloc((size_t)N * 256 * 2);
    uchar_t*  h1f8 = (uchar_t*)alloc((size_t)N * 256);
    ushort_t* x1b  = (ushort_t*)alloc((size_t)N * 256 * 2);
    ushort_t* w1t  = (ushort_t*)alloc((size_t)256 * 256 * 2);
    ushort_t* w2t  = (ushort_t*)alloc((size_t)16 * 256 * 2);
    float* h2      = (float*)alloc((size_t)N * 16 * 4);
    float* as1     = (float*)alloc((size_t)N * 8 * 4);
    float* ad1     = (float*)alloc((size_t)N * 8 * 4);
    float* as2v    = (float*)alloc((size_t)N * 4);
    float* ad2v    = (float*)alloc((size_t)N * 4);
    int*   deg     = (int*)alloc((size_t)N * 4);
    int*   incl    = (int*)alloc((size_t)N * 4);
    int*   offs    = (int*)alloc((size_t)(N + 1) * 4);
    int*   bsum    = (int*)alloc(256 * 4);
    int*   bpre    = (int*)alloc(256 * 4);
    int*   srcs    = (int*)alloc((size_t)Etot * 4);
    int*   slot    = (int*)alloc((size_t)Etot * 4);

    int nb = (N + 1023) / 1024;
    int cnt_blocks = (Etot + 255) / 256;
    int scat_blocks = (Etot + 1023) / 1024;

    // zero deg, then merged prep (W1t | W2t | Xbf | deg_count+slot)
    hipMemsetAsync(deg, 0, (size_t)N * 4, stream);
    hipLaunchKernelGGL(prep_k, dim3(65 + 2048 + cnt_blocks), dim3(256), 0, stream,
                       x, xbf, (long)N * 64, W1, w1t, W2, w2t, dst, E, Etot, deg, slot);
    // CSR scans
    hipLaunchKernelGGL(scan1_k, dim3(nb), dim3(256), 0, stream, deg, incl, bsum, N);
    hipLaunchKernelGGL(scan2_k, dim3(1), dim3(64), 0, stream, bsum, bpre, nb);
    hipLaunchKernelGGL(scan3_k, dim3((N + 255) / 256), dim3(256), 0, stream,
                       incl, deg, bpre, offs, N, Etot);
    // atomic-free scatter
    hipLaunchKernelGGL(scatter_k, dim3(scat_blocks), dim3(256), 0, stream,
                       src, dst, slot, offs, E, Etot, srcs);
    // GEMM1 (MFMA, async-staged, 64x128 tile, fused alpha1, fp8 h1 out)
    dim3 g1(2, (N + 63) / 64);
    hipLaunchKernelGGL(gemm1_k, g1, dim3(256), 0, stream,
                       xbf, w1t, a1s, a1d, h1f8, as1, ad1, N);
    // layer 1 aggregate (fp8 gather)
    hipLaunchKernelGGL(gat1_agg_k, dim3((N + 3) / 4), dim3(256), 0, stream,
                       h1f8, as1, ad1, offs, srcs, b1, x1b, N);
    // layer 2: MFMA gemm2 + aggregate
    hipLaunchKernelGGL(gemm2_k, dim3((N + 63) / 64), dim3(256), 0, stream,
                       x1b, w2t, a2s, a2d, h2, as2v, ad2v, N);
    hipLaunchKernelGGL(gat2_agg_k, dim3((N + 3) / 4), dim3(256), 0, stream,
                       h2, as2v, ad2v, offs, srcs, b2, out, N);
}

// Round 18
// 189.940 us; speedup vs baseline: 1.2558x; 1.0012x over previous
//
#include <hip/hip_runtime.h>
#include <hip/hip_bf16.h>

#define HID 256
#define H1H 8
#define C1 32
#define C2 16
#define NEG 0.2f

typedef unsigned short ushort_t;
typedef unsigned int uint_t;
typedef unsigned char uchar_t;
typedef __attribute__((ext_vector_type(8))) short short8;
typedef __attribute__((ext_vector_type(4))) float f32x4;
typedef __attribute__((ext_vector_type(2))) float f32x2;

__device__ __forceinline__ float lrelu(float t){ return (t >= 0.f) ? t : NEG * t; }
__device__ __forceinline__ ushort_t f2bf(float f){
    uint_t u = __float_as_uint(f);
    u = (u + 0x7fffu + ((u >> 16) & 1u)) >> 16;   // RNE
    return (ushort_t)u;
}
__device__ __forceinline__ float bf_lo(uint_t p){ return __uint_as_float(p << 16); }
__device__ __forceinline__ float bf_hi(uint_t p){ return __uint_as_float(p & 0xffff0000u); }
__device__ __forceinline__ uchar_t f2fp8(float f){
    int r = __builtin_amdgcn_cvt_pk_fp8_f32(f, f, 0, false);   // OCP e4m3, RNE
    return (uchar_t)(r & 0xFF);
}

#define GLOAD_LDS16(g, l) \
    __builtin_amdgcn_global_load_lds( \
        (const __attribute__((address_space(1))) void*)(g), \
        (__attribute__((address_space(3))) void*)(l), 16, 0, 0)

// ---------------- prep (merged): deg_count+slot (FIRST, 4 edges/thread) | W1t | W2t | Xbf ----
// deg must be zeroed (hipMemsetAsync) BEFORE this kernel.
// Count blocks dispatch first so their atomic latency chains overlap the streaming blocks.
__global__ __launch_bounds__(256) void prep_k(const float* __restrict__ X,
                                              ushort_t* __restrict__ Xbf, long n4,
                                              const float* __restrict__ W1,
                                              ushort_t* __restrict__ W1t,
                                              const float* __restrict__ W2,
                                              ushort_t* __restrict__ W2t,
                                              const int* __restrict__ dst,
                                              int E, int Etot, int* __restrict__ deg,
                                              int* __restrict__ slot, int cnt4)
{
    int bid = blockIdx.x;
    int tid = threadIdx.x;
    if (bid < cnt4) {
        // ---- deg count + slot: 4 independent atomic chains per thread ----
        long base = (long)bid * 1024;
        #pragma unroll
        for (int q = 0; q < 4; q++) {
            long i = base + q * 256 + tid;
            if (i < E) {
                slot[i] = atomicAdd(&deg[dst[i]], 1);
            } else if (i < Etot) {
                slot[i] = atomicAdd(&deg[i - E], 1);      // self loop
            }
        }
    } else if (bid < cnt4 + 64) {
        int b = bid - cnt4;
        __shared__ ushort_t sh[32][33];
        int bx = b & 7, by = b >> 3;                      // k-tile, n-tile
        int tx = tid & 31, ty = tid >> 5;                 // 32 x 8
        #pragma unroll
        for (int i = 0; i < 32; i += 8)
            sh[ty + i][tx] = f2bf(W1[(long)(bx * 32 + ty + i) * 256 + by * 32 + tx]);
        __syncthreads();
        #pragma unroll
        for (int i = 0; i < 32; i += 8)
            W1t[(long)(by * 32 + ty + i) * 256 + bx * 32 + tx] = sh[tx][ty + i];
    } else if (bid == cnt4 + 64) {
        // W2t[c][k] = bf16(W2[k][c]); 4096 elems
        for (int idx = tid; idx < 4096; idx += 256) {
            int k = idx >> 4, c = idx & 15;
            W2t[c * 256 + k] = f2bf(W2[idx]);
        }
    } else {
        long stride = (long)2048 * 256;
        for (long i = (long)(bid - cnt4 - 65) * 256 + tid; i < n4; i += stride) {
            float4 v = ((const float4*)X)[i];
            ushort4 o;
            o.x = f2bf(fmaxf(v.x, 0.f)); o.y = f2bf(fmaxf(v.y, 0.f));
            o.z = f2bf(fmaxf(v.z, 0.f)); o.w = f2bf(fmaxf(v.w, 0.f));
            ((ushort4*)Xbf)[i] = o;
        }
    }
}

// ---------------- GEMM1 (MFMA, async-staged, 64x128 tile): h1f8 = fp8( relu(x) @ W1 ) + alpha1 ----
__global__ __launch_bounds__(256) void gemm1_k(const ushort_t* __restrict__ Xbf,
                                               const ushort_t* __restrict__ W1t,
                                               const float* __restrict__ a1s_g,
                                               const float* __restrict__ a1d_g,
                                               uchar_t* __restrict__ H1f8,
                                               float* __restrict__ as1,
                                               float* __restrict__ ad1, int M)
{
    __shared__ ushort_t Abuf[64 * 64];    // 8 KiB: 64 rows x 8 chunks, chunk-swizzled
    __shared__ ushort_t Bbuf[128 * 64];   // 16 KiB: 128 cols x 8 chunks
    int tid = threadIdx.x;
    int bm = blockIdx.y * 64, bn = blockIdx.x * 128;
    int wid = tid >> 6, lane = tid & 63;
    int wr = wid >> 1, wc = wid & 1;
    int lg = lane >> 4, lm = lane & 15;

    f32x4 acc[2][4];
    #pragma unroll
    for (int m = 0; m < 2; m++)
        #pragma unroll
        for (int n = 0; n < 4; n++) acc[m][n] = (f32x4){0.f, 0.f, 0.f, 0.f};

    int rA[2], lcA[2];
    #pragma unroll
    for (int q = 0; q < 2; q++) {
        int idx = q * 256 + tid;
        rA[q] = idx >> 3;
        lcA[q] = (idx & 7) ^ (rA[q] & 7);
    }
    int rB[4], lcB[4];
    #pragma unroll
    for (int q = 0; q < 4; q++) {
        int idx = q * 256 + tid;
        rB[q] = idx >> 3;
        lcB[q] = (idx & 7) ^ (rB[q] & 7);
    }

    for (int k0 = 0; k0 < 256; k0 += 64) {
        __syncthreads();
        #pragma unroll
        for (int q = 0; q < 2; q++) {
            const ushort_t* asrc = Xbf + (long)(bm + rA[q]) * 256 + k0 + lcA[q] * 8;
            GLOAD_LDS16(asrc, Abuf + (q * 256 + wid * 64) * 8);
        }
        #pragma unroll
        for (int q = 0; q < 4; q++) {
            const ushort_t* bsrc = W1t + (long)(bn + rB[q]) * 256 + k0 + lcB[q] * 8;
            GLOAD_LDS16(bsrc, Bbuf + (q * 256 + wid * 64) * 8);
        }
        __syncthreads();
        #pragma unroll
        for (int ks = 0; ks < 2; ks++) {
            int kg = ks * 4 + lg;
            short8 af[2], bfr[4];
            #pragma unroll
            for (int m = 0; m < 2; m++) {
                int R = wr * 32 + m * 16 + lm;
                af[m] = *(const short8*)&Abuf[(R * 8 + (kg ^ (R & 7))) * 8];
            }
            #pragma unroll
            for (int n = 0; n < 4; n++) {
                int Cc = wc * 64 + n * 16 + lm;
                bfr[n] = *(const short8*)&Bbuf[(Cc * 8 + (kg ^ (Cc & 7))) * 8];
            }
            #pragma unroll
            for (int m = 0; m < 2; m++)
                #pragma unroll
                for (int n = 0; n < 4; n++)
                    acc[m][n] = __builtin_amdgcn_mfma_f32_16x16x32_bf16(af[m], bfr[n], acc[m][n], 0, 0, 0);
        }
    }

    // fused alpha1 (fp32 accumulators -> full precision dots)
    int h0 = ((bn >> 5) + (wc << 1));
    float as_l0 = a1s_g[h0 * 32 + lm],       as_h0 = a1s_g[h0 * 32 + 16 + lm];
    float as_l1 = a1s_g[(h0 + 1) * 32 + lm], as_h1 = a1s_g[(h0 + 1) * 32 + 16 + lm];
    float ad_l0 = a1d_g[h0 * 32 + lm],       ad_h0 = a1d_g[h0 * 32 + 16 + lm];
    float ad_l1 = a1d_g[(h0 + 1) * 32 + lm], ad_h1 = a1d_g[(h0 + 1) * 32 + 16 + lm];

    #pragma unroll
    for (int m = 0; m < 2; m++) {
        #pragma unroll
        for (int r = 0; r < 4; r++) {
            int gm = bm + wr * 32 + m * 16 + lg * 4 + r;
            float s0 = acc[m][0][r] * as_l0 + acc[m][1][r] * as_h0;
            float s1 = acc[m][2][r] * as_l1 + acc[m][3][r] * as_h1;
            float d0 = acc[m][0][r] * ad_l0 + acc[m][1][r] * ad_h0;
            float d1 = acc[m][2][r] * ad_l1 + acc[m][3][r] * ad_h1;
            #pragma unroll
            for (int off = 1; off < 16; off <<= 1) {
                s0 += __shfl_xor(s0, off);
                s1 += __shfl_xor(s1, off);
                d0 += __shfl_xor(d0, off);
                d1 += __shfl_xor(d1, off);
            }
            if (gm < M) {
                uchar_t* basep = H1f8 + (long)gm * 256 + bn + wc * 64 + lm;
                #pragma unroll
                for (int n = 0; n < 4; n++)
                    basep[n * 16] = f2fp8(acc[m][n][r]);
                if (lm == 0) {
                    float2 sv = {s0, s1}, dv = {d0, d1};
                    *(float2*)&as1[(gm << 3) + h0] = sv;
                    *(float2*)&ad1[(gm << 3) + h0] = dv;
                }
            }
        }
    }
}

// ---------------- CSR scans ----------------
__global__ __launch_bounds__(256) void scan1_k(const int* __restrict__ deg,
                                               int* __restrict__ incl,
                                               int* __restrict__ bsum, int Nn)
{
    __shared__ int sh[256];
    int t = threadIdx.x;
    int base = blockIdx.x * 1024 + t * 4;
    int v0 = (base     < Nn) ? deg[base]     : 0;
    int v1 = (base + 1 < Nn) ? deg[base + 1] : 0;
    int v2 = (base + 2 < Nn) ? deg[base + 2] : 0;
    int v3 = (base + 3 < Nn) ? deg[base + 3] : 0;
    int s0 = v0, s1 = s0 + v1, s2 = s1 + v2, s3 = s2 + v3;
    sh[t] = s3;
    __syncthreads();
    for (int off = 1; off < 256; off <<= 1) {
        int x = (t >= off) ? sh[t - off] : 0;
        __syncthreads();
        sh[t] += x;
        __syncthreads();
    }
    int prev = (t > 0) ? sh[t - 1] : 0;
    if (base     < Nn) incl[base]     = prev + s0;
    if (base + 1 < Nn) incl[base + 1] = prev + s1;
    if (base + 2 < Nn) incl[base + 2] = prev + s2;
    if (base + 3 < Nn) incl[base + 3] = prev + s3;
    if (t == 255) bsum[blockIdx.x] = sh[255];
}
__global__ void scan2_k(const int* __restrict__ bsum, int* __restrict__ bpre, int nb)
{
    int t = threadIdx.x;                // single wave, nb <= 64
    int own = (t < nb) ? bsum[t] : 0;
    int v = own;
    for (int off = 1; off < 64; off <<= 1) {
        int x = __shfl_up(v, off);
        if (t >= off) v += x;
    }
    if (t < nb) bpre[t] = v - own;      // exclusive
}
__global__ void scan3_k(const int* __restrict__ incl, const int* __restrict__ deg,
                        const int* __restrict__ bpre, int* __restrict__ offs,
                        int Nn, int Etot)
{
    int i = blockIdx.x * 256 + threadIdx.x;
    if (i < Nn) {
        int e = bpre[i >> 10] + incl[i] - deg[i];
        offs[i] = e;
    }
    if (i == 0) offs[Nn] = Etot;
}

// ---------------- scatter: atomic-free (slot precomputed in prep) ----------------
__global__ __launch_bounds__(256) void scatter_k(const int* __restrict__ src,
    const int* __restrict__ dst, const int* __restrict__ slot,
    const int* __restrict__ offs, int E, int Etot, int* __restrict__ srcs)
{
    long base = (long)blockIdx.x * 1024;
    #pragma unroll
    for (int q = 0; q < 4; q++) {
        long i = base + q * 256 + threadIdx.x;
        if (i < E) {
            int d = dst[i];
            srcs[offs[d] + slot[i]] = src[i];       // offs is L2-resident (200 KB)
        } else if (i < Etot) {
            int n = (int)(i - E);
            srcs[offs[n] + slot[i]] = n;            // self loop
        }
    }
}

// ---------------- GAT layer 1 aggregate: wave per dst node (fp8 gather, 256B rows) ----------------
__global__ __launch_bounds__(256) void gat1_agg_k(const uchar_t* __restrict__ H1f8,
    const float* __restrict__ as1, const float* __restrict__ ad1,
    const int* __restrict__ offs, const int* __restrict__ srcs,
    const float* __restrict__ b1, ushort_t* __restrict__ X1b, int Nn)
{
    int w = (blockIdx.x << 2) + (threadIdx.x >> 6);
    if (w >= Nn) return;
    int lane = threadIdx.x & 63;
    int he = lane & 7, el = lane >> 3;
    int myh = lane >> 3;
    int beg = offs[w], end = offs[w + 1];
    int deg = end - beg;
    float adv = ad1[(w << 3) + he];
    float4 acc = {0.f, 0.f, 0.f, 0.f};

    if (deg <= 64) {
        int sv0=0,sv1=0,sv2=0,sv3=0,sv4=0,sv5=0,sv6=0,sv7=0;
        float wv0=0,wv1=0,wv2=0,wv3=0,wv4=0,wv5=0,wv6=0,wv7=0;
        {
            int j;
            j = beg + el;      if (j < end){ sv0 = srcs[j]; wv0 = __expf(lrelu(as1[(sv0<<3)+he]+adv)); }
            j = beg + 8 + el;  if (j < end){ sv1 = srcs[j]; wv1 = __expf(lrelu(as1[(sv1<<3)+he]+adv)); }
            j = beg + 16 + el; if (j < end){ sv2 = srcs[j]; wv2 = __expf(lrelu(as1[(sv2<<3)+he]+adv)); }
            j = beg + 24 + el; if (j < end){ sv3 = srcs[j]; wv3 = __expf(lrelu(as1[(sv3<<3)+he]+adv)); }
            j = beg + 32 + el; if (j < end){ sv4 = srcs[j]; wv4 = __expf(lrelu(as1[(sv4<<3)+he]+adv)); }
            j = beg + 40 + el; if (j < end){ sv5 = srcs[j]; wv5 = __expf(lrelu(as1[(sv5<<3)+he]+adv)); }
            j = beg + 48 + el; if (j < end){ sv6 = srcs[j]; wv6 = __expf(lrelu(as1[(sv6<<3)+he]+adv)); }
            j = beg + 56 + el; if (j < end){ sv7 = srcs[j]; wv7 = __expf(lrelu(as1[(sv7<<3)+he]+adv)); }
        }
        float d = ((wv0 + wv1) + (wv2 + wv3)) + ((wv4 + wv5) + (wv6 + wv7));
        #pragma unroll
        for (int off = 8; off < 64; off <<= 1) d += __shfl_xor(d, off);
        float inv = 1.f / d;
        // normalize on the OWNING lane BEFORE broadcast
        wv0 *= inv; wv1 *= inv; wv2 *= inv; wv3 *= inv;
        wv4 *= inv; wv5 *= inv; wv6 *= inv; wv7 *= inv;

        #define GAT1_BATCH(SV, WV, Q)                                            \
        {                                                                        \
            int ne = deg - (Q << 3);                                             \
            if (ne > 0) {                                                        \
                ne = min(ne, 8);                                                 \
                int sb[8]; float wb[8];                                          \
                _Pragma("unroll")                                                \
                for (int e8 = 0; e8 < 8; e8++) {                                 \
                    sb[e8] = __shfl(SV, e8 << 3);                                \
                    wb[e8] = __shfl(WV, (e8 << 3) + myh);                        \
                }                                                                \
                if (ne == 8) {                                                   \
                    _Pragma("unroll")                                            \
                    for (int e8 = 0; e8 < 8; e8++) {                             \
                        uint_t v = ((const uint_t*)(H1f8 + ((long)sb[e8] << 8)))[lane]; \
                        f32x2 lo = __builtin_amdgcn_cvt_pk_f32_fp8((int)v, false); \
                        f32x2 hi = __builtin_amdgcn_cvt_pk_f32_fp8((int)v, true);  \
                        acc.x += wb[e8] * lo[0];                                 \
                        acc.y += wb[e8] * lo[1];                                 \
                        acc.z += wb[e8] * hi[0];                                 \
                        acc.w += wb[e8] * hi[1];                                 \
                    }                                                            \
                } else {                                                         \
                    _Pragma("unroll")                                            \
                    for (int e8 = 0; e8 < 8; e8++) {                             \
                        if (e8 < ne) {                                           \
                            uint_t v = ((const uint_t*)(H1f8 + ((long)sb[e8] << 8)))[lane]; \
                            f32x2 lo = __builtin_amdgcn_cvt_pk_f32_fp8((int)v, false); \
                            f32x2 hi = __builtin_amdgcn_cvt_pk_f32_fp8((int)v, true);  \
                            acc.x += wb[e8] * lo[0];                             \
                            acc.y += wb[e8] * lo[1];                             \
                            acc.z += wb[e8] * hi[0];                             \
                            acc.w += wb[e8] * hi[1];                             \
                        }                                                        \
                    }                                                            \
                }                                                                \
            }                                                                    \
        }
        GAT1_BATCH(sv0, wv0, 0)
        GAT1_BATCH(sv1, wv1, 1)
        GAT1_BATCH(sv2, wv2, 2)
        GAT1_BATCH(sv3, wv3, 3)
        GAT1_BATCH(sv4, wv4, 4)
        GAT1_BATCH(sv5, wv5, 5)
        GAT1_BATCH(sv6, wv6, 6)
        GAT1_BATCH(sv7, wv7, 7)
        #undef GAT1_BATCH
    } else {
        float dA = 0.f, dB = 0.f;
        for (int j0 = beg; j0 < end; j0 += 16) {
            int j = j0 + el, jb = j0 + 8 + el;
            if (j < end)  dA += __expf(lrelu(as1[(srcs[j] << 3) + he] + adv));
            if (jb < end) dB += __expf(lrelu(as1[(srcs[jb] << 3) + he] + adv));
        }
        float d = dA + dB;
        #pragma unroll
        for (int off = 8; off < 64; off <<= 1) d += __shfl_xor(d, off);
        float inv = 1.f / d;
        for (int j0 = beg; j0 < end; j0 += 8) {
            int j = j0 + el;
            int s = 0; float wv = 0.f;
            if (j < end) {
                s = srcs[j];
                wv = __expf(lrelu(as1[(s << 3) + he] + adv)) * inv;
            }
            int ne = min(end - j0, 8);
            int sb[8]; float wb[8];
            #pragma unroll
            for (int e8 = 0; e8 < 8; e8++) {
                sb[e8] = __shfl(s, e8 << 3);
                wb[e8] = __shfl(wv, (e8 << 3) + myh);
            }
            #pragma unroll
            for (int e8 = 0; e8 < 8; e8++) {
                if (e8 < ne) {
                    uint_t v = ((const uint_t*)(H1f8 + ((long)sb[e8] << 8)))[lane];
                    f32x2 lo = __builtin_amdgcn_cvt_pk_f32_fp8((int)v, false);
                    f32x2 hi = __builtin_amdgcn_cvt_pk_f32_fp8((int)v, true);
                    acc.x += wb[e8] * lo[0];
                    acc.y += wb[e8] * lo[1];
                    acc.z += wb[e8] * hi[0];
                    acc.w += wb[e8] * hi[1];
                }
            }
        }
    }

    float4 bb = ((const float4*)b1)[lane];
    float o0 = fmaxf(acc.x + bb.x, 0.f);
    float o1 = fmaxf(acc.y + bb.y, 0.f);
    float o2 = fmaxf(acc.z + bb.z, 0.f);
    float o3 = fmaxf(acc.w + bb.w, 0.f);
    uint2 ov;
    ov.x = (uint_t)f2bf(o0) | ((uint_t)f2bf(o1) << 16);
    ov.y = (uint_t)f2bf(o2) | ((uint_t)f2bf(o3) << 16);
    ((uint2*)(X1b + ((long)w << 8)))[lane] = ov;
}

// ---------------- GEMM2 (MFMA) + fused alpha2: h2 = x1b @ W2t^T ----------------
__global__ __launch_bounds__(256) void gemm2_k(const ushort_t* __restrict__ X1b,
    const ushort_t* __restrict__ W2t, const float* __restrict__ a2s_w,
    const float* __restrict__ a2d_w, float* __restrict__ H2,
    float* __restrict__ as2, float* __restrict__ ad2, int Nn)
{
    int wid = threadIdx.x >> 6, lane = threadIdx.x & 63;
    int row0 = blockIdx.x * 64 + wid * 16;
    if (row0 >= Nn) return;
    int lm = lane & 15, lg = lane >> 4;
    f32x4 acc = (f32x4){0.f, 0.f, 0.f, 0.f};
    const ushort_t* arow = X1b + (long)(row0 + lm) * 256 + lg * 8;
    const ushort_t* brow = W2t + lm * 256 + lg * 8;
    #pragma unroll
    for (int k0 = 0; k0 < 256; k0 += 32) {
        short8 af = *(const short8*)(arow + k0);
        short8 bf = *(const short8*)(brow + k0);
        acc = __builtin_amdgcn_mfma_f32_16x16x32_bf16(af, bf, acc, 0, 0, 0);
    }
    float a2sv = a2s_w[lm], a2dv = a2d_w[lm];
    #pragma unroll
    for (int r = 0; r < 4; r++) {
        int grow = row0 + lg * 4 + r;
        if (grow < Nn) H2[(grow << 4) + lm] = acc[r];
        float s = acc[r] * a2sv, d2 = acc[r] * a2dv;
        #pragma unroll
        for (int off = 1; off < 16; off <<= 1) {
            s += __shfl_xor(s, off);
            d2 += __shfl_xor(d2, off);
        }
        if (lm == 0 && grow < Nn) { as2[grow] = s; ad2[grow] = d2; }
    }
}

// ---------------- GAT layer 2 aggregate + final softmax (weight-cached) ----------------
__global__ __launch_bounds__(256) void gat2_agg_k(const float* __restrict__ H2,
    const float* __restrict__ as2, const float* __restrict__ ad2,
    const int* __restrict__ offs, const int* __restrict__ srcs,
    const float* __restrict__ b2, float* __restrict__ out, int Nn)
{
    int w = (blockIdx.x << 2) + (threadIdx.x >> 6);
    if (w >= Nn) return;
    int lane = threadIdx.x & 63;
    int beg = offs[w], end = offs[w + 1];
    int deg = end - beg;
    float adv = ad2[w];
    int c = lane & 15, eg = lane >> 4;
    float acc = 0.f;

    if (deg <= 64) {
        int j = beg + lane;
        int s_l = 0; float w_l = 0.f;
        if (j < end) { s_l = srcs[j]; w_l = __expf(lrelu(as2[s_l] + adv)); }
        float d = w_l;
        #pragma unroll
        for (int off = 1; off < 64; off <<= 1) d += __shfl_xor(d, off);
        float w_n = w_l / d;
        for (int j0 = 0; j0 < deg; j0 += 4) {
            int jj = j0 + eg;
            int s = __shfl(s_l, jj);
            float wv = __shfl(w_n, jj);
            if (jj < deg)
                acc += wv * H2[(s << 4) + c];
        }
    } else {
        float d = 0.f;
        for (int j = beg + lane; j < end; j += 64)
            d += __expf(lrelu(as2[srcs[j]] + adv));
        #pragma unroll
        for (int off = 1; off < 64; off <<= 1) d += __shfl_xor(d, off);
        float inv = 1.f / d;
        for (int j0 = beg; j0 < end; j0 += 4) {
            int j = j0 + eg;
            if (j < end) {
                int s = srcs[j];
                float wv = __expf(lrelu(as2[s] + adv)) * inv;
                acc += wv * H2[(s << 4) + c];
            }
        }
    }
    acc += __shfl_xor(acc, 16);
    acc += __shfl_xor(acc, 32);
    float v = acc + b2[c];
    float mx = v;
    #pragma unroll
    for (int off = 1; off < 16; off <<= 1) mx = fmaxf(mx, __shfl_xor(mx, off));
    float ex = __expf(v - mx);
    float se = ex;
    #pragma unroll
    for (int off = 1; off < 16; off <<= 1) se += __shfl_xor(se, off);
    if (eg == 0) out[(w << 4) + c] = ex / se;
}

// ---------------- host launcher ----------------
extern "C" void kernel_launch(void* const* d_in, const int* in_sizes, int n_in,
                              void* d_out, int out_size, void* d_ws, size_t ws_size,
                              hipStream_t stream)
{
    const float* x    = (const float*)d_in[0];
    const int*   ei   = (const int*)d_in[1];
    const float* W1   = (const float*)d_in[2];
    const float* a1s  = (const float*)d_in[3];
    const float* a1d  = (const float*)d_in[4];
    const float* b1   = (const float*)d_in[5];
    const float* W2   = (const float*)d_in[6];
    const float* a2s  = (const float*)d_in[7];
    const float* a2d  = (const float*)d_in[8];
    const float* b2   = (const float*)d_in[9];
    float* out = (float*)d_out;

    int N = in_sizes[0] / HID;
    int E = in_sizes[1] / 2;
    int Etot = E + N;
    const int* src = ei;
    const int* dst = ei + E;

    char* p = (char*)d_ws;
    auto alloc = [&](size_t bytes) {
        void* r = (void*)p;
        p += (bytes + 255) & ~(size_t)255;
        return r;
    };
    ushort_t* xbf  = (ushort_t*)alloc((size_t)N * 256 * 2);
    uchar_t*  h1f8 = (uchar_t*)alloc((size_t)N * 256);
    ushort_t* x1b  = (ushort_t*)alloc((size_t)N * 256 * 2);
    ushort_t* w1t  = (ushort_t*)alloc((size_t)256 * 256 * 2);
    ushort_t* w2t  = (ushort_t*)alloc((size_t)16 * 256 * 2);
    float* h2      = (float*)alloc((size_t)N * 16 * 4);
    float* as1     = (float*)alloc((size_t)N * 8 * 4);
    float* ad1     = (float*)alloc((size_t)N * 8 * 4);
    float* as2v    = (float*)alloc((size_t)N * 4);
    float* ad2v    = (float*)alloc((size_t)N * 4);
    int*   deg     = (int*)alloc((size_t)N * 4);
    int*   incl    = (int*)alloc((size_t)N * 4);
    int*   offs    = (int*)alloc((size_t)(N + 1) * 4);
    int*   bsum    = (int*)alloc(256 * 4);
    int*   bpre    = (int*)alloc(256 * 4);
    int*   srcs    = (int*)alloc((size_t)Etot * 4);
    int*   slot    = (int*)alloc((size_t)Etot * 4);

    int nb = (N + 1023) / 1024;
    int cnt4 = (Etot + 1023) / 1024;
    int scat_blocks = (Etot + 1023) / 1024;

    // zero deg, then merged prep (count+slot FIRST | W1t | W2t | Xbf)
    hipMemsetAsync(deg, 0, (size_t)N * 4, stream);
    hipLaunchKernelGGL(prep_k, dim3(cnt4 + 65 + 2048), dim3(256), 0, stream,
                       x, xbf, (long)N * 64, W1, w1t, W2, w2t, dst, E, Etot,
                       deg, slot, cnt4);
    // CSR scans
    hipLaunchKernelGGL(scan1_k, dim3(nb), dim3(256), 0, stream, deg, incl, bsum, N);
    hipLaunchKernelGGL(scan2_k, dim3(1), dim3(64), 0, stream, bsum, bpre, nb);
    hipLaunchKernelGGL(scan3_k, dim3((N + 255) / 256), dim3(256), 0, stream,
                       incl, deg, bpre, offs, N, Etot);
    // atomic-free scatter
    hipLaunchKernelGGL(scatter_k, dim3(scat_blocks), dim3(256), 0, stream,
                       src, dst, slot, offs, E, Etot, srcs);
    // GEMM1 (MFMA, async-staged, 64x128 tile, fused alpha1, fp8 h1 out)
    dim3 g1(2, (N + 63) / 64);
    hipLaunchKernelGGL(gemm1_k, g1, dim3(256), 0, stream,
                       xbf, w1t, a1s, a1d, h1f8, as1, ad1, N);
    // layer 1 aggregate (fp8 gather)
    hipLaunchKernelGGL(gat1_agg_k, dim3((N + 3) / 4), dim3(256), 0, stream,
                       h1f8, as1, ad1, offs, srcs, b1, x1b, N);
    // layer 2: MFMA gemm2 + aggregate
    hipLaunchKernelGGL(gemm2_k, dim3((N + 63) / 64), dim3(256), 0, stream,
                       x1b, w2t, a2s, a2d, h2, as2v, ad2v, N);
    hipLaunchKernelGGL(gat2_agg_k, dim3((N + 3) / 4), dim3(256), 0, stream,
                       h2, as2v, ad2v, offs, srcs, b2, out, N);
}

// Round 19
// 189.933 us; speedup vs baseline: 1.2559x; 1.0000x over previous
//
#include <hip/hip_runtime.h>
#include <hip/hip_bf16.h>

#define HID 256
#define H1H 8
#define C1 32
#define C2 16
#define NEG 0.2f

typedef unsigned short ushort_t;
typedef unsigned int uint_t;
typedef unsigned char uchar_t;
typedef __attribute__((ext_vector_type(8))) short short8;
typedef __attribute__((ext_vector_type(4))) float f32x4;
typedef __attribute__((ext_vector_type(2))) float f32x2;

__device__ __forceinline__ float lrelu(float t){ return (t >= 0.f) ? t : NEG * t; }
__device__ __forceinline__ ushort_t f2bf(float f){
    uint_t u = __float_as_uint(f);
    u = (u + 0x7fffu + ((u >> 16) & 1u)) >> 16;   // RNE
    return (ushort_t)u;
}
__device__ __forceinline__ float bf_lo(uint_t p){ return __uint_as_float(p << 16); }
__device__ __forceinline__ float bf_hi(uint_t p){ return __uint_as_float(p & 0xffff0000u); }
__device__ __forceinline__ uchar_t f2fp8(float f){
    int r = __builtin_amdgcn_cvt_pk_fp8_f32(f, f, 0, false);   // OCP e4m3, RNE
    return (uchar_t)(r & 0xFF);
}

#define GLOAD_LDS16(g, l) \
    __builtin_amdgcn_global_load_lds( \
        (const __attribute__((address_space(1))) void*)(g), \
        (__attribute__((address_space(3))) void*)(l), 16, 0, 0)

// ---------------- prep (streaming only): W1t | W2t | Xbf ----------------
__global__ __launch_bounds__(256) void prep_k(const float* __restrict__ X,
                                              ushort_t* __restrict__ Xbf, long n4,
                                              const float* __restrict__ W1,
                                              ushort_t* __restrict__ W1t,
                                              const float* __restrict__ W2,
                                              ushort_t* __restrict__ W2t)
{
    int bid = blockIdx.x;
    int tid = threadIdx.x;
    if (bid < 64) {
        __shared__ ushort_t sh[32][33];
        int bx = bid & 7, by = bid >> 3;                  // k-tile, n-tile
        int tx = tid & 31, ty = tid >> 5;                 // 32 x 8
        #pragma unroll
        for (int i = 0; i < 32; i += 8)
            sh[ty + i][tx] = f2bf(W1[(long)(bx * 32 + ty + i) * 256 + by * 32 + tx]);
        __syncthreads();
        #pragma unroll
        for (int i = 0; i < 32; i += 8)
            W1t[(long)(by * 32 + ty + i) * 256 + bx * 32 + tx] = sh[tx][ty + i];
    } else if (bid == 64) {
        // W2t[c][k] = bf16(W2[k][c]); 4096 elems
        for (int idx = tid; idx < 4096; idx += 256) {
            int k = idx >> 4, c = idx & 15;
            W2t[c * 256 + k] = f2bf(W2[idx]);
        }
    } else {
        long stride = (long)2048 * 256;
        for (long i = (long)(bid - 65) * 256 + tid; i < n4; i += stride) {
            float4 v = ((const float4*)X)[i];
            ushort4 o;
            o.x = f2bf(fmaxf(v.x, 0.f)); o.y = f2bf(fmaxf(v.y, 0.f));
            o.z = f2bf(fmaxf(v.z, 0.f)); o.w = f2bf(fmaxf(v.w, 0.f));
            ((ushort4*)Xbf)[i] = o;
        }
    }
}

// ---------------- GEMM1 (MFMA, 64x128 tile) + co-scheduled deg count (real edges only) ----
// blocks [0, cntB): count+slot (4 indep atomic chains/thread, latency-bound -> hides
// under the MFMA blocks' occupancy); blocks [cntB, ...): GEMM tiles.
__global__ __launch_bounds__(256) void gemm1_k(const ushort_t* __restrict__ Xbf,
                                               const ushort_t* __restrict__ W1t,
                                               const float* __restrict__ a1s_g,
                                               const float* __restrict__ a1d_g,
                                               uchar_t* __restrict__ H1f8,
                                               float* __restrict__ as1,
                                               float* __restrict__ ad1, int M,
                                               const int* __restrict__ dst, int E,
                                               int* __restrict__ deg,
                                               int* __restrict__ slot, int cntB)
{
    __shared__ ushort_t Abuf[64 * 64];    // 8 KiB
    __shared__ ushort_t Bbuf[128 * 64];   // 16 KiB
    int bid = blockIdx.x;
    int tid = threadIdx.x;

    if (bid < cntB) {
        // ---- deg count + slot: 4 independent atomic chains per thread ----
        long base = (long)bid * 1024;
        #pragma unroll
        for (int q = 0; q < 4; q++) {
            long i = base + q * 256 + tid;
            if (i < E) slot[i] = atomicAdd(&deg[dst[i]], 1);
        }
        return;
    }

    int bid2 = bid - cntB;
    int bm = (bid2 >> 1) * 64, bn = (bid2 & 1) * 128;
    int wid = tid >> 6, lane = tid & 63;
    int wr = wid >> 1, wc = wid & 1;
    int lg = lane >> 4, lm = lane & 15;

    f32x4 acc[2][4];
    #pragma unroll
    for (int m = 0; m < 2; m++)
        #pragma unroll
        for (int n = 0; n < 4; n++) acc[m][n] = (f32x4){0.f, 0.f, 0.f, 0.f};

    int rA[2], lcA[2];
    #pragma unroll
    for (int q = 0; q < 2; q++) {
        int idx = q * 256 + tid;
        rA[q] = idx >> 3;
        lcA[q] = (idx & 7) ^ (rA[q] & 7);
    }
    int rB[4], lcB[4];
    #pragma unroll
    for (int q = 0; q < 4; q++) {
        int idx = q * 256 + tid;
        rB[q] = idx >> 3;
        lcB[q] = (idx & 7) ^ (rB[q] & 7);
    }

    for (int k0 = 0; k0 < 256; k0 += 64) {
        __syncthreads();
        #pragma unroll
        for (int q = 0; q < 2; q++) {
            const ushort_t* asrc = Xbf + (long)(bm + rA[q]) * 256 + k0 + lcA[q] * 8;
            GLOAD_LDS16(asrc, Abuf + (q * 256 + wid * 64) * 8);
        }
        #pragma unroll
        for (int q = 0; q < 4; q++) {
            const ushort_t* bsrc = W1t + (long)(bn + rB[q]) * 256 + k0 + lcB[q] * 8;
            GLOAD_LDS16(bsrc, Bbuf + (q * 256 + wid * 64) * 8);
        }
        __syncthreads();
        #pragma unroll
        for (int ks = 0; ks < 2; ks++) {
            int kg = ks * 4 + lg;
            short8 af[2], bfr[4];
            #pragma unroll
            for (int m = 0; m < 2; m++) {
                int R = wr * 32 + m * 16 + lm;
                af[m] = *(const short8*)&Abuf[(R * 8 + (kg ^ (R & 7))) * 8];
            }
            #pragma unroll
            for (int n = 0; n < 4; n++) {
                int Cc = wc * 64 + n * 16 + lm;
                bfr[n] = *(const short8*)&Bbuf[(Cc * 8 + (kg ^ (Cc & 7))) * 8];
            }
            #pragma unroll
            for (int m = 0; m < 2; m++)
                #pragma unroll
                for (int n = 0; n < 4; n++)
                    acc[m][n] = __builtin_amdgcn_mfma_f32_16x16x32_bf16(af[m], bfr[n], acc[m][n], 0, 0, 0);
        }
    }

    // fused alpha1 (fp32 accumulators)
    int h0 = ((bn >> 5) + (wc << 1));
    float as_l0 = a1s_g[h0 * 32 + lm],       as_h0 = a1s_g[h0 * 32 + 16 + lm];
    float as_l1 = a1s_g[(h0 + 1) * 32 + lm], as_h1 = a1s_g[(h0 + 1) * 32 + 16 + lm];
    float ad_l0 = a1d_g[h0 * 32 + lm],       ad_h0 = a1d_g[h0 * 32 + 16 + lm];
    float ad_l1 = a1d_g[(h0 + 1) * 32 + lm], ad_h1 = a1d_g[(h0 + 1) * 32 + 16 + lm];

    #pragma unroll
    for (int m = 0; m < 2; m++) {
        #pragma unroll
        for (int r = 0; r < 4; r++) {
            int gm = bm + wr * 32 + m * 16 + lg * 4 + r;
            float s0 = acc[m][0][r] * as_l0 + acc[m][1][r] * as_h0;
            float s1 = acc[m][2][r] * as_l1 + acc[m][3][r] * as_h1;
            float d0 = acc[m][0][r] * ad_l0 + acc[m][1][r] * ad_h0;
            float d1 = acc[m][2][r] * ad_l1 + acc[m][3][r] * ad_h1;
            #pragma unroll
            for (int off = 1; off < 16; off <<= 1) {
                s0 += __shfl_xor(s0, off);
                s1 += __shfl_xor(s1, off);
                d0 += __shfl_xor(d0, off);
                d1 += __shfl_xor(d1, off);
            }
            if (gm < M) {
                uchar_t* basep = H1f8 + (long)gm * 256 + bn + wc * 64 + lm;
                #pragma unroll
                for (int n = 0; n < 4; n++)
                    basep[n * 16] = f2fp8(acc[m][n][r]);
                if (lm == 0) {
                    float2 sv = {s0, s1}, dv = {d0, d1};
                    *(float2*)&as1[(gm << 3) + h0] = sv;
                    *(float2*)&ad1[(gm << 3) + h0] = dv;
                }
            }
        }
    }
}

// ---------------- CSR scans (segment size = deg + 1 implicit self loop) ----------------
__global__ __launch_bounds__(256) void scan1_k(const int* __restrict__ deg,
                                               int* __restrict__ incl,
                                               int* __restrict__ bsum, int Nn)
{
    __shared__ int sh[256];
    int t = threadIdx.x;
    int base = blockIdx.x * 1024 + t * 4;
    int v0 = (base     < Nn) ? deg[base]     + 1 : 0;
    int v1 = (base + 1 < Nn) ? deg[base + 1] + 1 : 0;
    int v2 = (base + 2 < Nn) ? deg[base + 2] + 1 : 0;
    int v3 = (base + 3 < Nn) ? deg[base + 3] + 1 : 0;
    int s0 = v0, s1 = s0 + v1, s2 = s1 + v2, s3 = s2 + v3;
    sh[t] = s3;
    __syncthreads();
    for (int off = 1; off < 256; off <<= 1) {
        int x = (t >= off) ? sh[t - off] : 0;
        __syncthreads();
        sh[t] += x;
        __syncthreads();
    }
    int prev = (t > 0) ? sh[t - 1] : 0;
    if (base     < Nn) incl[base]     = prev + s0;
    if (base + 1 < Nn) incl[base + 1] = prev + s1;
    if (base + 2 < Nn) incl[base + 2] = prev + s2;
    if (base + 3 < Nn) incl[base + 3] = prev + s3;
    if (t == 255) bsum[blockIdx.x] = sh[255];
}
__global__ void scan2_k(const int* __restrict__ bsum, int* __restrict__ bpre, int nb)
{
    int t = threadIdx.x;                // single wave, nb <= 64
    int own = (t < nb) ? bsum[t] : 0;
    int v = own;
    for (int off = 1; off < 64; off <<= 1) {
        int x = __shfl_up(v, off);
        if (t >= off) v += x;
    }
    if (t < nb) bpre[t] = v - own;      // exclusive
}
__global__ void scan3_k(const int* __restrict__ incl, const int* __restrict__ deg,
                        const int* __restrict__ bpre, int* __restrict__ offs,
                        int Nn, int Etot)
{
    int i = blockIdx.x * 256 + threadIdx.x;
    if (i < Nn) {
        int e = bpre[i >> 10] + incl[i] - (deg[i] + 1);
        offs[i] = e;
    }
    if (i == 0) offs[Nn] = Etot;
}

// ---------------- scatter: atomic-free; self loop statically in last slot ----------------
__global__ __launch_bounds__(256) void scatter_k(const int* __restrict__ src,
    const int* __restrict__ dst, const int* __restrict__ slot,
    const int* __restrict__ offs, int E, int Etot, int* __restrict__ srcs)
{
    long base = (long)blockIdx.x * 1024;
    #pragma unroll
    for (int q = 0; q < 4; q++) {
        long i = base + q * 256 + threadIdx.x;
        if (i < E) {
            int d = dst[i];
            srcs[offs[d] + slot[i]] = src[i];       // offs is L2-resident (200 KB)
        } else if (i < Etot) {
            int n = (int)(i - E);
            srcs[offs[n + 1] - 1] = n;              // self loop -> last slot
        }
    }
}

// ---------------- GAT layer 1 aggregate: wave per dst node (fp8 gather, 256B rows) ----------------
__global__ __launch_bounds__(256) void gat1_agg_k(const uchar_t* __restrict__ H1f8,
    const float* __restrict__ as1, const float* __restrict__ ad1,
    const int* __restrict__ offs, const int* __restrict__ srcs,
    const float* __restrict__ b1, ushort_t* __restrict__ X1b, int Nn)
{
    int w = (blockIdx.x << 2) + (threadIdx.x >> 6);
    if (w >= Nn) return;
    int lane = threadIdx.x & 63;
    int he = lane & 7, el = lane >> 3;
    int myh = lane >> 3;
    int beg = offs[w], end = offs[w + 1];
    int deg = end - beg;
    float adv = ad1[(w << 3) + he];
    float4 acc = {0.f, 0.f, 0.f, 0.f};

    if (deg <= 64) {
        int sv0=0,sv1=0,sv2=0,sv3=0,sv4=0,sv5=0,sv6=0,sv7=0;
        float wv0=0,wv1=0,wv2=0,wv3=0,wv4=0,wv5=0,wv6=0,wv7=0;
        {
            int j;
            j = beg + el;      if (j < end){ sv0 = srcs[j]; wv0 = __expf(lrelu(as1[(sv0<<3)+he]+adv)); }
            j = beg + 8 + el;  if (j < end){ sv1 = srcs[j]; wv1 = __expf(lrelu(as1[(sv1<<3)+he]+adv)); }
            j = beg + 16 + el; if (j < end){ sv2 = srcs[j]; wv2 = __expf(lrelu(as1[(sv2<<3)+he]+adv)); }
            j = beg + 24 + el; if (j < end){ sv3 = srcs[j]; wv3 = __expf(lrelu(as1[(sv3<<3)+he]+adv)); }
            j = beg + 32 + el; if (j < end){ sv4 = srcs[j]; wv4 = __expf(lrelu(as1[(sv4<<3)+he]+adv)); }
            j = beg + 40 + el; if (j < end){ sv5 = srcs[j]; wv5 = __expf(lrelu(as1[(sv5<<3)+he]+adv)); }
            j = beg + 48 + el; if (j < end){ sv6 = srcs[j]; wv6 = __expf(lrelu(as1[(sv6<<3)+he]+adv)); }
            j = beg + 56 + el; if (j < end){ sv7 = srcs[j]; wv7 = __expf(lrelu(as1[(sv7<<3)+he]+adv)); }
        }
        float d = ((wv0 + wv1) + (wv2 + wv3)) + ((wv4 + wv5) + (wv6 + wv7));
        #pragma unroll
        for (int off = 8; off < 64; off <<= 1) d += __shfl_xor(d, off);
        float inv = 1.f / d;
        // normalize on the OWNING lane BEFORE broadcast
        wv0 *= inv; wv1 *= inv; wv2 *= inv; wv3 *= inv;
        wv4 *= inv; wv5 *= inv; wv6 *= inv; wv7 *= inv;

        #define GAT1_BATCH(SV, WV, Q)                                            \
        {                                                                        \
            int ne = deg - (Q << 3);                                             \
            if (ne > 0) {                                                        \
                ne = min(ne, 8);                                                 \
                int sb[8]; float wb[8];                                          \
                _Pragma("unroll")                                                \
                for (int e8 = 0; e8 < 8; e8++) {                                 \
                    sb[e8] = __shfl(SV, e8 << 3);                                \
                    wb[e8] = __shfl(WV, (e8 << 3) + myh);                        \
                }                                                                \
                if (ne == 8) {                                                   \
                    _Pragma("unroll")                                            \
                    for (int e8 = 0; e8 < 8; e8++) {                             \
                        uint_t v = ((const uint_t*)(H1f8 + ((long)sb[e8] << 8)))[lane]; \
                        f32x2 lo = __builtin_amdgcn_cvt_pk_f32_fp8((int)v, false); \
                        f32x2 hi = __builtin_amdgcn_cvt_pk_f32_fp8((int)v, true);  \
                        acc.x += wb[e8] * lo[0];                                 \
                        acc.y += wb[e8] * lo[1];                                 \
                        acc.z += wb[e8] * hi[0];                                 \
                        acc.w += wb[e8] * hi[1];                                 \
                    }                                                            \
                } else {                                                         \
                    _Pragma("unroll")                                            \
                    for (int e8 = 0; e8 < 8; e8++) {                             \
                        if (e8 < ne) {                                           \
                            uint_t v = ((const uint_t*)(H1f8 + ((long)sb[e8] << 8)))[lane]; \
                            f32x2 lo = __builtin_amdgcn_cvt_pk_f32_fp8((int)v, false); \
                            f32x2 hi = __builtin_amdgcn_cvt_pk_f32_fp8((int)v, true);  \
                            acc.x += wb[e8] * lo[0];                             \
                            acc.y += wb[e8] * lo[1];                             \
                            acc.z += wb[e8] * hi[0];                             \
                            acc.w += wb[e8] * hi[1];                             \
                        }                                                        \
                    }                                                            \
                }                                                                \
            }                                                                    \
        }
        GAT1_BATCH(sv0, wv0, 0)
        GAT1_BATCH(sv1, wv1, 1)
        GAT1_BATCH(sv2, wv2, 2)
        GAT1_BATCH(sv3, wv3, 3)
        GAT1_BATCH(sv4, wv4, 4)
        GAT1_BATCH(sv5, wv5, 5)
        GAT1_BATCH(sv6, wv6, 6)
        GAT1_BATCH(sv7, wv7, 7)
        #undef GAT1_BATCH
    } else {
        float dA = 0.f, dB = 0.f;
        for (int j0 = beg; j0 < end; j0 += 16) {
            int j = j0 + el, jb = j0 + 8 + el;
            if (j < end)  dA += __expf(lrelu(as1[(srcs[j] << 3) + he] + adv));
            if (jb < end) dB += __expf(lrelu(as1[(srcs[jb] << 3) + he] + adv));
        }
        float d = dA + dB;
        #pragma unroll
        for (int off = 8; off < 64; off <<= 1) d += __shfl_xor(d, off);
        float inv = 1.f / d;
        for (int j0 = beg; j0 < end; j0 += 8) {
            int j = j0 + el;
            int s = 0; float wv = 0.f;
            if (j < end) {
                s = srcs[j];
                wv = __expf(lrelu(as1[(s << 3) + he] + adv)) * inv;
            }
            int ne = min(end - j0, 8);
            int sb[8]; float wb[8];
            #pragma unroll
            for (int e8 = 0; e8 < 8; e8++) {
                sb[e8] = __shfl(s, e8 << 3);
                wb[e8] = __shfl(wv, (e8 << 3) + myh);
            }
            #pragma unroll
            for (int e8 = 0; e8 < 8; e8++) {
                if (e8 < ne) {
                    uint_t v = ((const uint_t*)(H1f8 + ((long)sb[e8] << 8)))[lane];
                    f32x2 lo = __builtin_amdgcn_cvt_pk_f32_fp8((int)v, false);
                    f32x2 hi = __builtin_amdgcn_cvt_pk_f32_fp8((int)v, true);
                    acc.x += wb[e8] * lo[0];
                    acc.y += wb[e8] * lo[1];
                    acc.z += wb[e8] * hi[0];
                    acc.w += wb[e8] * hi[1];
                }
            }
        }
    }

    float4 bb = ((const float4*)b1)[lane];
    float o0 = fmaxf(acc.x + bb.x, 0.f);
    float o1 = fmaxf(acc.y + bb.y, 0.f);
    float o2 = fmaxf(acc.z + bb.z, 0.f);
    float o3 = fmaxf(acc.w + bb.w, 0.f);
    uint2 ov;
    ov.x = (uint_t)f2bf(o0) | ((uint_t)f2bf(o1) << 16);
    ov.y = (uint_t)f2bf(o2) | ((uint_t)f2bf(o3) << 16);
    ((uint2*)(X1b + ((long)w << 8)))[lane] = ov;
}

// ---------------- GEMM2 (MFMA) + fused alpha2: h2 = x1b @ W2t^T ----------------
__global__ __launch_bounds__(256) void gemm2_k(const ushort_t* __restrict__ X1b,
    const ushort_t* __restrict__ W2t, const float* __restrict__ a2s_w,
    const float* __restrict__ a2d_w, float* __restrict__ H2,
    float* __restrict__ as2, float* __restrict__ ad2, int Nn)
{
    int wid = threadIdx.x >> 6, lane = threadIdx.x & 63;
    int row0 = blockIdx.x * 64 + wid * 16;
    if (row0 >= Nn) return;
    int lm = lane & 15, lg = lane >> 4;
    f32x4 acc = (f32x4){0.f, 0.f, 0.f, 0.f};
    const ushort_t* arow = X1b + (long)(row0 + lm) * 256 + lg * 8;
    const ushort_t* brow = W2t + lm * 256 + lg * 8;
    #pragma unroll
    for (int k0 = 0; k0 < 256; k0 += 32) {
        short8 af = *(const short8*)(arow + k0);
        short8 bf = *(const short8*)(brow + k0);
        acc = __builtin_amdgcn_mfma_f32_16x16x32_bf16(af, bf, acc, 0, 0, 0);
    }
    float a2sv = a2s_w[lm], a2dv = a2d_w[lm];
    #pragma unroll
    for (int r = 0; r < 4; r++) {
        int grow = row0 + lg * 4 + r;
        if (grow < Nn) H2[(grow << 4) + lm] = acc[r];
        float s = acc[r] * a2sv, d2 = acc[r] * a2dv;
        #pragma unroll
        for (int off = 1; off < 16; off <<= 1) {
            s += __shfl_xor(s, off);
            d2 += __shfl_xor(d2, off);
        }
        if (lm == 0 && grow < Nn) { as2[grow] = s; ad2[grow] = d2; }
    }
}

// ---------------- GAT layer 2 aggregate + final softmax (weight-cached) ----------------
__global__ __launch_bounds__(256) void gat2_agg_k(const float* __restrict__ H2,
    const float* __restrict__ as2, const float* __restrict__ ad2,
    const int* __restrict__ offs, const int* __restrict__ srcs,
    const float* __restrict__ b2, float* __restrict__ out, int Nn)
{
    int w = (blockIdx.x << 2) + (threadIdx.x >> 6);
    if (w >= Nn) return;
    int lane = threadIdx.x & 63;
    int beg = offs[w], end = offs[w + 1];
    int deg = end - beg;
    float adv = ad2[w];
    int c = lane & 15, eg = lane >> 4;
    float acc = 0.f;

    if (deg <= 64) {
        int j = beg + lane;
        int s_l = 0; float w_l = 0.f;
        if (j < end) { s_l = srcs[j]; w_l = __expf(lrelu(as2[s_l] + adv)); }
        float d = w_l;
        #pragma unroll
        for (int off = 1; off < 64; off <<= 1) d += __shfl_xor(d, off);
        float w_n = w_l / d;
        for (int j0 = 0; j0 < deg; j0 += 4) {
            int jj = j0 + eg;
            int s = __shfl(s_l, jj);
            float wv = __shfl(w_n, jj);
            if (jj < deg)
                acc += wv * H2[(s << 4) + c];
        }
    } else {
        float d = 0.f;
        for (int j = beg + lane; j < end; j += 64)
            d += __expf(lrelu(as2[srcs[j]] + adv));
        #pragma unroll
        for (int off = 1; off < 64; off <<= 1) d += __shfl_xor(d, off);
        float inv = 1.f / d;
        for (int j0 = beg; j0 < end; j0 += 4) {
            int j = j0 + eg;
            if (j < end) {
                int s = srcs[j];
                float wv = __expf(lrelu(as2[s] + adv)) * inv;
                acc += wv * H2[(s << 4) + c];
            }
        }
    }
    acc += __shfl_xor(acc, 16);
    acc += __shfl_xor(acc, 32);
    float v = acc + b2[c];
    float mx = v;
    #pragma unroll
    for (int off = 1; off < 16; off <<= 1) mx = fmaxf(mx, __shfl_xor(mx, off));
    float ex = __expf(v - mx);
    float se = ex;
    #pragma unroll
    for (int off = 1; off < 16; off <<= 1) se += __shfl_xor(se, off);
    if (eg == 0) out[(w << 4) + c] = ex / se;
}

// ---------------- host launcher ----------------
extern "C" void kernel_launch(void* const* d_in, const int* in_sizes, int n_in,
                              void* d_out, int out_size, void* d_ws, size_t ws_size,
                              hipStream_t stream)
{
    const float* x    = (const float*)d_in[0];
    const int*   ei   = (const int*)d_in[1];
    const float* W1   = (const float*)d_in[2];
    const float* a1s  = (const float*)d_in[3];
    const float* a1d  = (const float*)d_in[4];
    const float* b1   = (const float*)d_in[5];
    const float* W2   = (const float*)d_in[6];
    const float* a2s  = (const float*)d_in[7];
    const float* a2d  = (const float*)d_in[8];
    const float* b2   = (const float*)d_in[9];
    float* out = (float*)d_out;

    int N = in_sizes[0] / HID;
    int E = in_sizes[1] / 2;
    int Etot = E + N;
    const int* src = ei;
    const int* dst = ei + E;

    char* p = (char*)d_ws;
    auto alloc = [&](size_t bytes) {
        void* r = (void*)p;
        p += (bytes + 255) & ~(size_t)255;
        return r;
    };
    ushort_t* xbf  = (ushort_t*)alloc((size_t)N * 256 * 2);
    uchar_t*  h1f8 = (uchar_t*)alloc((size_t)N * 256);
    ushort_t* x1b  = (ushort_t*)alloc((size_t)N * 256 * 2);
    ushort_t* w1t  = (ushort_t*)alloc((size_t)256 * 256 * 2);
    ushort_t* w2t  = (ushort_t*)alloc((size_t)16 * 256 * 2);
    float* h2      = (float*)alloc((size_t)N * 16 * 4);
    float* as1     = (float*)alloc((size_t)N * 8 * 4);
    float* ad1     = (float*)alloc((size_t)N * 8 * 4);
    float* as2v    = (float*)alloc((size_t)N * 4);
    float* ad2v    = (float*)alloc((size_t)N * 4);
    int*   deg     = (int*)alloc((size_t)N * 4);
    int*   incl    = (int*)alloc((size_t)N * 4);
    int*   offs    = (int*)alloc((size_t)(N + 1) * 4);
    int*   bsum    = (int*)alloc(256 * 4);
    int*   bpre    = (int*)alloc(256 * 4);
    int*   srcs    = (int*)alloc((size_t)Etot * 4);
    int*   slot    = (int*)alloc((size_t)Etot * 4);

    int nb = (N + 1023) / 1024;
    int cntB = (E + 1023) / 1024;
    int scat_blocks = (Etot + 1023) / 1024;
    int gemmB = 2 * ((N + 63) / 64);

    // zero deg, then streaming prep (W1t | W2t | Xbf)
    hipMemsetAsync(deg, 0, (size_t)N * 4, stream);
    hipLaunchKernelGGL(prep_k, dim3(65 + 2048), dim3(256), 0, stream,
                       x, xbf, (long)N * 64, W1, w1t, W2, w2t);
    // GEMM1 (MFMA, fused alpha1, fp8 out) + co-scheduled deg count (real edges)
    hipLaunchKernelGGL(gemm1_k, dim3(cntB + gemmB), dim3(256), 0, stream,
                       xbf, w1t, a1s, a1d, h1f8, as1, ad1, N,
                       dst, E, deg, slot, cntB);
    // CSR scans (deg+1 implicit self loop)
    hipLaunchKernelGGL(scan1_k, dim3(nb), dim3(256), 0, stream, deg, incl, bsum, N);
    hipLaunchKernelGGL(scan2_k, dim3(1), dim3(64), 0, stream, bsum, bpre, nb);
    hipLaunchKernelGGL(scan3_k, dim3((N + 255) / 256), dim3(256), 0, stream,
                       incl, deg, bpre, offs, N, Etot);
    // atomic-free scatter (self loop -> last slot)
    hipLaunchKernelGGL(scatter_k, dim3(scat_blocks), dim3(256), 0, stream,
                       src, dst, slot, offs, E, Etot, srcs);
    // layer 1 aggregate (fp8 gather)
    hipLaunchKernelGGL(gat1_agg_k, dim3((N + 3) / 4), dim3(256), 0, stream,
                       h1f8, as1, ad1, offs, srcs, b1, x1b, N);
    // layer 2: MFMA gemm2 + aggregate
    hipLaunchKernelGGL(gemm2_k, dim3((N + 63) / 64), dim3(256), 0, stream,
                       x1b, w2t, a2s, a2d, h2, as2v, ad2v, N);
    hipLaunchKernelGGL(gat2_agg_k, dim3((N + 3) / 4), dim3(256), 0, stream,
                       h2, as2v, ad2v, offs, srcs, b2, out, N);
}

// Round 20
// 180.035 us; speedup vs baseline: 1.3249x; 1.0550x over previous
//
#include <hip/hip_runtime.h>
#include <hip/hip_bf16.h>

#define HID 256
#define H1H 8
#define C1 32
#define C2 16
#define NEG 0.2f

typedef unsigned short ushort_t;
typedef unsigned int uint_t;
typedef unsigned char uchar_t;
typedef __attribute__((ext_vector_type(8))) short short8;
typedef __attribute__((ext_vector_type(4))) float f32x4;
typedef __attribute__((ext_vector_type(2))) float f32x2;

__device__ __forceinline__ float lrelu(float t){ return (t >= 0.f) ? t : NEG * t; }
__device__ __forceinline__ ushort_t f2bf(float f){
    uint_t u = __float_as_uint(f);
    u = (u + 0x7fffu + ((u >> 16) & 1u)) >> 16;   // RNE
    return (ushort_t)u;
}
__device__ __forceinline__ float bf_lo(uint_t p){ return __uint_as_float(p << 16); }
__device__ __forceinline__ float bf_hi(uint_t p){ return __uint_as_float(p & 0xffff0000u); }
__device__ __forceinline__ uchar_t f2fp8(float f){
    int r = __builtin_amdgcn_cvt_pk_fp8_f32(f, f, 0, false);   // OCP e4m3, RNE
    return (uchar_t)(r & 0xFF);
}

#define GLOAD_LDS16(g, l) \
    __builtin_amdgcn_global_load_lds( \
        (const __attribute__((address_space(1))) void*)(g), \
        (__attribute__((address_space(3))) void*)(l), 16, 0, 0)

// ---------------- prep (streaming only): W1t | W2t | Xbf ----------------
__global__ __launch_bounds__(256) void prep_k(const float* __restrict__ X,
                                              ushort_t* __restrict__ Xbf, long n4,
                                              const float* __restrict__ W1,
                                              ushort_t* __restrict__ W1t,
                                              const float* __restrict__ W2,
                                              ushort_t* __restrict__ W2t)
{
    int bid = blockIdx.x;
    int tid = threadIdx.x;
    if (bid < 64) {
        __shared__ ushort_t sh[32][33];
        int bx = bid & 7, by = bid >> 3;                  // k-tile, n-tile
        int tx = tid & 31, ty = tid >> 5;                 // 32 x 8
        #pragma unroll
        for (int i = 0; i < 32; i += 8)
            sh[ty + i][tx] = f2bf(W1[(long)(bx * 32 + ty + i) * 256 + by * 32 + tx]);
        __syncthreads();
        #pragma unroll
        for (int i = 0; i < 32; i += 8)
            W1t[(long)(by * 32 + ty + i) * 256 + bx * 32 + tx] = sh[tx][ty + i];
    } else if (bid == 64) {
        // W2t[c][k] = bf16(W2[k][c]); 4096 elems
        for (int idx = tid; idx < 4096; idx += 256) {
            int k = idx >> 4, c = idx & 15;
            W2t[c * 256 + k] = f2bf(W2[idx]);
        }
    } else {
        long stride = (long)2048 * 256;
        for (long i = (long)(bid - 65) * 256 + tid; i < n4; i += stride) {
            float4 v = ((const float4*)X)[i];
            ushort4 o;
            o.x = f2bf(fmaxf(v.x, 0.f)); o.y = f2bf(fmaxf(v.y, 0.f));
            o.z = f2bf(fmaxf(v.z, 0.f)); o.w = f2bf(fmaxf(v.w, 0.f));
            ((ushort4*)Xbf)[i] = o;
        }
    }
}

// ---------------- GEMM1 (MFMA, 64x128 tile) + co-scheduled deg count (real edges only) ----
__global__ __launch_bounds__(256) void gemm1_k(const ushort_t* __restrict__ Xbf,
                                               const ushort_t* __restrict__ W1t,
                                               const float* __restrict__ a1s_g,
                                               const float* __restrict__ a1d_g,
                                               uchar_t* __restrict__ H1f8,
                                               float* __restrict__ as1,
                                               float* __restrict__ ad1, int M,
                                               const int* __restrict__ dst, int E,
                                               int* __restrict__ deg,
                                               int* __restrict__ slot, int cntB)
{
    __shared__ ushort_t Abuf[64 * 64];    // 8 KiB
    __shared__ ushort_t Bbuf[128 * 64];   // 16 KiB
    int bid = blockIdx.x;
    int tid = threadIdx.x;

    if (bid < cntB) {
        long base = (long)bid * 1024;
        #pragma unroll
        for (int q = 0; q < 4; q++) {
            long i = base + q * 256 + tid;
            if (i < E) slot[i] = atomicAdd(&deg[dst[i]], 1);
        }
        return;
    }

    int bid2 = bid - cntB;
    int bm = (bid2 >> 1) * 64, bn = (bid2 & 1) * 128;
    int wid = tid >> 6, lane = tid & 63;
    int wr = wid >> 1, wc = wid & 1;
    int lg = lane >> 4, lm = lane & 15;

    f32x4 acc[2][4];
    #pragma unroll
    for (int m = 0; m < 2; m++)
        #pragma unroll
        for (int n = 0; n < 4; n++) acc[m][n] = (f32x4){0.f, 0.f, 0.f, 0.f};

    int rA[2], lcA[2];
    #pragma unroll
    for (int q = 0; q < 2; q++) {
        int idx = q * 256 + tid;
        rA[q] = idx >> 3;
        lcA[q] = (idx & 7) ^ (rA[q] & 7);
    }
    int rB[4], lcB[4];
    #pragma unroll
    for (int q = 0; q < 4; q++) {
        int idx = q * 256 + tid;
        rB[q] = idx >> 3;
        lcB[q] = (idx & 7) ^ (rB[q] & 7);
    }

    for (int k0 = 0; k0 < 256; k0 += 64) {
        __syncthreads();
        #pragma unroll
        for (int q = 0; q < 2; q++) {
            const ushort_t* asrc = Xbf + (long)(bm + rA[q]) * 256 + k0 + lcA[q] * 8;
            GLOAD_LDS16(asrc, Abuf + (q * 256 + wid * 64) * 8);
        }
        #pragma unroll
        for (int q = 0; q < 4; q++) {
            const ushort_t* bsrc = W1t + (long)(bn + rB[q]) * 256 + k0 + lcB[q] * 8;
            GLOAD_LDS16(bsrc, Bbuf + (q * 256 + wid * 64) * 8);
        }
        __syncthreads();
        #pragma unroll
        for (int ks = 0; ks < 2; ks++) {
            int kg = ks * 4 + lg;
            short8 af[2], bfr[4];
            #pragma unroll
            for (int m = 0; m < 2; m++) {
                int R = wr * 32 + m * 16 + lm;
                af[m] = *(const short8*)&Abuf[(R * 8 + (kg ^ (R & 7))) * 8];
            }
            #pragma unroll
            for (int n = 0; n < 4; n++) {
                int Cc = wc * 64 + n * 16 + lm;
                bfr[n] = *(const short8*)&Bbuf[(Cc * 8 + (kg ^ (Cc & 7))) * 8];
            }
            #pragma unroll
            for (int m = 0; m < 2; m++)
                #pragma unroll
                for (int n = 0; n < 4; n++)
                    acc[m][n] = __builtin_amdgcn_mfma_f32_16x16x32_bf16(af[m], bfr[n], acc[m][n], 0, 0, 0);
        }
    }

    // fused alpha1
    int h0 = ((bn >> 5) + (wc << 1));
    float as_l0 = a1s_g[h0 * 32 + lm],       as_h0 = a1s_g[h0 * 32 + 16 + lm];
    float as_l1 = a1s_g[(h0 + 1) * 32 + lm], as_h1 = a1s_g[(h0 + 1) * 32 + 16 + lm];
    float ad_l0 = a1d_g[h0 * 32 + lm],       ad_h0 = a1d_g[h0 * 32 + 16 + lm];
    float ad_l1 = a1d_g[(h0 + 1) * 32 + lm], ad_h1 = a1d_g[(h0 + 1) * 32 + 16 + lm];

    #pragma unroll
    for (int m = 0; m < 2; m++) {
        #pragma unroll
        for (int r = 0; r < 4; r++) {
            int gm = bm + wr * 32 + m * 16 + lg * 4 + r;
            float s0 = acc[m][0][r] * as_l0 + acc[m][1][r] * as_h0;
            float s1 = acc[m][2][r] * as_l1 + acc[m][3][r] * as_h1;
            float d0 = acc[m][0][r] * ad_l0 + acc[m][1][r] * ad_h0;
            float d1 = acc[m][2][r] * ad_l1 + acc[m][3][r] * ad_h1;
            #pragma unroll
            for (int off = 1; off < 16; off <<= 1) {
                s0 += __shfl_xor(s0, off);
                s1 += __shfl_xor(s1, off);
                d0 += __shfl_xor(d0, off);
                d1 += __shfl_xor(d1, off);
            }
            if (gm < M) {
                uchar_t* basep = H1f8 + (long)gm * 256 + bn + wc * 64 + lm;
                #pragma unroll
                for (int n = 0; n < 4; n++)
                    basep[n * 16] = f2fp8(acc[m][n][r]);
                if (lm == 0) {
                    float2 sv = {s0, s1}, dv = {d0, d1};
                    *(float2*)&as1[(gm << 3) + h0] = sv;
                    *(float2*)&ad1[(gm << 3) + h0] = dv;
                }
            }
        }
    }
}

// ---------------- CSR scans (segment size = deg + 1 implicit self loop) ----------------
__global__ __launch_bounds__(256) void scan1_k(const int* __restrict__ deg,
                                               int* __restrict__ incl,
                                               int* __restrict__ bsum, int Nn)
{
    __shared__ int sh[256];
    int t = threadIdx.x;
    int base = blockIdx.x * 1024 + t * 4;
    int v0 = (base     < Nn) ? deg[base]     + 1 : 0;
    int v1 = (base + 1 < Nn) ? deg[base + 1] + 1 : 0;
    int v2 = (base + 2 < Nn) ? deg[base + 2] + 1 : 0;
    int v3 = (base + 3 < Nn) ? deg[base + 3] + 1 : 0;
    int s0 = v0, s1 = s0 + v1, s2 = s1 + v2, s3 = s2 + v3;
    sh[t] = s3;
    __syncthreads();
    for (int off = 1; off < 256; off <<= 1) {
        int x = (t >= off) ? sh[t - off] : 0;
        __syncthreads();
        sh[t] += x;
        __syncthreads();
    }
    int prev = (t > 0) ? sh[t - 1] : 0;
    if (base     < Nn) incl[base]     = prev + s0;
    if (base + 1 < Nn) incl[base + 1] = prev + s1;
    if (base + 2 < Nn) incl[base + 2] = prev + s2;
    if (base + 3 < Nn) incl[base + 3] = prev + s3;
    if (t == 255) bsum[blockIdx.x] = sh[255];
}
__global__ void scan2_k(const int* __restrict__ bsum, int* __restrict__ bpre, int nb)
{
    int t = threadIdx.x;                // single wave, nb <= 64
    int own = (t < nb) ? bsum[t] : 0;
    int v = own;
    for (int off = 1; off < 64; off <<= 1) {
        int x = __shfl_up(v, off);
        if (t >= off) v += x;
    }
    if (t < nb) bpre[t] = v - own;      // exclusive
}
__global__ void scan3_k(const int* __restrict__ incl, const int* __restrict__ deg,
                        const int* __restrict__ bpre, int* __restrict__ offs,
                        int Nn, int Etot)
{
    int i = blockIdx.x * 256 + threadIdx.x;
    if (i < Nn) {
        int e = bpre[i >> 10] + incl[i] - (deg[i] + 1);
        offs[i] = e;
    }
    if (i == 0) offs[Nn] = Etot;
}

// ---------------- scatter: atomic-free; self loop statically in last slot ----------------
__global__ __launch_bounds__(256) void scatter_k(const int* __restrict__ src,
    const int* __restrict__ dst, const int* __restrict__ slot,
    const int* __restrict__ offs, int E, int Etot, int* __restrict__ srcs)
{
    long base = (long)blockIdx.x * 1024;
    #pragma unroll
    for (int q = 0; q < 4; q++) {
        long i = base + q * 256 + threadIdx.x;
        if (i < E) {
            int d = dst[i];
            srcs[offs[d] + slot[i]] = src[i];       // offs is L2-resident (200 KB)
        } else if (i < Etot) {
            int n = (int)(i - E);
            srcs[offs[n + 1] - 1] = n;              // self loop -> last slot
        }
    }
}

// ---------------- GAT layer 1 aggregate: wave per dst node (fp8 gather, deep-MLP pass 2) ----
// Pad-based guards: OOB lanes have wv=0 (FMA adds 0) and sv=0 (row 0, L1-hit after
// first touch) -> per-lane guards removed; first 2 batches unconditional (16 loads
// in one burst); batches 2..7 guarded at batch granularity only.
__global__ __launch_bounds__(256) void gat1_agg_k(const uchar_t* __restrict__ H1f8,
    const float* __restrict__ as1, const float* __restrict__ ad1,
    const int* __restrict__ offs, const int* __restrict__ srcs,
    const float* __restrict__ b1, ushort_t* __restrict__ X1b, int Nn)
{
    int w = (blockIdx.x << 2) + (threadIdx.x >> 6);
    if (w >= Nn) return;
    int lane = threadIdx.x & 63;
    int he = lane & 7, el = lane >> 3;
    int myh = lane >> 3;
    int beg = offs[w], end = offs[w + 1];
    int deg = end - beg;
    float adv = ad1[(w << 3) + he];
    float4 acc = {0.f, 0.f, 0.f, 0.f};

    if (deg <= 64) {
        int sv0=0,sv1=0,sv2=0,sv3=0,sv4=0,sv5=0,sv6=0,sv7=0;
        float wv0=0,wv1=0,wv2=0,wv3=0,wv4=0,wv5=0,wv6=0,wv7=0;
        {
            int j;
            j = beg + el;      if (j < end){ sv0 = srcs[j]; wv0 = __expf(lrelu(as1[(sv0<<3)+he]+adv)); }
            j = beg + 8 + el;  if (j < end){ sv1 = srcs[j]; wv1 = __expf(lrelu(as1[(sv1<<3)+he]+adv)); }
            j = beg + 16 + el; if (j < end){ sv2 = srcs[j]; wv2 = __expf(lrelu(as1[(sv2<<3)+he]+adv)); }
            j = beg + 24 + el; if (j < end){ sv3 = srcs[j]; wv3 = __expf(lrelu(as1[(sv3<<3)+he]+adv)); }
            j = beg + 32 + el; if (j < end){ sv4 = srcs[j]; wv4 = __expf(lrelu(as1[(sv4<<3)+he]+adv)); }
            j = beg + 40 + el; if (j < end){ sv5 = srcs[j]; wv5 = __expf(lrelu(as1[(sv5<<3)+he]+adv)); }
            j = beg + 48 + el; if (j < end){ sv6 = srcs[j]; wv6 = __expf(lrelu(as1[(sv6<<3)+he]+adv)); }
            j = beg + 56 + el; if (j < end){ sv7 = srcs[j]; wv7 = __expf(lrelu(as1[(sv7<<3)+he]+adv)); }
        }
        float d = ((wv0 + wv1) + (wv2 + wv3)) + ((wv4 + wv5) + (wv6 + wv7));
        #pragma unroll
        for (int off = 8; off < 64; off <<= 1) d += __shfl_xor(d, off);
        float inv = 1.f / d;
        // normalize on the OWNING lane BEFORE broadcast (pads stay 0)
        wv0 *= inv; wv1 *= inv; wv2 *= inv; wv3 *= inv;
        wv4 *= inv; wv5 *= inv; wv6 *= inv; wv7 *= inv;

        // batches 0+1 unconditional, 16 loads in flight (covers deg<=16 fully)
        {
            int sb[16]; float wb[16];
            #pragma unroll
            for (int e8 = 0; e8 < 8; e8++) {
                sb[e8]     = __shfl(sv0, e8 << 3);
                wb[e8]     = __shfl(wv0, (e8 << 3) + myh);
                sb[e8 + 8] = __shfl(sv1, e8 << 3);
                wb[e8 + 8] = __shfl(wv1, (e8 << 3) + myh);
            }
            uint_t v[16];
            #pragma unroll
            for (int e8 = 0; e8 < 16; e8++)
                v[e8] = ((const uint_t*)(H1f8 + ((long)sb[e8] << 8)))[lane];
            #pragma unroll
            for (int e8 = 0; e8 < 16; e8++) {
                f32x2 lo = __builtin_amdgcn_cvt_pk_f32_fp8((int)v[e8], false);
                f32x2 hi = __builtin_amdgcn_cvt_pk_f32_fp8((int)v[e8], true);
                acc.x += wb[e8] * lo[0];
                acc.y += wb[e8] * lo[1];
                acc.z += wb[e8] * hi[0];
                acc.w += wb[e8] * hi[1];
            }
        }
        // batches 2..7: guarded at batch granularity, loads unguarded (pads benign)
        #define GAT1_BATCH(SV, WV, Q)                                            \
        if (deg > (Q << 3)) {                                                    \
            int sb[8]; float wb[8];                                              \
            _Pragma("unroll")                                                    \
            for (int e8 = 0; e8 < 8; e8++) {                                     \
                sb[e8] = __shfl(SV, e8 << 3);                                    \
                wb[e8] = __shfl(WV, (e8 << 3) + myh);                            \
            }                                                                    \
            uint_t v[8];                                                         \
            _Pragma("unroll")                                                    \
            for (int e8 = 0; e8 < 8; e8++)                                       \
                v[e8] = ((const uint_t*)(H1f8 + ((long)sb[e8] << 8)))[lane];     \
            _Pragma("unroll")                                                    \
            for (int e8 = 0; e8 < 8; e8++) {                                     \
                f32x2 lo = __builtin_amdgcn_cvt_pk_f32_fp8((int)v[e8], false);   \
                f32x2 hi = __builtin_amdgcn_cvt_pk_f32_fp8((int)v[e8], true);    \
                acc.x += wb[e8] * lo[0];                                         \
                acc.y += wb[e8] * lo[1];                                         \
                acc.z += wb[e8] * hi[0];                                         \
                acc.w += wb[e8] * hi[1];                                         \
            }                                                                    \
        }
        GAT1_BATCH(sv2, wv2, 2)
        GAT1_BATCH(sv3, wv3, 3)
        GAT1_BATCH(sv4, wv4, 4)
        GAT1_BATCH(sv5, wv5, 5)
        GAT1_BATCH(sv6, wv6, 6)
        GAT1_BATCH(sv7, wv7, 7)
        #undef GAT1_BATCH
    } else {
        float dA = 0.f, dB = 0.f;
        for (int j0 = beg; j0 < end; j0 += 16) {
            int j = j0 + el, jb = j0 + 8 + el;
            if (j < end)  dA += __expf(lrelu(as1[(srcs[j] << 3) + he] + adv));
            if (jb < end) dB += __expf(lrelu(as1[(srcs[jb] << 3) + he] + adv));
        }
        float d = dA + dB;
        #pragma unroll
        for (int off = 8; off < 64; off <<= 1) d += __shfl_xor(d, off);
        float inv = 1.f / d;
        for (int j0 = beg; j0 < end; j0 += 8) {
            int j = j0 + el;
            int s = 0; float wv = 0.f;
            if (j < end) {
                s = srcs[j];
                wv = __expf(lrelu(as1[(s << 3) + he] + adv)) * inv;
            }
            int ne = min(end - j0, 8);
            int sb[8]; float wb[8];
            #pragma unroll
            for (int e8 = 0; e8 < 8; e8++) {
                sb[e8] = __shfl(s, e8 << 3);
                wb[e8] = __shfl(wv, (e8 << 3) + myh);
            }
            #pragma unroll
            for (int e8 = 0; e8 < 8; e8++) {
                if (e8 < ne) {
                    uint_t v = ((const uint_t*)(H1f8 + ((long)sb[e8] << 8)))[lane];
                    f32x2 lo = __builtin_amdgcn_cvt_pk_f32_fp8((int)v, false);
                    f32x2 hi = __builtin_amdgcn_cvt_pk_f32_fp8((int)v, true);
                    acc.x += wb[e8] * lo[0];
                    acc.y += wb[e8] * lo[1];
                    acc.z += wb[e8] * hi[0];
                    acc.w += wb[e8] * hi[1];
                }
            }
        }
    }

    float4 bb = ((const float4*)b1)[lane];
    float o0 = fmaxf(acc.x + bb.x, 0.f);
    float o1 = fmaxf(acc.y + bb.y, 0.f);
    float o2 = fmaxf(acc.z + bb.z, 0.f);
    float o3 = fmaxf(acc.w + bb.w, 0.f);
    uint2 ov;
    ov.x = (uint_t)f2bf(o0) | ((uint_t)f2bf(o1) << 16);
    ov.y = (uint_t)f2bf(o2) | ((uint_t)f2bf(o3) << 16);
    ((uint2*)(X1b + ((long)w << 8)))[lane] = ov;
}

// ---------------- GEMM2 (MFMA) + fused alpha2: h2 = x1b @ W2t^T ----------------
__global__ __launch_bounds__(256) void gemm2_k(const ushort_t* __restrict__ X1b,
    const ushort_t* __restrict__ W2t, const float* __restrict__ a2s_w,
    const float* __restrict__ a2d_w, float* __restrict__ H2,
    float* __restrict__ as2, float* __restrict__ ad2, int Nn)
{
    int wid = threadIdx.x >> 6, lane = threadIdx.x & 63;
    int row0 = blockIdx.x * 64 + wid * 16;
    if (row0 >= Nn) return;
    int lm = lane & 15, lg = lane >> 4;
    f32x4 acc = (f32x4){0.f, 0.f, 0.f, 0.f};
    const ushort_t* arow = X1b + (long)(row0 + lm) * 256 + lg * 8;
    const ushort_t* brow = W2t + lm * 256 + lg * 8;
    #pragma unroll
    for (int k0 = 0; k0 < 256; k0 += 32) {
        short8 af = *(const short8*)(arow + k0);
        short8 bf = *(const short8*)(brow + k0);
        acc = __builtin_amdgcn_mfma_f32_16x16x32_bf16(af, bf, acc, 0, 0, 0);
    }
    float a2sv = a2s_w[lm], a2dv = a2d_w[lm];
    #pragma unroll
    for (int r = 0; r < 4; r++) {
        int grow = row0 + lg * 4 + r;
        if (grow < Nn) H2[(grow << 4) + lm] = acc[r];
        float s = acc[r] * a2sv, d2 = acc[r] * a2dv;
        #pragma unroll
        for (int off = 1; off < 16; off <<= 1) {
            s += __shfl_xor(s, off);
            d2 += __shfl_xor(d2, off);
        }
        if (lm == 0 && grow < Nn) { as2[grow] = s; ad2[grow] = d2; }
    }
}

// ---------------- GAT layer 2 aggregate + final softmax (weight-cached) ----------------
__global__ __launch_bounds__(256) void gat2_agg_k(const float* __restrict__ H2,
    const float* __restrict__ as2, const float* __restrict__ ad2,
    const int* __restrict__ offs, const int* __restrict__ srcs,
    const float* __restrict__ b2, float* __restrict__ out, int Nn)
{
    int w = (blockIdx.x << 2) + (threadIdx.x >> 6);
    if (w >= Nn) return;
    int lane = threadIdx.x & 63;
    int beg = offs[w], end = offs[w + 1];
    int deg = end - beg;
    float adv = ad2[w];
    int c = lane & 15, eg = lane >> 4;
    float acc = 0.f;

    if (deg <= 64) {
        int j = beg + lane;
        int s_l = 0; float w_l = 0.f;
        if (j < end) { s_l = srcs[j]; w_l = __expf(lrelu(as2[s_l] + adv)); }
        float d = w_l;
        #pragma unroll
        for (int off = 1; off < 64; off <<= 1) d += __shfl_xor(d, off);
        float w_n = w_l / d;
        for (int j0 = 0; j0 < deg; j0 += 4) {
            int jj = j0 + eg;
            int s = __shfl(s_l, jj);
            float wv = __shfl(w_n, jj);
            if (jj < deg)
                acc += wv * H2[(s << 4) + c];
        }
    } else {
        float d = 0.f;
        for (int j = beg + lane; j < end; j += 64)
            d += __expf(lrelu(as2[srcs[j]] + adv));
        #pragma unroll
        for (int off = 1; off < 64; off <<= 1) d += __shfl_xor(d, off);
        float inv = 1.f / d;
        for (int j0 = beg; j0 < end; j0 += 4) {
            int j = j0 + eg;
            if (j < end) {
                int s = srcs[j];
                float wv = __expf(lrelu(as2[s] + adv)) * inv;
                acc += wv * H2[(s << 4) + c];
            }
        }
    }
    acc += __shfl_xor(acc, 16);
    acc += __shfl_xor(acc, 32);
    float v = acc + b2[c];
    float mx = v;
    #pragma unroll
    for (int off = 1; off < 16; off <<= 1) mx = fmaxf(mx, __shfl_xor(mx, off));
    float ex = __expf(v - mx);
    float se = ex;
    #pragma unroll
    for (int off = 1; off < 16; off <<= 1) se += __shfl_xor(se, off);
    if (eg == 0) out[(w << 4) + c] = ex / se;
}

// ---------------- host launcher ----------------
extern "C" void kernel_launch(void* const* d_in, const int* in_sizes, int n_in,
                              void* d_out, int out_size, void* d_ws, size_t ws_size,
                              hipStream_t stream)
{
    const float* x    = (const float*)d_in[0];
    const int*   ei   = (const int*)d_in[1];
    const float* W1   = (const float*)d_in[2];
    const float* a1s  = (const float*)d_in[3];
    const float* a1d  = (const float*)d_in[4];
    const float* b1   = (const float*)d_in[5];
    const float* W2   = (const float*)d_in[6];
    const float* a2s  = (const float*)d_in[7];
    const float* a2d  = (const float*)d_in[8];
    const float* b2   = (const float*)d_in[9];
    float* out = (float*)d_out;

    int N = in_sizes[0] / HID;
    int E = in_sizes[1] / 2;
    int Etot = E + N;
    const int* src = ei;
    const int* dst = ei + E;

    char* p = (char*)d_ws;
    auto alloc = [&](size_t bytes) {
        void* r = (void*)p;
        p += (bytes + 255) & ~(size_t)255;
        return r;
    };
    ushort_t* xbf  = (ushort_t*)alloc((size_t)N * 256 * 2);
    uchar_t*  h1f8 = (uchar_t*)alloc((size_t)N * 256);
    ushort_t* x1b  = (ushort_t*)alloc((size_t)N * 256 * 2);
    ushort_t* w1t  = (ushort_t*)alloc((size_t)256 * 256 * 2);
    ushort_t* w2t  = (ushort_t*)alloc((size_t)16 * 256 * 2);
    float* h2      = (float*)alloc((size_t)N * 16 * 4);
    float* as1     = (float*)alloc((size_t)N * 8 * 4);
    float* ad1     = (float*)alloc((size_t)N * 8 * 4);
    float* as2v    = (float*)alloc((size_t)N * 4);
    float* ad2v    = (float*)alloc((size_t)N * 4);
    int*   deg     = (int*)alloc((size_t)N * 4);
    int*   incl    = (int*)alloc((size_t)N * 4);
    int*   offs    = (int*)alloc((size_t)(N + 1) * 4);
    int*   bsum    = (int*)alloc(256 * 4);
    int*   bpre    = (int*)alloc(256 * 4);
    int*   srcs    = (int*)alloc((size_t)Etot * 4);
    int*   slot    = (int*)alloc((size_t)Etot * 4);

    int nb = (N + 1023) / 1024;
    int cntB = (E + 1023) / 1024;
    int scat_blocks = (Etot + 1023) / 1024;
    int gemmB = 2 * ((N + 63) / 64);

    // zero deg, then streaming prep (W1t | W2t | Xbf)
    hipMemsetAsync(deg, 0, (size_t)N * 4, stream);
    hipLaunchKernelGGL(prep_k, dim3(65 + 2048), dim3(256), 0, stream,
                       x, xbf, (long)N * 64, W1, w1t, W2, w2t);
    // GEMM1 (MFMA, fused alpha1, fp8 out) + co-scheduled deg count (real edges)
    hipLaunchKernelGGL(gemm1_k, dim3(cntB + gemmB), dim3(256), 0, stream,
                       xbf, w1t, a1s, a1d, h1f8, as1, ad1, N,
                       dst, E, deg, slot, cntB);
    // CSR scans (deg+1 implicit self loop)
    hipLaunchKernelGGL(scan1_k, dim3(nb), dim3(256), 0, stream, deg, incl, bsum, N);
    hipLaunchKernelGGL(scan2_k, dim3(1), dim3(64), 0, stream, bsum, bpre, nb);
    hipLaunchKernelGGL(scan3_k, dim3((N + 255) / 256), dim3(256), 0, stream,
                       incl, deg, bpre, offs, N, Etot);
    // atomic-free scatter (self loop -> last slot)
    hipLaunchKernelGGL(scatter_k, dim3(scat_blocks), dim3(256), 0, stream,
                       src, dst, slot, offs, E, Etot, srcs);
    // layer 1 aggregate (fp8 gather, deep-MLP)
    hipLaunchKernelGGL(gat1_agg_k, dim3((N + 3) / 4), dim3(256), 0, stream,
                       h1f8, as1, ad1, offs, srcs, b1, x1b, N);
    // layer 2: MFMA gemm2 + aggregate
    hipLaunchKernelGGL(gemm2_k, dim3((N + 63) / 64), dim3(256), 0, stream,
                       x1b, w2t, a2s, a2d, h2, as2v, ad2v, N);
    hipLaunchKernelGGL(gat2_agg_k, dim3((N + 3) / 4), dim3(256), 0, stream,
                       h2, as2v, ad2v, offs, srcs, b2, out, N);
}

// Round 21
// 171.994 us; speedup vs baseline: 1.3868x; 1.0467x over previous
//
#include <hip/hip_runtime.h>
#include <hip/hip_bf16.h>

#define HID 256
#define H1H 8
#define C1 32
#define C2 16
#define NEG 0.2f

typedef unsigned short ushort_t;
typedef unsigned int uint_t;
typedef unsigned char uchar_t;
typedef __attribute__((ext_vector_type(8))) short short8;
typedef __attribute__((ext_vector_type(4))) float f32x4;
typedef __attribute__((ext_vector_type(2))) float f32x2;

__device__ __forceinline__ float lrelu(float t){ return (t >= 0.f) ? t : NEG * t; }
__device__ __forceinline__ ushort_t f2bf(float f){
    uint_t u = __float_as_uint(f);
    u = (u + 0x7fffu + ((u >> 16) & 1u)) >> 16;   // RNE
    return (ushort_t)u;
}
__device__ __forceinline__ float bf_lo(uint_t p){ return __uint_as_float(p << 16); }
__device__ __forceinline__ float bf_hi(uint_t p){ return __uint_as_float(p & 0xffff0000u); }
__device__ __forceinline__ uchar_t f2fp8(float f){
    int r = __builtin_amdgcn_cvt_pk_fp8_f32(f, f, 0, false);   // OCP e4m3, RNE
    return (uchar_t)(r & 0xFF);
}

#define GLOAD_LDS16(g, l) \
    __builtin_amdgcn_global_load_lds( \
        (const __attribute__((address_space(1))) void*)(g), \
        (__attribute__((address_space(3))) void*)(l), 16, 0, 0)

// ---------------- prep (streaming only): W1t | W2t | Xbf ----------------
__global__ __launch_bounds__(256) void prep_k(const float* __restrict__ X,
                                              ushort_t* __restrict__ Xbf, long n4,
                                              const float* __restrict__ W1,
                                              ushort_t* __restrict__ W1t,
                                              const float* __restrict__ W2,
                                              ushort_t* __restrict__ W2t)
{
    int bid = blockIdx.x;
    int tid = threadIdx.x;
    if (bid < 64) {
        __shared__ ushort_t sh[32][33];
        int bx = bid & 7, by = bid >> 3;                  // k-tile, n-tile
        int tx = tid & 31, ty = tid >> 5;                 // 32 x 8
        #pragma unroll
        for (int i = 0; i < 32; i += 8)
            sh[ty + i][tx] = f2bf(W1[(long)(bx * 32 + ty + i) * 256 + by * 32 + tx]);
        __syncthreads();
        #pragma unroll
        for (int i = 0; i < 32; i += 8)
            W1t[(long)(by * 32 + ty + i) * 256 + bx * 32 + tx] = sh[tx][ty + i];
    } else if (bid == 64) {
        // W2t[c][k] = bf16(W2[k][c]); 4096 elems
        for (int idx = tid; idx < 4096; idx += 256) {
            int k = idx >> 4, c = idx & 15;
            W2t[c * 256 + k] = f2bf(W2[idx]);
        }
    } else {
        long stride = (long)2048 * 256;
        for (long i = (long)(bid - 65) * 256 + tid; i < n4; i += stride) {
            float4 v = ((const float4*)X)[i];
            ushort4 o;
            o.x = f2bf(fmaxf(v.x, 0.f)); o.y = f2bf(fmaxf(v.y, 0.f));
            o.z = f2bf(fmaxf(v.z, 0.f)); o.w = f2bf(fmaxf(v.w, 0.f));
            ((ushort4*)Xbf)[i] = o;
        }
    }
}

// ---------------- GEMM1 (MFMA, 64x128 tile) + co-scheduled deg count (real edges only) ----
__global__ __launch_bounds__(256) void gemm1_k(const ushort_t* __restrict__ Xbf,
                                               const ushort_t* __restrict__ W1t,
                                               const float* __restrict__ a1s_g,
                                               const float* __restrict__ a1d_g,
                                               uchar_t* __restrict__ H1f8,
                                               float* __restrict__ as1,
                                               float* __restrict__ ad1, int M,
                                               const int* __restrict__ dst, int E,
                                               int* __restrict__ deg,
                                               int* __restrict__ slot, int cntB)
{
    __shared__ ushort_t Abuf[64 * 64];    // 8 KiB
    __shared__ ushort_t Bbuf[128 * 64];   // 16 KiB
    int bid = blockIdx.x;
    int tid = threadIdx.x;

    if (bid < cntB) {
        long base = (long)bid * 1024;
        #pragma unroll
        for (int q = 0; q < 4; q++) {
            long i = base + q * 256 + tid;
            if (i < E) slot[i] = atomicAdd(&deg[dst[i]], 1);
        }
        return;
    }

    int bid2 = bid - cntB;
    int bm = (bid2 >> 1) * 64, bn = (bid2 & 1) * 128;
    int wid = tid >> 6, lane = tid & 63;
    int wr = wid >> 1, wc = wid & 1;
    int lg = lane >> 4, lm = lane & 15;

    f32x4 acc[2][4];
    #pragma unroll
    for (int m = 0; m < 2; m++)
        #pragma unroll
        for (int n = 0; n < 4; n++) acc[m][n] = (f32x4){0.f, 0.f, 0.f, 0.f};

    int rA[2], lcA[2];
    #pragma unroll
    for (int q = 0; q < 2; q++) {
        int idx = q * 256 + tid;
        rA[q] = idx >> 3;
        lcA[q] = (idx & 7) ^ (rA[q] & 7);
    }
    int rB[4], lcB[4];
    #pragma unroll
    for (int q = 0; q < 4; q++) {
        int idx = q * 256 + tid;
        rB[q] = idx >> 3;
        lcB[q] = (idx & 7) ^ (rB[q] & 7);
    }

    for (int k0 = 0; k0 < 256; k0 += 64) {
        __syncthreads();
        #pragma unroll
        for (int q = 0; q < 2; q++) {
            const ushort_t* asrc = Xbf + (long)(bm + rA[q]) * 256 + k0 + lcA[q] * 8;
            GLOAD_LDS16(asrc, Abuf + (q * 256 + wid * 64) * 8);
        }
        #pragma unroll
        for (int q = 0; q < 4; q++) {
            const ushort_t* bsrc = W1t + (long)(bn + rB[q]) * 256 + k0 + lcB[q] * 8;
            GLOAD_LDS16(bsrc, Bbuf + (q * 256 + wid * 64) * 8);
        }
        __syncthreads();
        #pragma unroll
        for (int ks = 0; ks < 2; ks++) {
            int kg = ks * 4 + lg;
            short8 af[2], bfr[4];
            #pragma unroll
            for (int m = 0; m < 2; m++) {
                int R = wr * 32 + m * 16 + lm;
                af[m] = *(const short8*)&Abuf[(R * 8 + (kg ^ (R & 7))) * 8];
            }
            #pragma unroll
            for (int n = 0; n < 4; n++) {
                int Cc = wc * 64 + n * 16 + lm;
                bfr[n] = *(const short8*)&Bbuf[(Cc * 8 + (kg ^ (Cc & 7))) * 8];
            }
            #pragma unroll
            for (int m = 0; m < 2; m++)
                #pragma unroll
                for (int n = 0; n < 4; n++)
                    acc[m][n] = __builtin_amdgcn_mfma_f32_16x16x32_bf16(af[m], bfr[n], acc[m][n], 0, 0, 0);
        }
    }

    // fused alpha1
    int h0 = ((bn >> 5) + (wc << 1));
    float as_l0 = a1s_g[h0 * 32 + lm],       as_h0 = a1s_g[h0 * 32 + 16 + lm];
    float as_l1 = a1s_g[(h0 + 1) * 32 + lm], as_h1 = a1s_g[(h0 + 1) * 32 + 16 + lm];
    float ad_l0 = a1d_g[h0 * 32 + lm],       ad_h0 = a1d_g[h0 * 32 + 16 + lm];
    float ad_l1 = a1d_g[(h0 + 1) * 32 + lm], ad_h1 = a1d_g[(h0 + 1) * 32 + 16 + lm];

    #pragma unroll
    for (int m = 0; m < 2; m++) {
        #pragma unroll
        for (int r = 0; r < 4; r++) {
            int gm = bm + wr * 32 + m * 16 + lg * 4 + r;
            float s0 = acc[m][0][r] * as_l0 + acc[m][1][r] * as_h0;
            float s1 = acc[m][2][r] * as_l1 + acc[m][3][r] * as_h1;
            float d0 = acc[m][0][r] * ad_l0 + acc[m][1][r] * ad_h0;
            float d1 = acc[m][2][r] * ad_l1 + acc[m][3][r] * ad_h1;
            #pragma unroll
            for (int off = 1; off < 16; off <<= 1) {
                s0 += __shfl_xor(s0, off);
                s1 += __shfl_xor(s1, off);
                d0 += __shfl_xor(d0, off);
                d1 += __shfl_xor(d1, off);
            }
            if (gm < M) {
                uchar_t* basep = H1f8 + (long)gm * 256 + bn + wc * 64 + lm;
                #pragma unroll
                for (int n = 0; n < 4; n++)
                    basep[n * 16] = f2fp8(acc[m][n][r]);
                if (lm == 0) {
                    float2 sv = {s0, s1}, dv = {d0, d1};
                    *(float2*)&as1[(gm << 3) + h0] = sv;
                    *(float2*)&ad1[(gm << 3) + h0] = dv;
                }
            }
        }
    }
}

// ---------------- CSR scans (segment size = deg + 1 implicit self loop) ----------------
__global__ __launch_bounds__(256) void scan1_k(const int* __restrict__ deg,
                                               int* __restrict__ incl,
                                               int* __restrict__ bsum, int Nn)
{
    __shared__ int sh[256];
    int t = threadIdx.x;
    int base = blockIdx.x * 1024 + t * 4;
    int v0 = (base     < Nn) ? deg[base]     + 1 : 0;
    int v1 = (base + 1 < Nn) ? deg[base + 1] + 1 : 0;
    int v2 = (base + 2 < Nn) ? deg[base + 2] + 1 : 0;
    int v3 = (base + 3 < Nn) ? deg[base + 3] + 1 : 0;
    int s0 = v0, s1 = s0 + v1, s2 = s1 + v2, s3 = s2 + v3;
    sh[t] = s3;
    __syncthreads();
    for (int off = 1; off < 256; off <<= 1) {
        int x = (t >= off) ? sh[t - off] : 0;
        __syncthreads();
        sh[t] += x;
        __syncthreads();
    }
    int prev = (t > 0) ? sh[t - 1] : 0;
    if (base     < Nn) incl[base]     = prev + s0;
    if (base + 1 < Nn) incl[base + 1] = prev + s1;
    if (base + 2 < Nn) incl[base + 2] = prev + s2;
    if (base + 3 < Nn) incl[base + 3] = prev + s3;
    if (t == 255) bsum[blockIdx.x] = sh[255];
}
__global__ void scan2_k(const int* __restrict__ bsum, int* __restrict__ bpre, int nb)
{
    int t = threadIdx.x;                // single wave, nb <= 64
    int own = (t < nb) ? bsum[t] : 0;
    int v = own;
    for (int off = 1; off < 64; off <<= 1) {
        int x = __shfl_up(v, off);
        if (t >= off) v += x;
    }
    if (t < nb) bpre[t] = v - own;      // exclusive
}
__global__ void scan3_k(const int* __restrict__ incl, const int* __restrict__ deg,
                        const int* __restrict__ bpre, int* __restrict__ offs,
                        int Nn, int Etot)
{
    int i = blockIdx.x * 256 + threadIdx.x;
    if (i < Nn) {
        int e = bpre[i >> 10] + incl[i] - (deg[i] + 1);
        offs[i] = e;
    }
    if (i == 0) offs[Nn] = Etot;
}

// ---------------- scatter: atomic-free; 8 edges/thread; self loop -> last slot ----------------
__global__ __launch_bounds__(256) void scatter_k(const int* __restrict__ src,
    const int* __restrict__ dst, const int* __restrict__ slot,
    const int* __restrict__ offs, int E, int Etot, int* __restrict__ srcs)
{
    long base = (long)blockIdx.x * 2048;
    #pragma unroll
    for (int q = 0; q < 8; q++) {
        long i = base + q * 256 + threadIdx.x;
        if (i < E) {
            int d = dst[i];
            srcs[offs[d] + slot[i]] = src[i];       // offs is L2-resident (200 KB)
        } else if (i < Etot) {
            int n = (int)(i - E);
            srcs[offs[n + 1] - 1] = n;              // self loop -> last slot
        }
    }
}

// ---------------- GAT layer 1 aggregate: wave per dst node (fp8 gather, deep-MLP) ----
// Pad-benign guards: OOB lanes have wv=0, sv=0 (row 0, L1-hit). Batches 0+1
// unconditional (16 loads); (2,3),(4,5),(6,7) pairwise-guarded 16-load bursts.
__global__ __launch_bounds__(256) void gat1_agg_k(const uchar_t* __restrict__ H1f8,
    const float* __restrict__ as1, const float* __restrict__ ad1,
    const int* __restrict__ offs, const int* __restrict__ srcs,
    const float* __restrict__ b1, ushort_t* __restrict__ X1b, int Nn)
{
    int w = (blockIdx.x << 2) + (threadIdx.x >> 6);
    if (w >= Nn) return;
    int lane = threadIdx.x & 63;
    int he = lane & 7, el = lane >> 3;
    int myh = lane >> 3;
    int beg = offs[w], end = offs[w + 1];
    int deg = end - beg;
    float adv = ad1[(w << 3) + he];
    float4 acc = {0.f, 0.f, 0.f, 0.f};

    if (deg <= 64) {
        int sv0=0,sv1=0,sv2=0,sv3=0,sv4=0,sv5=0,sv6=0,sv7=0;
        float wv0=0,wv1=0,wv2=0,wv3=0,wv4=0,wv5=0,wv6=0,wv7=0;
        {
            int j;
            j = beg + el;      if (j < end){ sv0 = srcs[j]; wv0 = __expf(lrelu(as1[(sv0<<3)+he]+adv)); }
            j = beg + 8 + el;  if (j < end){ sv1 = srcs[j]; wv1 = __expf(lrelu(as1[(sv1<<3)+he]+adv)); }
            j = beg + 16 + el; if (j < end){ sv2 = srcs[j]; wv2 = __expf(lrelu(as1[(sv2<<3)+he]+adv)); }
            j = beg + 24 + el; if (j < end){ sv3 = srcs[j]; wv3 = __expf(lrelu(as1[(sv3<<3)+he]+adv)); }
            j = beg + 32 + el; if (j < end){ sv4 = srcs[j]; wv4 = __expf(lrelu(as1[(sv4<<3)+he]+adv)); }
            j = beg + 40 + el; if (j < end){ sv5 = srcs[j]; wv5 = __expf(lrelu(as1[(sv5<<3)+he]+adv)); }
            j = beg + 48 + el; if (j < end){ sv6 = srcs[j]; wv6 = __expf(lrelu(as1[(sv6<<3)+he]+adv)); }
            j = beg + 56 + el; if (j < end){ sv7 = srcs[j]; wv7 = __expf(lrelu(as1[(sv7<<3)+he]+adv)); }
        }
        float d = ((wv0 + wv1) + (wv2 + wv3)) + ((wv4 + wv5) + (wv6 + wv7));
        #pragma unroll
        for (int off = 8; off < 64; off <<= 1) d += __shfl_xor(d, off);
        float inv = 1.f / d;
        wv0 *= inv; wv1 *= inv; wv2 *= inv; wv3 *= inv;
        wv4 *= inv; wv5 *= inv; wv6 *= inv; wv7 *= inv;

        // 16-load burst over a batch pair (pads benign)
        #define GAT1_PAIR(SVa, WVa, SVb, WVb)                                    \
        {                                                                        \
            int sb[16]; float wb[16];                                            \
            _Pragma("unroll")                                                    \
            for (int e8 = 0; e8 < 8; e8++) {                                     \
                sb[e8]     = __shfl(SVa, e8 << 3);                               \
                wb[e8]     = __shfl(WVa, (e8 << 3) + myh);                       \
                sb[e8 + 8] = __shfl(SVb, e8 << 3);                               \
                wb[e8 + 8] = __shfl(WVb, (e8 << 3) + myh);                       \
            }                                                                    \
            uint_t v[16];                                                        \
            _Pragma("unroll")                                                    \
            for (int e8 = 0; e8 < 16; e8++)                                      \
                v[e8] = ((const uint_t*)(H1f8 + ((long)sb[e8] << 8)))[lane];     \
            _Pragma("unroll")                                                    \
            for (int e8 = 0; e8 < 16; e8++) {                                    \
                f32x2 lo = __builtin_amdgcn_cvt_pk_f32_fp8((int)v[e8], false);   \
                f32x2 hi = __builtin_amdgcn_cvt_pk_f32_fp8((int)v[e8], true);    \
                acc.x += wb[e8] * lo[0];                                         \
                acc.y += wb[e8] * lo[1];                                         \
                acc.z += wb[e8] * hi[0];                                         \
                acc.w += wb[e8] * hi[1];                                         \
            }                                                                    \
        }
        GAT1_PAIR(sv0, wv0, sv1, wv1)
        if (deg > 16) GAT1_PAIR(sv2, wv2, sv3, wv3)
        if (deg > 32) GAT1_PAIR(sv4, wv4, sv5, wv5)
        if (deg > 48) GAT1_PAIR(sv6, wv6, sv7, wv7)
        #undef GAT1_PAIR
    } else {
        float dA = 0.f, dB = 0.f;
        for (int j0 = beg; j0 < end; j0 += 16) {
            int j = j0 + el, jb = j0 + 8 + el;
            if (j < end)  dA += __expf(lrelu(as1[(srcs[j] << 3) + he] + adv));
            if (jb < end) dB += __expf(lrelu(as1[(srcs[jb] << 3) + he] + adv));
        }
        float d = dA + dB;
        #pragma unroll
        for (int off = 8; off < 64; off <<= 1) d += __shfl_xor(d, off);
        float inv = 1.f / d;
        for (int j0 = beg; j0 < end; j0 += 8) {
            int j = j0 + el;
            int s = 0; float wv = 0.f;
            if (j < end) {
                s = srcs[j];
                wv = __expf(lrelu(as1[(s << 3) + he] + adv)) * inv;
            }
            int ne = min(end - j0, 8);
            int sb[8]; float wb[8];
            #pragma unroll
            for (int e8 = 0; e8 < 8; e8++) {
                sb[e8] = __shfl(s, e8 << 3);
                wb[e8] = __shfl(wv, (e8 << 3) + myh);
            }
            #pragma unroll
            for (int e8 = 0; e8 < 8; e8++) {
                if (e8 < ne) {
                    uint_t v = ((const uint_t*)(H1f8 + ((long)sb[e8] << 8)))[lane];
                    f32x2 lo = __builtin_amdgcn_cvt_pk_f32_fp8((int)v, false);
                    f32x2 hi = __builtin_amdgcn_cvt_pk_f32_fp8((int)v, true);
                    acc.x += wb[e8] * lo[0];
                    acc.y += wb[e8] * lo[1];
                    acc.z += wb[e8] * hi[0];
                    acc.w += wb[e8] * hi[1];
                }
            }
        }
    }

    float4 bb = ((const float4*)b1)[lane];
    float o0 = fmaxf(acc.x + bb.x, 0.f);
    float o1 = fmaxf(acc.y + bb.y, 0.f);
    float o2 = fmaxf(acc.z + bb.z, 0.f);
    float o3 = fmaxf(acc.w + bb.w, 0.f);
    uint2 ov;
    ov.x = (uint_t)f2bf(o0) | ((uint_t)f2bf(o1) << 16);
    ov.y = (uint_t)f2bf(o2) | ((uint_t)f2bf(o3) << 16);
    ((uint2*)(X1b + ((long)w << 8)))[lane] = ov;
}

// ---------------- GEMM2 (MFMA) + fused alpha2: h2 = x1b @ W2t^T ----------------
__global__ __launch_bounds__(256) void gemm2_k(const ushort_t* __restrict__ X1b,
    const ushort_t* __restrict__ W2t, const float* __restrict__ a2s_w,
    const float* __restrict__ a2d_w, float* __restrict__ H2,
    float* __restrict__ as2, float* __restrict__ ad2, int Nn)
{
    int wid = threadIdx.x >> 6, lane = threadIdx.x & 63;
    int row0 = blockIdx.x * 64 + wid * 16;
    if (row0 >= Nn) return;
    int lm = lane & 15, lg = lane >> 4;
    f32x4 acc = (f32x4){0.f, 0.f, 0.f, 0.f};
    const ushort_t* arow = X1b + (long)(row0 + lm) * 256 + lg * 8;
    const ushort_t* brow = W2t + lm * 256 + lg * 8;
    #pragma unroll
    for (int k0 = 0; k0 < 256; k0 += 32) {
        short8 af = *(const short8*)(arow + k0);
        short8 bf = *(const short8*)(brow + k0);
        acc = __builtin_amdgcn_mfma_f32_16x16x32_bf16(af, bf, acc, 0, 0, 0);
    }
    float a2sv = a2s_w[lm], a2dv = a2d_w[lm];
    #pragma unroll
    for (int r = 0; r < 4; r++) {
        int grow = row0 + lg * 4 + r;
        if (grow < Nn) H2[(grow << 4) + lm] = acc[r];
        float s = acc[r] * a2sv, d2 = acc[r] * a2dv;
        #pragma unroll
        for (int off = 1; off < 16; off <<= 1) {
            s += __shfl_xor(s, off);
            d2 += __shfl_xor(d2, off);
        }
        if (lm == 0 && grow < Nn) { as2[grow] = s; ad2[grow] = d2; }
    }
}

// ---------------- GAT layer 2 aggregate + final softmax (deep-MLP pass 2) ----------------
__global__ __launch_bounds__(256) void gat2_agg_k(const float* __restrict__ H2,
    const float* __restrict__ as2, const float* __restrict__ ad2,
    const int* __restrict__ offs, const int* __restrict__ srcs,
    const float* __restrict__ b2, float* __restrict__ out, int Nn)
{
    int w = (blockIdx.x << 2) + (threadIdx.x >> 6);
    if (w >= Nn) return;
    int lane = threadIdx.x & 63;
    int beg = offs[w], end = offs[w + 1];
    int deg = end - beg;
    float adv = ad2[w];
    int c = lane & 15, eg = lane >> 4;
    float acc = 0.f;

    if (deg <= 64) {
        int j = beg + lane;
        int s_l = 0; float w_l = 0.f;
        if (j < end) { s_l = srcs[j]; w_l = __expf(lrelu(as2[s_l] + adv)); }
        float d = w_l;
        #pragma unroll
        for (int off = 1; off < 64; off <<= 1) d += __shfl_xor(d, off);
        float w_n = w_l / d;
        // deep-MLP: 16 edges in flight per iteration; pads benign (w=0, s=row0)
        for (int j0 = 0; j0 < deg; j0 += 16) {
            int s[4]; float wv[4];
            #pragma unroll
            for (int q = 0; q < 4; q++) {
                int jj = j0 + q * 4 + eg;
                s[q]  = __shfl(s_l, jj & 63);
                float t = __shfl(w_n, jj & 63);
                wv[q] = (jj < deg) ? t : 0.f;
            }
            float hv[4];
            #pragma unroll
            for (int q = 0; q < 4; q++)
                hv[q] = H2[(s[q] << 4) + c];
            #pragma unroll
            for (int q = 0; q < 4; q++)
                acc += wv[q] * hv[q];
        }
    } else {
        float d = 0.f;
        for (int j = beg + lane; j < end; j += 64)
            d += __expf(lrelu(as2[srcs[j]] + adv));
        #pragma unroll
        for (int off = 1; off < 64; off <<= 1) d += __shfl_xor(d, off);
        float inv = 1.f / d;
        for (int j0 = beg; j0 < end; j0 += 4) {
            int j = j0 + eg;
            if (j < end) {
                int s = srcs[j];
                float wv = __expf(lrelu(as2[s] + adv)) * inv;
                acc += wv * H2[(s << 4) + c];
            }
        }
    }
    acc += __shfl_xor(acc, 16);
    acc += __shfl_xor(acc, 32);
    float v = acc + b2[c];
    float mx = v;
    #pragma unroll
    for (int off = 1; off < 16; off <<= 1) mx = fmaxf(mx, __shfl_xor(mx, off));
    float ex = __expf(v - mx);
    float se = ex;
    #pragma unroll
    for (int off = 1; off < 16; off <<= 1) se += __shfl_xor(se, off);
    if (eg == 0) out[(w << 4) + c] = ex / se;
}

// ---------------- host launcher ----------------
extern "C" void kernel_launch(void* const* d_in, const int* in_sizes, int n_in,
                              void* d_out, int out_size, void* d_ws, size_t ws_size,
                              hipStream_t stream)
{
    const float* x    = (const float*)d_in[0];
    const int*   ei   = (const int*)d_in[1];
    const float* W1   = (const float*)d_in[2];
    const float* a1s  = (const float*)d_in[3];
    const float* a1d  = (const float*)d_in[4];
    const float* b1   = (const float*)d_in[5];
    const float* W2   = (const float*)d_in[6];
    const float* a2s  = (const float*)d_in[7];
    const float* a2d  = (const float*)d_in[8];
    const float* b2   = (const float*)d_in[9];
    float* out = (float*)d_out;

    int N = in_sizes[0] / HID;
    int E = in_sizes[1] / 2;
    int Etot = E + N;
    const int* src = ei;
    const int* dst = ei + E;

    char* p = (char*)d_ws;
    auto alloc = [&](size_t bytes) {
        void* r = (void*)p;
        p += (bytes + 255) & ~(size_t)255;
        return r;
    };
    ushort_t* xbf  = (ushort_t*)alloc((size_t)N * 256 * 2);
    uchar_t*  h1f8 = (uchar_t*)alloc((size_t)N * 256);
    ushort_t* x1b  = (ushort_t*)alloc((size_t)N * 256 * 2);
    ushort_t* w1t  = (ushort_t*)alloc((size_t)256 * 256 * 2);
    ushort_t* w2t  = (ushort_t*)alloc((size_t)16 * 256 * 2);
    float* h2      = (float*)alloc((size_t)N * 16 * 4);
    float* as1     = (float*)alloc((size_t)N * 8 * 4);
    float* ad1     = (float*)alloc((size_t)N * 8 * 4);
    float* as2v    = (float*)alloc((size_t)N * 4);
    float* ad2v    = (float*)alloc((size_t)N * 4);
    int*   deg     = (int*)alloc((size_t)N * 4);
    int*   incl    = (int*)alloc((size_t)N * 4);
    int*   offs    = (int*)alloc((size_t)(N + 1) * 4);
    int*   bsum    = (int*)alloc(256 * 4);
    int*   bpre    = (int*)alloc(256 * 4);
    int*   srcs    = (int*)alloc((size_t)Etot * 4);
    int*   slot    = (int*)alloc((size_t)Etot * 4);

    int nb = (N + 1023) / 1024;
    int cntB = (E + 1023) / 1024;
    int scat_blocks = (Etot + 2047) / 2048;
    int gemmB = 2 * ((N + 63) / 64);

    // zero deg, then streaming prep (W1t | W2t | Xbf)
    hipMemsetAsync(deg, 0, (size_t)N * 4, stream);
    hipLaunchKernelGGL(prep_k, dim3(65 + 2048), dim3(256), 0, stream,
                       x, xbf, (long)N * 64, W1, w1t, W2, w2t);
    // GEMM1 (MFMA, fused alpha1, fp8 out) + co-scheduled deg count (real edges)
    hipLaunchKernelGGL(gemm1_k, dim3(cntB + gemmB), dim3(256), 0, stream,
                       xbf, w1t, a1s, a1d, h1f8, as1, ad1, N,
                       dst, E, deg, slot, cntB);
    // CSR scans (deg+1 implicit self loop)
    hipLaunchKernelGGL(scan1_k, dim3(nb), dim3(256), 0, stream, deg, incl, bsum, N);
    hipLaunchKernelGGL(scan2_k, dim3(1), dim3(64), 0, stream, bsum, bpre, nb);
    hipLaunchKernelGGL(scan3_k, dim3((N + 255) / 256), dim3(256), 0, stream,
                       incl, deg, bpre, offs, N, Etot);
    // atomic-free scatter (self loop -> last slot)
    hipLaunchKernelGGL(scatter_k, dim3(scat_blocks), dim3(256), 0, stream,
                       src, dst, slot, offs, E, Etot, srcs);
    // layer 1 aggregate (fp8 gather, deep-MLP)
    hipLaunchKernelGGL(gat1_agg_k, dim3((N + 3) / 4), dim3(256), 0, stream,
                       h1f8, as1, ad1, offs, srcs, b1, x1b, N);
    // layer 2: MFMA gemm2 + aggregate
    hipLaunchKernelGGL(gemm2_k, dim3((N + 63) / 64), dim3(256), 0, stream,
                       x1b, w2t, a2s, a2d, h2, as2v, ad2v, N);
    hipLaunchKernelGGL(gat2_agg_k, dim3((N + 3) / 4), dim3(256), 0, stream,
                       h2, as2v, ad2v, offs, srcs, b2, out, N);
}

// Round 22
// 163.142 us; speedup vs baseline: 1.4621x; 1.0543x over previous
//
#include <hip/hip_runtime.h>
#include <hip/hip_bf16.h>

#define HID 256
#define H1H 8
#define C1 32
#define C2 16
#define NEG 0.2f

typedef unsigned short ushort_t;
typedef unsigned int uint_t;
typedef unsigned char uchar_t;
typedef __attribute__((ext_vector_type(8))) short short8;
typedef __attribute__((ext_vector_type(4))) float f32x4;
typedef __attribute__((ext_vector_type(2))) float f32x2;

__device__ __forceinline__ float lrelu(float t){ return (t >= 0.f) ? t : NEG * t; }
__device__ __forceinline__ ushort_t f2bf(float f){
    uint_t u = __float_as_uint(f);
    u = (u + 0x7fffu + ((u >> 16) & 1u)) >> 16;   // RNE
    return (ushort_t)u;
}
__device__ __forceinline__ float bf_lo(uint_t p){ return __uint_as_float(p << 16); }
__device__ __forceinline__ float bf_hi(uint_t p){ return __uint_as_float(p & 0xffff0000u); }
__device__ __forceinline__ uchar_t f2fp8(float f){
    int r = __builtin_amdgcn_cvt_pk_fp8_f32(f, f, 0, false);   // OCP e4m3, RNE
    return (uchar_t)(r & 0xFF);
}

#define GLOAD_LDS16(g, l) \
    __builtin_amdgcn_global_load_lds( \
        (const __attribute__((address_space(1))) void*)(g), \
        (__attribute__((address_space(3))) void*)(l), 16, 0, 0)

// ---------------- prep: deg count (edges [0,Ehalf), FIRST) | W1t | W2t | Xbf stream ----
// deg must be zeroed (hipMemsetAsync) BEFORE this kernel.
__global__ __launch_bounds__(256) void prep_k(const float* __restrict__ X,
                                              ushort_t* __restrict__ Xbf, long n4,
                                              const float* __restrict__ W1,
                                              ushort_t* __restrict__ W1t,
                                              const float* __restrict__ W2,
                                              ushort_t* __restrict__ W2t,
                                              const int* __restrict__ dst, int Ehalf,
                                              int* __restrict__ deg,
                                              int* __restrict__ slot, int cntB0)
{
    int bid = blockIdx.x;
    int tid = threadIdx.x;
    if (bid < cntB0) {
        // ---- deg count + slot over [0, Ehalf): 4 independent atomic chains/thread ----
        long base = (long)bid * 1024;
        #pragma unroll
        for (int q = 0; q < 4; q++) {
            long i = base + q * 256 + tid;
            if (i < Ehalf) slot[i] = atomicAdd(&deg[dst[i]], 1);
        }
    } else if (bid < cntB0 + 64) {
        int b = bid - cntB0;
        __shared__ ushort_t sh[32][33];
        int bx = b & 7, by = b >> 3;                      // k-tile, n-tile
        int tx = tid & 31, ty = tid >> 5;                 // 32 x 8
        #pragma unroll
        for (int i = 0; i < 32; i += 8)
            sh[ty + i][tx] = f2bf(W1[(long)(bx * 32 + ty + i) * 256 + by * 32 + tx]);
        __syncthreads();
        #pragma unroll
        for (int i = 0; i < 32; i += 8)
            W1t[(long)(by * 32 + ty + i) * 256 + bx * 32 + tx] = sh[tx][ty + i];
    } else if (bid == cntB0 + 64) {
        // W2t[c][k] = bf16(W2[k][c]); 4096 elems
        for (int idx = tid; idx < 4096; idx += 256) {
            int k = idx >> 4, c = idx & 15;
            W2t[c * 256 + k] = f2bf(W2[idx]);
        }
    } else {
        long stride = (long)2048 * 256;
        for (long i = (long)(bid - cntB0 - 65) * 256 + tid; i < n4; i += stride) {
            float4 v = ((const float4*)X)[i];
            ushort4 o;
            o.x = f2bf(fmaxf(v.x, 0.f)); o.y = f2bf(fmaxf(v.y, 0.f));
            o.z = f2bf(fmaxf(v.z, 0.f)); o.w = f2bf(fmaxf(v.w, 0.f));
            ((ushort4*)Xbf)[i] = o;
        }
    }
}

// ---------------- GEMM1 (MFMA, 64x128 tile) + co-scheduled deg count (edges [Ehalf,E)) ----
__global__ __launch_bounds__(256) void gemm1_k(const ushort_t* __restrict__ Xbf,
                                               const ushort_t* __restrict__ W1t,
                                               const float* __restrict__ a1s_g,
                                               const float* __restrict__ a1d_g,
                                               uchar_t* __restrict__ H1f8,
                                               float* __restrict__ as1,
                                               float* __restrict__ ad1, int M,
                                               const int* __restrict__ dst,
                                               int Ehalf, int E,
                                               int* __restrict__ deg,
                                               int* __restrict__ slot, int cntB)
{
    __shared__ ushort_t Abuf[64 * 64];    // 8 KiB
    __shared__ ushort_t Bbuf[128 * 64];   // 16 KiB
    int bid = blockIdx.x;
    int tid = threadIdx.x;

    if (bid < cntB) {
        long base = Ehalf + (long)bid * 1024;
        #pragma unroll
        for (int q = 0; q < 4; q++) {
            long i = base + q * 256 + tid;
            if (i < E) slot[i] = atomicAdd(&deg[dst[i]], 1);
        }
        return;
    }

    int bid2 = bid - cntB;
    int bm = (bid2 >> 1) * 64, bn = (bid2 & 1) * 128;
    int wid = tid >> 6, lane = tid & 63;
    int wr = wid >> 1, wc = wid & 1;
    int lg = lane >> 4, lm = lane & 15;

    f32x4 acc[2][4];
    #pragma unroll
    for (int m = 0; m < 2; m++)
        #pragma unroll
        for (int n = 0; n < 4; n++) acc[m][n] = (f32x4){0.f, 0.f, 0.f, 0.f};

    int rA[2], lcA[2];
    #pragma unroll
    for (int q = 0; q < 2; q++) {
        int idx = q * 256 + tid;
        rA[q] = idx >> 3;
        lcA[q] = (idx & 7) ^ (rA[q] & 7);
    }
    int rB[4], lcB[4];
    #pragma unroll
    for (int q = 0; q < 4; q++) {
        int idx = q * 256 + tid;
        rB[q] = idx >> 3;
        lcB[q] = (idx & 7) ^ (rB[q] & 7);
    }

    for (int k0 = 0; k0 < 256; k0 += 64) {
        __syncthreads();
        #pragma unroll
        for (int q = 0; q < 2; q++) {
            const ushort_t* asrc = Xbf + (long)(bm + rA[q]) * 256 + k0 + lcA[q] * 8;
            GLOAD_LDS16(asrc, Abuf + (q * 256 + wid * 64) * 8);
        }
        #pragma unroll
        for (int q = 0; q < 4; q++) {
            const ushort_t* bsrc = W1t + (long)(bn + rB[q]) * 256 + k0 + lcB[q] * 8;
            GLOAD_LDS16(bsrc, Bbuf + (q * 256 + wid * 64) * 8);
        }
        __syncthreads();
        #pragma unroll
        for (int ks = 0; ks < 2; ks++) {
            int kg = ks * 4 + lg;
            short8 af[2], bfr[4];
            #pragma unroll
            for (int m = 0; m < 2; m++) {
                int R = wr * 32 + m * 16 + lm;
                af[m] = *(const short8*)&Abuf[(R * 8 + (kg ^ (R & 7))) * 8];
            }
            #pragma unroll
            for (int n = 0; n < 4; n++) {
                int Cc = wc * 64 + n * 16 + lm;
                bfr[n] = *(const short8*)&Bbuf[(Cc * 8 + (kg ^ (Cc & 7))) * 8];
            }
            #pragma unroll
            for (int m = 0; m < 2; m++)
                #pragma unroll
                for (int n = 0; n < 4; n++)
                    acc[m][n] = __builtin_amdgcn_mfma_f32_16x16x32_bf16(af[m], bfr[n], acc[m][n], 0, 0, 0);
        }
    }

    // fused alpha1
    int h0 = ((bn >> 5) + (wc << 1));
    float as_l0 = a1s_g[h0 * 32 + lm],       as_h0 = a1s_g[h0 * 32 + 16 + lm];
    float as_l1 = a1s_g[(h0 + 1) * 32 + lm], as_h1 = a1s_g[(h0 + 1) * 32 + 16 + lm];
    float ad_l0 = a1d_g[h0 * 32 + lm],       ad_h0 = a1d_g[h0 * 32 + 16 + lm];
    float ad_l1 = a1d_g[(h0 + 1) * 32 + lm], ad_h1 = a1d_g[(h0 + 1) * 32 + 16 + lm];

    #pragma unroll
    for (int m = 0; m < 2; m++) {
        #pragma unroll
        for (int r = 0; r < 4; r++) {
            int gm = bm + wr * 32 + m * 16 + lg * 4 + r;
            float s0 = acc[m][0][r] * as_l0 + acc[m][1][r] * as_h0;
            float s1 = acc[m][2][r] * as_l1 + acc[m][3][r] * as_h1;
            float d0 = acc[m][0][r] * ad_l0 + acc[m][1][r] * ad_h0;
            float d1 = acc[m][2][r] * ad_l1 + acc[m][3][r] * ad_h1;
            #pragma unroll
            for (int off = 1; off < 16; off <<= 1) {
                s0 += __shfl_xor(s0, off);
                s1 += __shfl_xor(s1, off);
                d0 += __shfl_xor(d0, off);
                d1 += __shfl_xor(d1, off);
            }
            if (gm < M) {
                uchar_t* basep = H1f8 + (long)gm * 256 + bn + wc * 64 + lm;
                #pragma unroll
                for (int n = 0; n < 4; n++)
                    basep[n * 16] = f2fp8(acc[m][n][r]);
                if (lm == 0) {
                    float2 sv = {s0, s1}, dv = {d0, d1};
                    *(float2*)&as1[(gm << 3) + h0] = sv;
                    *(float2*)&ad1[(gm << 3) + h0] = dv;
                }
            }
        }
    }
}

// ---------------- CSR scans (segment size = deg + 1 implicit self loop) ----------------
__global__ __launch_bounds__(256) void scan1_k(const int* __restrict__ deg,
                                               int* __restrict__ incl,
                                               int* __restrict__ bsum, int Nn)
{
    __shared__ int sh[256];
    int t = threadIdx.x;
    int base = blockIdx.x * 1024 + t * 4;
    int v0 = (base     < Nn) ? deg[base]     + 1 : 0;
    int v1 = (base + 1 < Nn) ? deg[base + 1] + 1 : 0;
    int v2 = (base + 2 < Nn) ? deg[base + 2] + 1 : 0;
    int v3 = (base + 3 < Nn) ? deg[base + 3] + 1 : 0;
    int s0 = v0, s1 = s0 + v1, s2 = s1 + v2, s3 = s2 + v3;
    sh[t] = s3;
    __syncthreads();
    for (int off = 1; off < 256; off <<= 1) {
        int x = (t >= off) ? sh[t - off] : 0;
        __syncthreads();
        sh[t] += x;
        __syncthreads();
    }
    int prev = (t > 0) ? sh[t - 1] : 0;
    if (base     < Nn) incl[base]     = prev + s0;
    if (base + 1 < Nn) incl[base + 1] = prev + s1;
    if (base + 2 < Nn) incl[base + 2] = prev + s2;
    if (base + 3 < Nn) incl[base + 3] = prev + s3;
    if (t == 255) bsum[blockIdx.x] = sh[255];
}
__global__ void scan2_k(const int* __restrict__ bsum, int* __restrict__ bpre, int nb)
{
    int t = threadIdx.x;                // single wave, nb <= 64
    int own = (t < nb) ? bsum[t] : 0;
    int v = own;
    for (int off = 1; off < 64; off <<= 1) {
        int x = __shfl_up(v, off);
        if (t >= off) v += x;
    }
    if (t < nb) bpre[t] = v - own;      // exclusive
}
__global__ void scan3_k(const int* __restrict__ incl, const int* __restrict__ deg,
                        const int* __restrict__ bpre, int* __restrict__ offs,
                        int Nn, int Etot)
{
    int i = blockIdx.x * 256 + threadIdx.x;
    if (i < Nn) {
        int e = bpre[i >> 10] + incl[i] - (deg[i] + 1);
        offs[i] = e;
    }
    if (i == 0) offs[Nn] = Etot;
}

// ---------------- scatter: atomic-free; 8 edges/thread; self loop -> last slot ----------------
__global__ __launch_bounds__(256) void scatter_k(const int* __restrict__ src,
    const int* __restrict__ dst, const int* __restrict__ slot,
    const int* __restrict__ offs, int E, int Etot, int* __restrict__ srcs)
{
    long base = (long)blockIdx.x * 2048;
    #pragma unroll
    for (int q = 0; q < 8; q++) {
        long i = base + q * 256 + threadIdx.x;
        if (i < E) {
            int d = dst[i];
            srcs[offs[d] + slot[i]] = src[i];       // offs is L2-resident (200 KB)
        } else if (i < Etot) {
            int n = (int)(i - E);
            srcs[offs[n + 1] - 1] = n;              // self loop -> last slot
        }
    }
}

// ---------------- GAT layer 1 aggregate: wave per dst node (fp8 gather, deep-MLP) ----
__global__ __launch_bounds__(256) void gat1_agg_k(const uchar_t* __restrict__ H1f8,
    const float* __restrict__ as1, const float* __restrict__ ad1,
    const int* __restrict__ offs, const int* __restrict__ srcs,
    const float* __restrict__ b1, ushort_t* __restrict__ X1b, int Nn)
{
    int w = (blockIdx.x << 2) + (threadIdx.x >> 6);
    if (w >= Nn) return;
    int lane = threadIdx.x & 63;
    int he = lane & 7, el = lane >> 3;
    int myh = lane >> 3;
    int beg = offs[w], end = offs[w + 1];
    int deg = end - beg;
    float adv = ad1[(w << 3) + he];
    float4 acc = {0.f, 0.f, 0.f, 0.f};

    if (deg <= 64) {
        int sv0=0,sv1=0,sv2=0,sv3=0,sv4=0,sv5=0,sv6=0,sv7=0;
        float wv0=0,wv1=0,wv2=0,wv3=0,wv4=0,wv5=0,wv6=0,wv7=0;
        {
            int j;
            j = beg + el;      if (j < end){ sv0 = srcs[j]; wv0 = __expf(lrelu(as1[(sv0<<3)+he]+adv)); }
            j = beg + 8 + el;  if (j < end){ sv1 = srcs[j]; wv1 = __expf(lrelu(as1[(sv1<<3)+he]+adv)); }
            j = beg + 16 + el; if (j < end){ sv2 = srcs[j]; wv2 = __expf(lrelu(as1[(sv2<<3)+he]+adv)); }
            j = beg + 24 + el; if (j < end){ sv3 = srcs[j]; wv3 = __expf(lrelu(as1[(sv3<<3)+he]+adv)); }
            j = beg + 32 + el; if (j < end){ sv4 = srcs[j]; wv4 = __expf(lrelu(as1[(sv4<<3)+he]+adv)); }
            j = beg + 40 + el; if (j < end){ sv5 = srcs[j]; wv5 = __expf(lrelu(as1[(sv5<<3)+he]+adv)); }
            j = beg + 48 + el; if (j < end){ sv6 = srcs[j]; wv6 = __expf(lrelu(as1[(sv6<<3)+he]+adv)); }
            j = beg + 56 + el; if (j < end){ sv7 = srcs[j]; wv7 = __expf(lrelu(as1[(sv7<<3)+he]+adv)); }
        }
        float d = ((wv0 + wv1) + (wv2 + wv3)) + ((wv4 + wv5) + (wv6 + wv7));
        #pragma unroll
        for (int off = 8; off < 64; off <<= 1) d += __shfl_xor(d, off);
        float inv = 1.f / d;
        wv0 *= inv; wv1 *= inv; wv2 *= inv; wv3 *= inv;
        wv4 *= inv; wv5 *= inv; wv6 *= inv; wv7 *= inv;

        #define GAT1_PAIR(SVa, WVa, SVb, WVb)                                    \
        {                                                                        \
            int sb[16]; float wb[16];                                            \
            _Pragma("unroll")                                                    \
            for (int e8 = 0; e8 < 8; e8++) {                                     \
                sb[e8]     = __shfl(SVa, e8 << 3);                               \
                wb[e8]     = __shfl(WVa, (e8 << 3) + myh);                       \
                sb[e8 + 8] = __shfl(SVb, e8 << 3);                               \
                wb[e8 + 8] = __shfl(WVb, (e8 << 3) + myh);                       \
            }                                                                    \
            uint_t v[16];                                                        \
            _Pragma("unroll")                                                    \
            for (int e8 = 0; e8 < 16; e8++)                                      \
                v[e8] = ((const uint_t*)(H1f8 + ((long)sb[e8] << 8)))[lane];     \
            _Pragma("unroll")                                                    \
            for (int e8 = 0; e8 < 16; e8++) {                                    \
                f32x2 lo = __builtin_amdgcn_cvt_pk_f32_fp8((int)v[e8], false);   \
                f32x2 hi = __builtin_amdgcn_cvt_pk_f32_fp8((int)v[e8], true);    \
                acc.x += wb[e8] * lo[0];                                         \
                acc.y += wb[e8] * lo[1];                                         \
                acc.z += wb[e8] * hi[0];                                         \
                acc.w += wb[e8] * hi[1];                                         \
            }                                                                    \
        }
        GAT1_PAIR(sv0, wv0, sv1, wv1)
        if (deg > 16) GAT1_PAIR(sv2, wv2, sv3, wv3)
        if (deg > 32) GAT1_PAIR(sv4, wv4, sv5, wv5)
        if (deg > 48) GAT1_PAIR(sv6, wv6, sv7, wv7)
        #undef GAT1_PAIR
    } else {
        float dA = 0.f, dB = 0.f;
        for (int j0 = beg; j0 < end; j0 += 16) {
            int j = j0 + el, jb = j0 + 8 + el;
            if (j < end)  dA += __expf(lrelu(as1[(srcs[j] << 3) + he] + adv));
            if (jb < end) dB += __expf(lrelu(as1[(srcs[jb] << 3) + he] + adv));
        }
        float d = dA + dB;
        #pragma unroll
        for (int off = 8; off < 64; off <<= 1) d += __shfl_xor(d, off);
        float inv = 1.f / d;
        for (int j0 = beg; j0 < end; j0 += 8) {
            int j = j0 + el;
            int s = 0; float wv = 0.f;
            if (j < end) {
                s = srcs[j];
                wv = __expf(lrelu(as1[(s << 3) + he] + adv)) * inv;
            }
            int ne = min(end - j0, 8);
            int sb[8]; float wb[8];
            #pragma unroll
            for (int e8 = 0; e8 < 8; e8++) {
                sb[e8] = __shfl(s, e8 << 3);
                wb[e8] = __shfl(wv, (e8 << 3) + myh);
            }
            #pragma unroll
            for (int e8 = 0; e8 < 8; e8++) {
                if (e8 < ne) {
                    uint_t v = ((const uint_t*)(H1f8 + ((long)sb[e8] << 8)))[lane];
                    f32x2 lo = __builtin_amdgcn_cvt_pk_f32_fp8((int)v, false);
                    f32x2 hi = __builtin_amdgcn_cvt_pk_f32_fp8((int)v, true);
                    acc.x += wb[e8] * lo[0];
                    acc.y += wb[e8] * lo[1];
                    acc.z += wb[e8] * hi[0];
                    acc.w += wb[e8] * hi[1];
                }
            }
        }
    }

    float4 bb = ((const float4*)b1)[lane];
    float o0 = fmaxf(acc.x + bb.x, 0.f);
    float o1 = fmaxf(acc.y + bb.y, 0.f);
    float o2 = fmaxf(acc.z + bb.z, 0.f);
    float o3 = fmaxf(acc.w + bb.w, 0.f);
    uint2 ov;
    ov.x = (uint_t)f2bf(o0) | ((uint_t)f2bf(o1) << 16);
    ov.y = (uint_t)f2bf(o2) | ((uint_t)f2bf(o3) << 16);
    ((uint2*)(X1b + ((long)w << 8)))[lane] = ov;
}

// ---------------- GEMM2 (MFMA) + fused alpha2: h2 = x1b @ W2t^T ----------------
__global__ __launch_bounds__(256) void gemm2_k(const ushort_t* __restrict__ X1b,
    const ushort_t* __restrict__ W2t, const float* __restrict__ a2s_w,
    const float* __restrict__ a2d_w, float* __restrict__ H2,
    float* __restrict__ as2, float* __restrict__ ad2, int Nn)
{
    int wid = threadIdx.x >> 6, lane = threadIdx.x & 63;
    int row0 = blockIdx.x * 64 + wid * 16;
    if (row0 >= Nn) return;
    int lm = lane & 15, lg = lane >> 4;
    f32x4 acc = (f32x4){0.f, 0.f, 0.f, 0.f};
    const ushort_t* arow = X1b + (long)(row0 + lm) * 256 + lg * 8;
    const ushort_t* brow = W2t + lm * 256 + lg * 8;
    #pragma unroll
    for (int k0 = 0; k0 < 256; k0 += 32) {
        short8 af = *(const short8*)(arow + k0);
        short8 bf = *(const short8*)(brow + k0);
        acc = __builtin_amdgcn_mfma_f32_16x16x32_bf16(af, bf, acc, 0, 0, 0);
    }
    float a2sv = a2s_w[lm], a2dv = a2d_w[lm];
    #pragma unroll
    for (int r = 0; r < 4; r++) {
        int grow = row0 + lg * 4 + r;
        if (grow < Nn) H2[(grow << 4) + lm] = acc[r];
        float s = acc[r] * a2sv, d2 = acc[r] * a2dv;
        #pragma unroll
        for (int off = 1; off < 16; off <<= 1) {
            s += __shfl_xor(s, off);
            d2 += __shfl_xor(d2, off);
        }
        if (lm == 0 && grow < Nn) { as2[grow] = s; ad2[grow] = d2; }
    }
}

// ---------------- GAT layer 2 aggregate + final softmax (deep-MLP pass 2) ----------------
__global__ __launch_bounds__(256) void gat2_agg_k(const float* __restrict__ H2,
    const float* __restrict__ as2, const float* __restrict__ ad2,
    const int* __restrict__ offs, const int* __restrict__ srcs,
    const float* __restrict__ b2, float* __restrict__ out, int Nn)
{
    int w = (blockIdx.x << 2) + (threadIdx.x >> 6);
    if (w >= Nn) return;
    int lane = threadIdx.x & 63;
    int beg = offs[w], end = offs[w + 1];
    int deg = end - beg;
    float adv = ad2[w];
    int c = lane & 15, eg = lane >> 4;
    float acc = 0.f;

    if (deg <= 64) {
        int j = beg + lane;
        int s_l = 0; float w_l = 0.f;
        if (j < end) { s_l = srcs[j]; w_l = __expf(lrelu(as2[s_l] + adv)); }
        float d = w_l;
        #pragma unroll
        for (int off = 1; off < 64; off <<= 1) d += __shfl_xor(d, off);
        float w_n = w_l / d;
        for (int j0 = 0; j0 < deg; j0 += 16) {
            int s[4]; float wv[4];
            #pragma unroll
            for (int q = 0; q < 4; q++) {
                int jj = j0 + q * 4 + eg;
                s[q]  = __shfl(s_l, jj & 63);
                float t = __shfl(w_n, jj & 63);
                wv[q] = (jj < deg) ? t : 0.f;
            }
            float hv[4];
            #pragma unroll
            for (int q = 0; q < 4; q++)
                hv[q] = H2[(s[q] << 4) + c];
            #pragma unroll
            for (int q = 0; q < 4; q++)
                acc += wv[q] * hv[q];
        }
    } else {
        float d = 0.f;
        for (int j = beg + lane; j < end; j += 64)
            d += __expf(lrelu(as2[srcs[j]] + adv));
        #pragma unroll
        for (int off = 1; off < 64; off <<= 1) d += __shfl_xor(d, off);
        float inv = 1.f / d;
        for (int j0 = beg; j0 < end; j0 += 4) {
            int j = j0 + eg;
            if (j < end) {
                int s = srcs[j];
                float wv = __expf(lrelu(as2[s] + adv)) * inv;
                acc += wv * H2[(s << 4) + c];
            }
        }
    }
    acc += __shfl_xor(acc, 16);
    acc += __shfl_xor(acc, 32);
    float v = acc + b2[c];
    float mx = v;
    #pragma unroll
    for (int off = 1; off < 16; off <<= 1) mx = fmaxf(mx, __shfl_xor(mx, off));
    float ex = __expf(v - mx);
    float se = ex;
    #pragma unroll
    for (int off = 1; off < 16; off <<= 1) se += __shfl_xor(se, off);
    if (eg == 0) out[(w << 4) + c] = ex / se;
}

// ---------------- host launcher ----------------
extern "C" void kernel_launch(void* const* d_in, const int* in_sizes, int n_in,
                              void* d_out, int out_size, void* d_ws, size_t ws_size,
                              hipStream_t stream)
{
    const float* x    = (const float*)d_in[0];
    const int*   ei   = (const int*)d_in[1];
    const float* W1   = (const float*)d_in[2];
    const float* a1s  = (const float*)d_in[3];
    const float* a1d  = (const float*)d_in[4];
    const float* b1   = (const float*)d_in[5];
    const float* W2   = (const float*)d_in[6];
    const float* a2s  = (const float*)d_in[7];
    const float* a2d  = (const float*)d_in[8];
    const float* b2   = (const float*)d_in[9];
    float* out = (float*)d_out;

    int N = in_sizes[0] / HID;
    int E = in_sizes[1] / 2;
    int Etot = E + N;
    const int* src = ei;
    const int* dst = ei + E;

    char* p = (char*)d_ws;
    auto alloc = [&](size_t bytes) {
        void* r = (void*)p;
        p += (bytes + 255) & ~(size_t)255;
        return r;
    };
    ushort_t* xbf  = (ushort_t*)alloc((size_t)N * 256 * 2);
    uchar_t*  h1f8 = (uchar_t*)alloc((size_t)N * 256);
    ushort_t* x1b  = (ushort_t*)alloc((size_t)N * 256 * 2);
    ushort_t* w1t  = (ushort_t*)alloc((size_t)256 * 256 * 2);
    ushort_t* w2t  = (ushort_t*)alloc((size_t)16 * 256 * 2);
    float* h2      = (float*)alloc((size_t)N * 16 * 4);
    float* as1     = (float*)alloc((size_t)N * 8 * 4);
    float* ad1     = (float*)alloc((size_t)N * 8 * 4);
    float* as2v    = (float*)alloc((size_t)N * 4);
    float* ad2v    = (float*)alloc((size_t)N * 4);
    int*   deg     = (int*)alloc((size_t)N * 4);
    int*   incl    = (int*)alloc((size_t)N * 4);
    int*   offs    = (int*)alloc((size_t)(N + 1) * 4);
    int*   bsum    = (int*)alloc(256 * 4);
    int*   bpre    = (int*)alloc(256 * 4);
    int*   srcs    = (int*)alloc((size_t)Etot * 4);
    int*   slot    = (int*)alloc((size_t)Etot * 4);

    int nb = (N + 1023) / 1024;
    int Ehalf = (E / 2) & ~1023;                 // block-aligned half
    int cntB0 = Ehalf / 1024;                    // count blocks in prep
    int cntB1 = (E - Ehalf + 1023) / 1024;       // count blocks in gemm1
    int scat_blocks = (Etot + 2047) / 2048;
    int gemmB = 2 * ((N + 63) / 64);

    // zero deg, then prep (count[0,Ehalf) | W1t | W2t | Xbf)
    hipMemsetAsync(deg, 0, (size_t)N * 4, stream);
    hipLaunchKernelGGL(prep_k, dim3(cntB0 + 65 + 2048), dim3(256), 0, stream,
                       x, xbf, (long)N * 64, W1, w1t, W2, w2t,
                       dst, Ehalf, deg, slot, cntB0);
    // GEMM1 (MFMA, fused alpha1, fp8 out) + co-scheduled count [Ehalf,E)
    hipLaunchKernelGGL(gemm1_k, dim3(cntB1 + gemmB), dim3(256), 0, stream,
                       xbf, w1t, a1s, a1d, h1f8, as1, ad1, N,
                       dst, Ehalf, E, deg, slot, cntB1);
    // CSR scans (deg+1 implicit self loop)
    hipLaunchKernelGGL(scan1_k, dim3(nb), dim3(256), 0, stream, deg, incl, bsum, N);
    hipLaunchKernelGGL(scan2_k, dim3(1), dim3(64), 0, stream, bsum, bpre, nb);
    hipLaunchKernelGGL(scan3_k, dim3((N + 255) / 256), dim3(256), 0, stream,
                       incl, deg, bpre, offs, N, Etot);
    // atomic-free scatter (self loop -> last slot)
    hipLaunchKernelGGL(scatter_k, dim3(scat_blocks), dim3(256), 0, stream,
                       src, dst, slot, offs, E, Etot, srcs);
    // layer 1 aggregate (fp8 gather, deep-MLP)
    hipLaunchKernelGGL(gat1_agg_k, dim3((N + 3) / 4), dim3(256), 0, stream,
                       h1f8, as1, ad1, offs, srcs, b1, x1b, N);
    // layer 2: MFMA gemm2 + aggregate
    hipLaunchKernelGGL(gemm2_k, dim3((N + 63) / 64), dim3(256), 0, stream,
                       x1b, w2t, a2s, a2d, h2, as2v, ad2v, N);
    hipLaunchKernelGGL(gat2_agg_k, dim3((N + 3) / 4), dim3(256), 0, stream,
                       h2, as2v, ad2v, offs, srcs, b2, out, N);
}